// Round 8
// baseline (793.171 us; speedup 1.0000x reference)
//
#include <hip/hip_runtime.h>
#include <hip/hip_bf16.h>
#include <cstddef>
#include <cstdint>

// Mamba2 (2 layers). GEMMs via split-bf16 MFMA (C = AhBh + AhBl + AlBh),
// segmented-parallel selective scan (NSEG=32). Scan blocks: 256 threads
// (4 waves = 4 n-quarters), each wave carries FOUR heads (B/C broadcasts
// amortized over 4 heads); hs[4][32]/lane; LDS-staged B/C/x (dbuf, CH=4);
// y merged across quarters via LDS (2 barriers/chunk, no atomics).
//
// Workspace unchanged: 226.8 MB (budget: 253 MB proven safe).

#define BATCH 4
#define SEQ   2048
#define DMODEL 512
#define DINNER 1024
#define DSTATE 128
#define HEADDIM 64
#define NHEADS 16
#define DCONV 4
#define CONVDIM 1280
#define DINPROJ 2320
#define NPAD_IN 2432          // 19 * 128
#define ROWS (BATCH * SEQ)    // 8192
#define NSEG 32
#define TSEG 64               // SEQ / NSEG
#define CH 4                  // steps staged per LDS chunk
#define NCH (TSEG / CH)       // 16 chunks per segment

typedef __attribute__((ext_vector_type(8))) short bf16x8;
typedef __attribute__((ext_vector_type(4))) float f32x4;

__device__ __forceinline__ float silu_f(float x) {
    return x * (1.0f / (1.0f + __expf(-x)));
}
__device__ __forceinline__ unsigned short f2bfu(float f) {  // RNE fp32->bf16
    unsigned u = __float_as_uint(f);
    unsigned r = u + 0x7FFFu + ((u >> 16) & 1u);
    return (unsigned short)(r >> 16);
}
__device__ __forceinline__ float bfu2f(unsigned short h) {
    return __uint_as_float(((unsigned)h) << 16);
}

// ---------------------------------------------------------------------------
// Split fp32 A[M*K] -> Ah, Al (bf16). 8 elems/thread.
// ---------------------------------------------------------------------------
__global__ __launch_bounds__(256)
void split_a_kernel(const float* __restrict__ A,
                    unsigned short* __restrict__ Ah,
                    unsigned short* __restrict__ Al)
{
    const size_t i = ((size_t)blockIdx.x * 256 + threadIdx.x) * 8;
    const float4 a = *(const float4*)&A[i];
    const float4 b = *(const float4*)&A[i + 4];
    float v[8] = {a.x, a.y, a.z, a.w, b.x, b.y, b.z, b.w};
    unsigned hv[8], lv[8];
#pragma unroll
    for (int j = 0; j < 8; ++j) {
        hv[j] = f2bfu(v[j]);
        lv[j] = f2bfu(v[j] - bfu2f((unsigned short)hv[j]));
    }
    uint4 ph = make_uint4(hv[0] | (hv[1] << 16), hv[2] | (hv[3] << 16),
                          hv[4] | (hv[5] << 16), hv[6] | (hv[7] << 16));
    uint4 pl = make_uint4(lv[0] | (lv[1] << 16), lv[2] | (lv[3] << 16),
                          lv[4] | (lv[5] << 16), lv[6] | (lv[7] << 16));
    *(uint4*)&Ah[i] = ph;
    *(uint4*)&Al[i] = pl;
}

// ---------------------------------------------------------------------------
// Transpose + split weight W[K][N] fp32 -> Oh/Ol[Npad][K] bf16 (n >= N -> 0).
// ---------------------------------------------------------------------------
__global__ __launch_bounds__(256)
void tsplit_w_kernel(const float* __restrict__ W, int K, int N,
                     unsigned short* __restrict__ Oh,
                     unsigned short* __restrict__ Ol)
{
    __shared__ float tile[32][33];
    const int n0 = blockIdx.x * 32, k0 = blockIdx.y * 32;
    const int c = threadIdx.x & 31, r8 = threadIdx.x >> 5;
    const int n = n0 + c;
#pragma unroll
    for (int i = 0; i < 4; ++i) {
        const int k = r8 + i * 8;
        float v = 0.0f;
        if (n < N) v = W[(size_t)(k0 + k) * N + n];
        tile[c][k] = v;
    }
    __syncthreads();
#pragma unroll
    for (int i = 0; i < 4; ++i) {
        const int nl = r8 + i * 8;
        const float v = tile[nl][c];
        const unsigned short h = f2bfu(v);
        const unsigned short l = f2bfu(v - bfu2f(h));
        const size_t o = (size_t)(n0 + nl) * K + k0 + c;
        Oh[o] = h;
        Ol[o] = l;
    }
}

// ---------------------------------------------------------------------------
// Split-bf16 MFMA GEMM (unchanged, passing).
// ---------------------------------------------------------------------------
__global__ __launch_bounds__(256)
void gemm_bf16s(const unsigned short* __restrict__ Ah,
                const unsigned short* __restrict__ Al,
                const unsigned short* __restrict__ Bh,
                const unsigned short* __restrict__ Bl,
                float* __restrict__ C, int ldc, int N, int K)
{
    __shared__ __align__(16) unsigned short As[2][128 * 32];
    __shared__ __align__(16) unsigned short Bs[2][128 * 32];

    const int tid = threadIdx.x;
    const int w = tid >> 6, lane = tid & 63;
    const int wm = w >> 1, wn = w & 1;
    const int row0 = blockIdx.y * 128, col0 = blockIdx.x * 128;

    const int srow = tid >> 1;
    const int sk   = (tid & 1) * 16;

    const int lr = lane & 15;
    const int lk = (lane >> 4) * 8;

    f32x4 acc[4][4];
#pragma unroll
    for (int i = 0; i < 4; ++i)
#pragma unroll
        for (int j = 0; j < 4; ++j) acc[i][j] = (f32x4){0.f, 0.f, 0.f, 0.f};

    for (int k0 = 0; k0 < K; k0 += 32) {
        const size_t ga = (size_t)(row0 + srow) * K + k0 + sk;
        const size_t gb = (size_t)(col0 + srow) * K + k0 + sk;
        const uint4 vah0 = *(const uint4*)&Ah[ga];
        const uint4 vah1 = *(const uint4*)&Ah[ga + 8];
        const uint4 val0 = *(const uint4*)&Al[ga];
        const uint4 val1 = *(const uint4*)&Al[ga + 8];
        const uint4 vbh0 = *(const uint4*)&Bh[gb];
        const uint4 vbh1 = *(const uint4*)&Bh[gb + 8];
        const uint4 vbl0 = *(const uint4*)&Bl[gb];
        const uint4 vbl1 = *(const uint4*)&Bl[gb + 8];
        __syncthreads();
        const int so = srow * 32 + sk;
        *(uint4*)&As[0][so] = vah0;  *(uint4*)&As[0][so + 8] = vah1;
        *(uint4*)&As[1][so] = val0;  *(uint4*)&As[1][so + 8] = val1;
        *(uint4*)&Bs[0][so] = vbh0;  *(uint4*)&Bs[0][so + 8] = vbh1;
        *(uint4*)&Bs[1][so] = vbl0;  *(uint4*)&Bs[1][so + 8] = vbl1;
        __syncthreads();

        bf16x8 a_h[4], a_l[4], b_h[4], b_l[4];
#pragma unroll
        for (int mt = 0; mt < 4; ++mt) {
            const int r = wm * 64 + mt * 16 + lr;
            a_h[mt] = *(const bf16x8*)&As[0][r * 32 + lk];
            a_l[mt] = *(const bf16x8*)&As[1][r * 32 + lk];
        }
#pragma unroll
        for (int nt = 0; nt < 4; ++nt) {
            const int c = wn * 64 + nt * 16 + lr;
            b_h[nt] = *(const bf16x8*)&Bs[0][c * 32 + lk];
            b_l[nt] = *(const bf16x8*)&Bs[1][c * 32 + lk];
        }
#pragma unroll
        for (int mt = 0; mt < 4; ++mt)
#pragma unroll
            for (int nt = 0; nt < 4; ++nt) {
                acc[mt][nt] = __builtin_amdgcn_mfma_f32_16x16x32_bf16(a_h[mt], b_h[nt], acc[mt][nt], 0, 0, 0);
                acc[mt][nt] = __builtin_amdgcn_mfma_f32_16x16x32_bf16(a_h[mt], b_l[nt], acc[mt][nt], 0, 0, 0);
                acc[mt][nt] = __builtin_amdgcn_mfma_f32_16x16x32_bf16(a_l[mt], b_h[nt], acc[mt][nt], 0, 0, 0);
            }
    }

    const int crow = (lane >> 4) * 4;
#pragma unroll
    for (int mt = 0; mt < 4; ++mt)
#pragma unroll
        for (int nt = 0; nt < 4; ++nt) {
            const int cc = col0 + wn * 64 + nt * 16 + lr;
            if (cc < N) {
#pragma unroll
                for (int r = 0; r < 4; ++r)
                    C[(size_t)(row0 + wm * 64 + mt * 16 + crow + r) * ldc + cc] = acc[mt][nt][r];
            }
        }
}

// ---------------------------------------------------------------------------
// Depthwise causal conv (4 taps) + bias + SiLU + dt/dA precompute.
// ---------------------------------------------------------------------------
__global__ __launch_bounds__(320)
void conv_kernel(const float* __restrict__ zx,
                 const float* __restrict__ cw,
                 const float* __restrict__ cb,
                 const float* __restrict__ dtbias,
                 const float* __restrict__ alog,
                 float* __restrict__ xh,
                 float* __restrict__ Bb,
                 float* __restrict__ Cb,
                 float* __restrict__ dtb,
                 float* __restrict__ dAb)
{
    const int row = blockIdx.x;
    const int l   = row & (SEQ - 1);
    const int c4  = threadIdx.x * 4;

    float4 acc = *(const float4*)&cb[c4];
#pragma unroll
    for (int k = 0; k < DCONV; ++k) {
        const int lk = l - (DCONV - 1) + k;
        if (lk >= 0) {
            const float4 v = *(const float4*)&zx[(size_t)(row - (DCONV - 1) + k) * DINPROJ + DINNER + c4];
            const float4 w = *(const float4*)&cw[k * CONVDIM + c4];
            acc.x = fmaf(v.x, w.x, acc.x);
            acc.y = fmaf(v.y, w.y, acc.y);
            acc.z = fmaf(v.z, w.z, acc.z);
            acc.w = fmaf(v.w, w.w, acc.w);
        }
    }
    acc.x = silu_f(acc.x);
    acc.y = silu_f(acc.y);
    acc.z = silu_f(acc.z);
    acc.w = silu_f(acc.w);

    if (c4 < DINNER) {
        *(float4*)&xh[(size_t)row * DINNER + c4] = acc;
    } else if (c4 < DINNER + DSTATE) {
        *(float4*)&Bb[(size_t)row * DSTATE + (c4 - DINNER)] = acc;
    } else {
        *(float4*)&Cb[(size_t)row * DSTATE + (c4 - DINNER - DSTATE)] = acc;
    }

    if (threadIdx.x < NHEADS) {
        const int hh = threadIdx.x;
        const float raw = zx[(size_t)row * DINPROJ + (DINNER + CONVDIM) + hh] + dtbias[hh];
        const float dtv = (raw > 20.0f) ? raw : log1pf(expf(raw));
        const float a = expf(alog[hh]);
        dtb[row * NHEADS + hh] = dtv;
        dAb[row * NHEADS + hh] = expf(-a * dtv);
    }
}

// ---------------------------------------------------------------------------
// Pass 1: local scan per (b,h4,seg): 256 thr (4 waves = n-quarters), 4 heads
// per wave, hs[4][32]/lane, h0 = 0. B/x LDS double-buffered (CH=4).
// ---------------------------------------------------------------------------
__global__ __launch_bounds__(256, 2)
void scan_local(const float* __restrict__ xh,
                const float* __restrict__ Bb,
                const float* __restrict__ dtb,
                const float* __restrict__ dAb,
                float* __restrict__ hloc,   // (b,h,seg) x (128n x 64p)
                float* __restrict__ ptot)   // (b,h,seg)
{
    const int bid  = blockIdx.x;
    const int seg  = bid & (NSEG - 1);
    const int h4   = (bid >> 5) & 3;
    const int b    = bid >> 7;
    const int tid  = threadIdx.x;
    const int q    = tid >> 6;
    const int lane = tid & 63;

    __shared__ __align__(16) float Bs[2][CH * 128];
    __shared__ __align__(16) float xs[2][CH * 256];   // [ts][head*64+p]
    __shared__ float dAs[2][CH * 4];
    __shared__ float dts[2][CH * 4];

    float hs[4][32];
#pragma unroll
    for (int e = 0; e < 4; ++e)
#pragma unroll
        for (int j = 0; j < 32; ++j) hs[e][j] = 0.0f;
    float pr[4] = {1.f, 1.f, 1.f, 1.f};

    const size_t row0 = (size_t)b * SEQ + (size_t)seg * TSEG;
    const float* __restrict__ Bp = Bb + row0 * DSTATE;
    const float* __restrict__ xp = xh + row0 * DINNER + h4 * 256;

    const int bts = tid >> 5, bn4 = (tid & 31) * 4;  // B slots (tid<128)
    const int xts = tid >> 6, xc4 = (tid & 63) * 4;  // x slots (all)
    const int sc  = tid - 128;                        // scalar slots

    float4 rb, rx;
    float rsc = 0.0f;

    // prefetch chunk 0
    if (tid < 128) rb = *(const float4*)&Bp[(size_t)bts * DSTATE + bn4];
    rx = *(const float4*)&xp[(size_t)xts * DINNER + xc4];
    if (sc >= 0 && sc < 16)
        rsc = dAb[(row0 + (sc >> 2)) * NHEADS + h4 * 4 + (sc & 3)];
    else if (sc >= 16 && sc < 32)
        rsc = dtb[(row0 + ((sc - 16) >> 2)) * NHEADS + h4 * 4 + (sc & 3)];

    for (int c = 0; c < NCH; ++c) {
        const int cur = c & 1;
        if (tid < 128) *(float4*)&Bs[cur][bts * 128 + bn4] = rb;
        *(float4*)&xs[cur][xts * 256 + xc4] = rx;
        if (sc >= 0 && sc < 16)       dAs[cur][sc] = rsc;
        else if (sc >= 16 && sc < 32) dts[cur][sc - 16] = rsc;
        __syncthreads();

        if (c + 1 < NCH) {
            const int t0 = (c + 1) * CH;
            if (tid < 128) rb = *(const float4*)&Bp[(size_t)(t0 + bts) * DSTATE + bn4];
            rx = *(const float4*)&xp[(size_t)(t0 + xts) * DINNER + xc4];
            if (sc >= 0 && sc < 16)
                rsc = dAb[(row0 + t0 + (sc >> 2)) * NHEADS + h4 * 4 + (sc & 3)];
            else if (sc >= 16 && sc < 32)
                rsc = dtb[(row0 + t0 + ((sc - 16) >> 2)) * NHEADS + h4 * 4 + (sc & 3)];
        }

#pragma unroll
        for (int ts = 0; ts < CH; ++ts) {
            float dA[4], dtx[4];
#pragma unroll
            for (int e = 0; e < 4; ++e) {
                dA[e]  = dAs[cur][ts * 4 + e];
                dtx[e] = dts[cur][ts * 4 + e] * xs[cur][ts * 256 + e * 64 + lane];
                pr[e] *= dA[e];
            }
#pragma unroll
            for (int j4 = 0; j4 < 8; ++j4) {
                const float4 b4 = *(const float4*)&Bs[cur][ts * 128 + q * 32 + j4 * 4];
#pragma unroll
                for (int e = 0; e < 4; ++e) {
                    hs[e][j4 * 4 + 0] = fmaf(dA[e], hs[e][j4 * 4 + 0], dtx[e] * b4.x);
                    hs[e][j4 * 4 + 1] = fmaf(dA[e], hs[e][j4 * 4 + 1], dtx[e] * b4.y);
                    hs[e][j4 * 4 + 2] = fmaf(dA[e], hs[e][j4 * 4 + 2], dtx[e] * b4.z);
                    hs[e][j4 * 4 + 3] = fmaf(dA[e], hs[e][j4 * 4 + 3], dtx[e] * b4.w);
                }
            }
        }
        __syncthreads();
    }

#pragma unroll
    for (int e = 0; e < 4; ++e) {
        const size_t sidx = ((size_t)(b * NHEADS + h4 * 4 + e) * NSEG + seg) * (DSTATE * HEADDIM);
#pragma unroll
        for (int j = 0; j < 32; ++j)
            hloc[sidx + (size_t)(q * 32 + j) * HEADDIM + lane] = hs[e][j];
    }
    if (tid == 0) {
#pragma unroll
        for (int e = 0; e < 4; ++e)
            ptot[(b * NHEADS + h4 * 4 + e) * NSEG + seg] = pr[e];
    }
}

// ---------------------------------------------------------------------------
// Pass 2: sequential combine over 32 segments (in-place: hloc becomes h0).
// ---------------------------------------------------------------------------
__global__ __launch_bounds__(256)
void combine_kernel(float* __restrict__ hloc,
                    const float* __restrict__ ptot)
{
    const int bid = blockIdx.x;
    const int bh = bid >> 3;
    const int chunk = bid & 7;
    const int e0 = chunk * 1024 + threadIdx.x * 4;

    float4 s = make_float4(0.f, 0.f, 0.f, 0.f);
    for (int k = 0; k < NSEG; ++k) {
        float* p = &hloc[((size_t)bh * NSEG + k) * (DSTATE * HEADDIM) + e0];
        const float4 v = *(const float4*)p;
        *(float4*)p = s;
        const float pt = ptot[bh * NSEG + k];
        s.x = fmaf(pt, s.x, v.x);
        s.y = fmaf(pt, s.y, v.y);
        s.z = fmaf(pt, s.z, v.z);
        s.w = fmaf(pt, s.w, v.w);
    }
}

// ---------------------------------------------------------------------------
// Pass 3: full scan per (b,h4,seg), true h0. 4 waves = n-quarters, 4 heads
// per wave; y merged across quarters via LDS (2 barriers/chunk).
// ---------------------------------------------------------------------------
__global__ __launch_bounds__(256, 2)
void scan_full(const float* __restrict__ xh,
               const float* __restrict__ Bb,
               const float* __restrict__ Cb,
               const float* __restrict__ dtb,
               const float* __restrict__ dAb,
               const float* __restrict__ h0,    // (b,h,seg) x (128n x 64p)
               float* __restrict__ yb)          // (rows, 1024)
{
    const int bid  = blockIdx.x;
    const int seg  = bid & (NSEG - 1);
    const int h4   = (bid >> 5) & 3;
    const int b    = bid >> 7;
    const int tid  = threadIdx.x;
    const int q    = tid >> 6;
    const int lane = tid & 63;

    __shared__ __align__(16) float Bs[2][CH * 128];
    __shared__ __align__(16) float Cs[2][CH * 128];
    __shared__ __align__(16) float xs[2][CH * 256];     // [ts][head*64+p]
    __shared__ __align__(16) float ys[4][4][CH * 64];   // [q][head][ts*64+p]
    __shared__ float dAs[2][CH * 4];
    __shared__ float dts[2][CH * 4];

    float hs[4][32];
#pragma unroll
    for (int e = 0; e < 4; ++e) {
        const size_t sidx = ((size_t)(b * NHEADS + h4 * 4 + e) * NSEG + seg) * (DSTATE * HEADDIM);
#pragma unroll
        for (int j = 0; j < 32; ++j)
            hs[e][j] = h0[sidx + (size_t)(q * 32 + j) * HEADDIM + lane];
    }

    const size_t row0 = (size_t)b * SEQ + (size_t)seg * TSEG;
    const float* __restrict__ Bp = Bb + row0 * DSTATE;
    const float* __restrict__ Cp = Cb + row0 * DSTATE;
    const float* __restrict__ xp = xh + row0 * DINNER + h4 * 256;
    float* __restrict__ yo = yb + row0 * DINNER + h4 * 256;

    const int bts = tid >> 5, bn4 = (tid & 31) * 4;  // B/C slots (tid<128)
    const int xts = tid >> 6, xc4 = (tid & 63) * 4;  // x slots (all)
    const int sc  = tid - 128;                        // scalar slots

    // y merge-store mapping (256 f4 slots per chunk)
    const int mts = tid >> 6;
    const int mch4 = (tid & 63) * 4;
    const int me  = (tid & 63) >> 4;
    const int mp4 = (tid & 15) * 4;

    float4 rb, rc, rx;
    float rsc = 0.0f;

    // prefetch chunk 0
    if (tid < 128) {
        rb = *(const float4*)&Bp[(size_t)bts * DSTATE + bn4];
        rc = *(const float4*)&Cp[(size_t)bts * DSTATE + bn4];
    }
    rx = *(const float4*)&xp[(size_t)xts * DINNER + xc4];
    if (sc >= 0 && sc < 16)
        rsc = dAb[(row0 + (sc >> 2)) * NHEADS + h4 * 4 + (sc & 3)];
    else if (sc >= 16 && sc < 32)
        rsc = dtb[(row0 + ((sc - 16) >> 2)) * NHEADS + h4 * 4 + (sc & 3)];

    for (int c = 0; c < NCH; ++c) {
        const int cur = c & 1;
        if (tid < 128) {
            *(float4*)&Bs[cur][bts * 128 + bn4] = rb;
            *(float4*)&Cs[cur][bts * 128 + bn4] = rc;
        }
        *(float4*)&xs[cur][xts * 256 + xc4] = rx;
        if (sc >= 0 && sc < 16)       dAs[cur][sc] = rsc;
        else if (sc >= 16 && sc < 32) dts[cur][sc - 16] = rsc;
        __syncthreads();                      // [1] staging visible; prev compute done

        // merge-store chunk c-1 (reads ys of all quarters)
        if (c > 0) {
            float4 a0 = *(const float4*)&ys[0][me][mts * 64 + mp4];
            const float4 a1 = *(const float4*)&ys[1][me][mts * 64 + mp4];
            const float4 a2 = *(const float4*)&ys[2][me][mts * 64 + mp4];
            const float4 a3 = *(const float4*)&ys[3][me][mts * 64 + mp4];
            a0.x += a1.x + a2.x + a3.x;
            a0.y += a1.y + a2.y + a3.y;
            a0.z += a1.z + a2.z + a3.z;
            a0.w += a1.w + a2.w + a3.w;
            *(float4*)&yo[(size_t)((c - 1) * CH + mts) * DINNER + mch4] = a0;
        }
        __syncthreads();                      // [2] merges done before ys overwrite

        if (c + 1 < NCH) {
            const int t0 = (c + 1) * CH;
            if (tid < 128) {
                rb = *(const float4*)&Bp[(size_t)(t0 + bts) * DSTATE + bn4];
                rc = *(const float4*)&Cp[(size_t)(t0 + bts) * DSTATE + bn4];
            }
            rx = *(const float4*)&xp[(size_t)(t0 + xts) * DINNER + xc4];
            if (sc >= 0 && sc < 16)
                rsc = dAb[(row0 + t0 + (sc >> 2)) * NHEADS + h4 * 4 + (sc & 3)];
            else if (sc >= 16 && sc < 32)
                rsc = dtb[(row0 + t0 + ((sc - 16) >> 2)) * NHEADS + h4 * 4 + (sc & 3)];
        }

#pragma unroll
        for (int ts = 0; ts < CH; ++ts) {
            float dA[4], dtx[4];
#pragma unroll
            for (int e = 0; e < 4; ++e) {
                dA[e]  = dAs[cur][ts * 4 + e];
                dtx[e] = dts[cur][ts * 4 + e] * xs[cur][ts * 256 + e * 64 + lane];
            }
            float yp_[4][4];
#pragma unroll
            for (int e = 0; e < 4; ++e) {
                yp_[e][0] = 0.f; yp_[e][1] = 0.f; yp_[e][2] = 0.f; yp_[e][3] = 0.f;
            }
#pragma unroll
            for (int j4 = 0; j4 < 8; ++j4) {
                const float4 b4 = *(const float4*)&Bs[cur][ts * 128 + q * 32 + j4 * 4];
                const float4 c4 = *(const float4*)&Cs[cur][ts * 128 + q * 32 + j4 * 4];
#pragma unroll
                for (int e = 0; e < 4; ++e) {
                    hs[e][j4 * 4 + 0] = fmaf(dA[e], hs[e][j4 * 4 + 0], dtx[e] * b4.x);
                    hs[e][j4 * 4 + 1] = fmaf(dA[e], hs[e][j4 * 4 + 1], dtx[e] * b4.y);
                    hs[e][j4 * 4 + 2] = fmaf(dA[e], hs[e][j4 * 4 + 2], dtx[e] * b4.z);
                    hs[e][j4 * 4 + 3] = fmaf(dA[e], hs[e][j4 * 4 + 3], dtx[e] * b4.w);
                    yp_[e][0] = fmaf(hs[e][j4 * 4 + 0], c4.x, yp_[e][0]);
                    yp_[e][1] = fmaf(hs[e][j4 * 4 + 1], c4.y, yp_[e][1]);
                    yp_[e][2] = fmaf(hs[e][j4 * 4 + 2], c4.z, yp_[e][2]);
                    yp_[e][3] = fmaf(hs[e][j4 * 4 + 3], c4.w, yp_[e][3]);
                }
            }
#pragma unroll
            for (int e = 0; e < 4; ++e)
                ys[q][e][ts * 64 + lane] = (yp_[e][0] + yp_[e][1]) + (yp_[e][2] + yp_[e][3]);
        }
    }

    __syncthreads();
    {   // store last chunk
        float4 a0 = *(const float4*)&ys[0][me][mts * 64 + mp4];
        const float4 a1 = *(const float4*)&ys[1][me][mts * 64 + mp4];
        const float4 a2 = *(const float4*)&ys[2][me][mts * 64 + mp4];
        const float4 a3 = *(const float4*)&ys[3][me][mts * 64 + mp4];
        a0.x += a1.x + a2.x + a3.x;
        a0.y += a1.y + a2.y + a3.y;
        a0.z += a1.z + a2.z + a3.z;
        a0.w += a1.w + a2.w + a3.w;
        *(float4*)&yo[(size_t)((NCH - 1) * CH + mts) * DINNER + mch4] = a0;
    }
}

// ---------------------------------------------------------------------------
// Gate + D-skip + RMSNorm; writes ynorm as split-bf16 planes.
// ---------------------------------------------------------------------------
__global__ __launch_bounds__(256)
void gate_kernel(const float* __restrict__ yb,
                 const float* __restrict__ xh,
                 const float* __restrict__ dskip,
                 const float* __restrict__ zx,
                 const float* __restrict__ nw,
                 unsigned short* __restrict__ yh,
                 unsigned short* __restrict__ yl)
{
    const int row = blockIdx.x;
    const int c4 = threadIdx.x * 4;

    float4 y = *(const float4*)&yb[(size_t)row * DINNER + c4];
    const float4 xv = *(const float4*)&xh[(size_t)row * DINNER + c4];
    const float dsk = dskip[c4 >> 6];
    y.x = fmaf(dsk, xv.x, y.x);
    y.y = fmaf(dsk, xv.y, y.y);
    y.z = fmaf(dsk, xv.z, y.z);
    y.w = fmaf(dsk, xv.w, y.w);

    const float4 z = *(const float4*)&zx[(size_t)row * DINPROJ + c4];
    float4 g;
    g.x = y.x * silu_f(z.x);
    g.y = y.y * silu_f(z.y);
    g.z = y.z * silu_f(z.z);
    g.w = y.w * silu_f(z.w);

    float local = g.x * g.x + g.y * g.y + g.z * g.z + g.w * g.w;
#pragma unroll
    for (int m = 32; m >= 1; m >>= 1) local += __shfl_xor(local, m, 64);

    __shared__ float red[4];
    if ((threadIdx.x & 63) == 0) red[threadIdx.x >> 6] = local;
    __syncthreads();
    const float total = red[0] + red[1] + red[2] + red[3];
    const float scale = rsqrtf(total * (1.0f / (float)DINNER) + 1e-5f);

    const float4 w = *(const float4*)&nw[c4];
    float o[4];
    o[0] = g.x * scale * w.x;
    o[1] = g.y * scale * w.y;
    o[2] = g.z * scale * w.z;
    o[3] = g.w * scale * w.w;

    unsigned hv[4], lv[4];
#pragma unroll
    for (int j = 0; j < 4; ++j) {
        hv[j] = f2bfu(o[j]);
        lv[j] = f2bfu(o[j] - bfu2f((unsigned short)hv[j]));
    }
    const size_t oi = (size_t)row * DINNER + c4;
    *(uint2*)&yh[oi] = make_uint2(hv[0] | (hv[1] << 16), hv[2] | (hv[3] << 16));
    *(uint2*)&yl[oi] = make_uint2(lv[0] | (lv[1] << 16), lv[2] | (lv[3] << 16));
}

// ---------------------------------------------------------------------------
extern "C" void kernel_launch(void* const* d_in, const int* in_sizes, int n_in,
                              void* d_out, int out_size, void* d_ws, size_t ws_size,
                              hipStream_t stream)
{
    const float* x_in    = (const float*)d_in[0];
    const float* in_w    = (const float*)d_in[1];
    const float* conv_w  = (const float*)d_in[2];
    const float* conv_b  = (const float*)d_in[3];
    const float* dt_bias = (const float*)d_in[4];
    const float* A_log   = (const float*)d_in[5];
    const float* D_skip  = (const float*)d_in[6];
    const float* norm_w  = (const float*)d_in[7];
    const float* out_w   = (const float*)d_in[8];
    float* out = (float*)d_out;

    float* ws   = (float*)d_ws;
    float* zx   = ws;                               // 19,005,440 f
    float* xh   = zx   + (size_t)ROWS * DINPROJ;    //  8,388,608 f
    float* Bb   = xh   + (size_t)ROWS * DINNER;     //  1,048,576 f
    float* Cb   = Bb   + (size_t)ROWS * DSTATE;     //  1,048,576 f
    float* dtb  = Cb   + (size_t)ROWS * DSTATE;     //    131,072 f
    float* dAb  = dtb  + (size_t)ROWS * NHEADS;     //    131,072 f
    float* yb   = dAb  + (size_t)ROWS * NHEADS;     //  8,388,608 f
    float* UN   = yb   + (size_t)ROWS * DINNER;     // 16,777,216 f (union)
    float* BtF  = UN   + (size_t)16777216;          //  1,245,184 f
    float* WtF  = BtF  + (size_t)1245184;           //    524,288 f
    float* ptot = WtF  + (size_t)524288;            //      2,048 f

    unsigned short* Ah = (unsigned short*)UN;                 // [8192][512]
    unsigned short* Al = Ah + (size_t)ROWS * DMODEL;
    float*          hloc = UN;                                // 16.78M f
    unsigned short* yh = (unsigned short*)UN;                 // [8192][1024]
    unsigned short* yl = yh + (size_t)ROWS * DINNER;

    unsigned short* Bth = (unsigned short*)BtF;               // [2432][512]
    unsigned short* Btl = Bth + (size_t)NPAD_IN * DMODEL;
    unsigned short* Wth = (unsigned short*)WtF;               // [512][1024]
    unsigned short* Wtl = Wth + (size_t)DMODEL * DINNER;

    for (int layer = 0; layer < 2; ++layer) {
        const float* xl = (layer == 0) ? x_in : out;

        split_a_kernel<<<(ROWS * DMODEL) / (256 * 8), 256, 0, stream>>>(xl, Ah, Al);

        tsplit_w_kernel<<<dim3(NPAD_IN / 32, DMODEL / 32), 256, 0, stream>>>(
            in_w + (size_t)layer * DMODEL * DINPROJ, DMODEL, DINPROJ, Bth, Btl);

        gemm_bf16s<<<dim3(NPAD_IN / 128, ROWS / 128), 256, 0, stream>>>(
            Ah, Al, Bth, Btl, zx, DINPROJ, DINPROJ, DMODEL);

        conv_kernel<<<ROWS, CONVDIM / 4, 0, stream>>>(
            zx,
            conv_w + (size_t)layer * DCONV * CONVDIM,
            conv_b + (size_t)layer * CONVDIM,
            dt_bias + (size_t)layer * NHEADS,
            A_log + (size_t)layer * NHEADS,
            xh, Bb, Cb, dtb, dAb);

        scan_local<<<BATCH * (NHEADS / 4) * NSEG, 256, 0, stream>>>(
            xh, Bb, dtb, dAb, hloc, ptot);

        combine_kernel<<<BATCH * NHEADS * 8, 256, 0, stream>>>(hloc, ptot);

        scan_full<<<BATCH * (NHEADS / 4) * NSEG, 256, 0, stream>>>(
            xh, Bb, Cb, dtb, dAb, hloc, yb);

        gate_kernel<<<ROWS, 256, 0, stream>>>(
            yb, xh, D_skip + (size_t)layer * NHEADS,
            zx, norm_w + (size_t)layer * DINNER, yh, yl);

        tsplit_w_kernel<<<dim3(DMODEL / 32, DINNER / 32), 256, 0, stream>>>(
            out_w + (size_t)layer * DINNER * DMODEL, DINNER, DMODEL, Wth, Wtl);

        gemm_bf16s<<<dim3(DMODEL / 128, ROWS / 128), 256, 0, stream>>>(
            yh, yl, Wth, Wtl, out, DMODEL, DMODEL, DINNER);
    }
}

// Round 9
// 730.612 us; speedup vs baseline: 1.0856x; 1.0856x over previous
//
#include <hip/hip_runtime.h>
#include <hip/hip_bf16.h>
#include <cstddef>
#include <cstdint>

// Mamba2 (2 layers). GEMMs via split-bf16 MFMA (C = AhBh + AhBl + AlBh),
// segmented-parallel selective scan (NSEG=32). Scan blocks: 512 threads
// (8 waves = 8 n-eighths), each wave carries FOUR heads (B/C broadcasts
// amortized over 4 heads); state = hs0..hs3[16]/lane (64 VGPRs -> no spill);
// LDS-staged B/C/x (dbuf, CH=4); y merged 8-way via LDS (2 barriers/chunk).
//
// Workspace unchanged: 226.8 MB (budget: 253 MB proven safe).

#define BATCH 4
#define SEQ   2048
#define DMODEL 512
#define DINNER 1024
#define DSTATE 128
#define HEADDIM 64
#define NHEADS 16
#define DCONV 4
#define CONVDIM 1280
#define DINPROJ 2320
#define NPAD_IN 2432          // 19 * 128
#define ROWS (BATCH * SEQ)    // 8192
#define NSEG 32
#define TSEG 64               // SEQ / NSEG
#define CH 4                  // steps staged per LDS chunk
#define NCH (TSEG / CH)       // 16 chunks per segment

typedef __attribute__((ext_vector_type(8))) short bf16x8;
typedef __attribute__((ext_vector_type(4))) float f32x4;

__device__ __forceinline__ float silu_f(float x) {
    return x * (1.0f / (1.0f + __expf(-x)));
}
__device__ __forceinline__ unsigned short f2bfu(float f) {  // RNE fp32->bf16
    unsigned u = __float_as_uint(f);
    unsigned r = u + 0x7FFFu + ((u >> 16) & 1u);
    return (unsigned short)(r >> 16);
}
__device__ __forceinline__ float bfu2f(unsigned short h) {
    return __uint_as_float(((unsigned)h) << 16);
}

// ---------------------------------------------------------------------------
// Split fp32 A[M*K] -> Ah, Al (bf16). 8 elems/thread.
// ---------------------------------------------------------------------------
__global__ __launch_bounds__(256)
void split_a_kernel(const float* __restrict__ A,
                    unsigned short* __restrict__ Ah,
                    unsigned short* __restrict__ Al)
{
    const size_t i = ((size_t)blockIdx.x * 256 + threadIdx.x) * 8;
    const float4 a = *(const float4*)&A[i];
    const float4 b = *(const float4*)&A[i + 4];
    float v[8] = {a.x, a.y, a.z, a.w, b.x, b.y, b.z, b.w};
    unsigned hv[8], lv[8];
#pragma unroll
    for (int j = 0; j < 8; ++j) {
        hv[j] = f2bfu(v[j]);
        lv[j] = f2bfu(v[j] - bfu2f((unsigned short)hv[j]));
    }
    uint4 ph = make_uint4(hv[0] | (hv[1] << 16), hv[2] | (hv[3] << 16),
                          hv[4] | (hv[5] << 16), hv[6] | (hv[7] << 16));
    uint4 pl = make_uint4(lv[0] | (lv[1] << 16), lv[2] | (lv[3] << 16),
                          lv[4] | (lv[5] << 16), lv[6] | (lv[7] << 16));
    *(uint4*)&Ah[i] = ph;
    *(uint4*)&Al[i] = pl;
}

// ---------------------------------------------------------------------------
// Transpose + split weight W[K][N] fp32 -> Oh/Ol[Npad][K] bf16 (n >= N -> 0).
// ---------------------------------------------------------------------------
__global__ __launch_bounds__(256)
void tsplit_w_kernel(const float* __restrict__ W, int K, int N,
                     unsigned short* __restrict__ Oh,
                     unsigned short* __restrict__ Ol)
{
    __shared__ float tile[32][33];
    const int n0 = blockIdx.x * 32, k0 = blockIdx.y * 32;
    const int c = threadIdx.x & 31, r8 = threadIdx.x >> 5;
    const int n = n0 + c;
#pragma unroll
    for (int i = 0; i < 4; ++i) {
        const int k = r8 + i * 8;
        float v = 0.0f;
        if (n < N) v = W[(size_t)(k0 + k) * N + n];
        tile[c][k] = v;
    }
    __syncthreads();
#pragma unroll
    for (int i = 0; i < 4; ++i) {
        const int nl = r8 + i * 8;
        const float v = tile[nl][c];
        const unsigned short h = f2bfu(v);
        const unsigned short l = f2bfu(v - bfu2f(h));
        const size_t o = (size_t)(n0 + nl) * K + k0 + c;
        Oh[o] = h;
        Ol[o] = l;
    }
}

// ---------------------------------------------------------------------------
// Split-bf16 MFMA GEMM (unchanged, passing).
// ---------------------------------------------------------------------------
__global__ __launch_bounds__(256)
void gemm_bf16s(const unsigned short* __restrict__ Ah,
                const unsigned short* __restrict__ Al,
                const unsigned short* __restrict__ Bh,
                const unsigned short* __restrict__ Bl,
                float* __restrict__ C, int ldc, int N, int K)
{
    __shared__ __align__(16) unsigned short As[2][128 * 32];
    __shared__ __align__(16) unsigned short Bs[2][128 * 32];

    const int tid = threadIdx.x;
    const int w = tid >> 6, lane = tid & 63;
    const int wm = w >> 1, wn = w & 1;
    const int row0 = blockIdx.y * 128, col0 = blockIdx.x * 128;

    const int srow = tid >> 1;
    const int sk   = (tid & 1) * 16;

    const int lr = lane & 15;
    const int lk = (lane >> 4) * 8;

    f32x4 acc[4][4];
#pragma unroll
    for (int i = 0; i < 4; ++i)
#pragma unroll
        for (int j = 0; j < 4; ++j) acc[i][j] = (f32x4){0.f, 0.f, 0.f, 0.f};

    for (int k0 = 0; k0 < K; k0 += 32) {
        const size_t ga = (size_t)(row0 + srow) * K + k0 + sk;
        const size_t gb = (size_t)(col0 + srow) * K + k0 + sk;
        const uint4 vah0 = *(const uint4*)&Ah[ga];
        const uint4 vah1 = *(const uint4*)&Ah[ga + 8];
        const uint4 val0 = *(const uint4*)&Al[ga];
        const uint4 val1 = *(const uint4*)&Al[ga + 8];
        const uint4 vbh0 = *(const uint4*)&Bh[gb];
        const uint4 vbh1 = *(const uint4*)&Bh[gb + 8];
        const uint4 vbl0 = *(const uint4*)&Bl[gb];
        const uint4 vbl1 = *(const uint4*)&Bl[gb + 8];
        __syncthreads();
        const int so = srow * 32 + sk;
        *(uint4*)&As[0][so] = vah0;  *(uint4*)&As[0][so + 8] = vah1;
        *(uint4*)&As[1][so] = val0;  *(uint4*)&As[1][so + 8] = val1;
        *(uint4*)&Bs[0][so] = vbh0;  *(uint4*)&Bs[0][so + 8] = vbh1;
        *(uint4*)&Bs[1][so] = vbl0;  *(uint4*)&Bs[1][so + 8] = vbl1;
        __syncthreads();

        bf16x8 a_h[4], a_l[4], b_h[4], b_l[4];
#pragma unroll
        for (int mt = 0; mt < 4; ++mt) {
            const int r = wm * 64 + mt * 16 + lr;
            a_h[mt] = *(const bf16x8*)&As[0][r * 32 + lk];
            a_l[mt] = *(const bf16x8*)&As[1][r * 32 + lk];
        }
#pragma unroll
        for (int nt = 0; nt < 4; ++nt) {
            const int c = wn * 64 + nt * 16 + lr;
            b_h[nt] = *(const bf16x8*)&Bs[0][c * 32 + lk];
            b_l[nt] = *(const bf16x8*)&Bs[1][c * 32 + lk];
        }
#pragma unroll
        for (int mt = 0; mt < 4; ++mt)
#pragma unroll
            for (int nt = 0; nt < 4; ++nt) {
                acc[mt][nt] = __builtin_amdgcn_mfma_f32_16x16x32_bf16(a_h[mt], b_h[nt], acc[mt][nt], 0, 0, 0);
                acc[mt][nt] = __builtin_amdgcn_mfma_f32_16x16x32_bf16(a_h[mt], b_l[nt], acc[mt][nt], 0, 0, 0);
                acc[mt][nt] = __builtin_amdgcn_mfma_f32_16x16x32_bf16(a_l[mt], b_h[nt], acc[mt][nt], 0, 0, 0);
            }
    }

    const int crow = (lane >> 4) * 4;
#pragma unroll
    for (int mt = 0; mt < 4; ++mt)
#pragma unroll
        for (int nt = 0; nt < 4; ++nt) {
            const int cc = col0 + wn * 64 + nt * 16 + lr;
            if (cc < N) {
#pragma unroll
                for (int r = 0; r < 4; ++r)
                    C[(size_t)(row0 + wm * 64 + mt * 16 + crow + r) * ldc + cc] = acc[mt][nt][r];
            }
        }
}

// ---------------------------------------------------------------------------
// Depthwise causal conv (4 taps) + bias + SiLU + dt/dA precompute.
// ---------------------------------------------------------------------------
__global__ __launch_bounds__(320)
void conv_kernel(const float* __restrict__ zx,
                 const float* __restrict__ cw,
                 const float* __restrict__ cb,
                 const float* __restrict__ dtbias,
                 const float* __restrict__ alog,
                 float* __restrict__ xh,
                 float* __restrict__ Bb,
                 float* __restrict__ Cb,
                 float* __restrict__ dtb,
                 float* __restrict__ dAb)
{
    const int row = blockIdx.x;
    const int l   = row & (SEQ - 1);
    const int c4  = threadIdx.x * 4;

    float4 acc = *(const float4*)&cb[c4];
#pragma unroll
    for (int k = 0; k < DCONV; ++k) {
        const int lk = l - (DCONV - 1) + k;
        if (lk >= 0) {
            const float4 v = *(const float4*)&zx[(size_t)(row - (DCONV - 1) + k) * DINPROJ + DINNER + c4];
            const float4 w = *(const float4*)&cw[k * CONVDIM + c4];
            acc.x = fmaf(v.x, w.x, acc.x);
            acc.y = fmaf(v.y, w.y, acc.y);
            acc.z = fmaf(v.z, w.z, acc.z);
            acc.w = fmaf(v.w, w.w, acc.w);
        }
    }
    acc.x = silu_f(acc.x);
    acc.y = silu_f(acc.y);
    acc.z = silu_f(acc.z);
    acc.w = silu_f(acc.w);

    if (c4 < DINNER) {
        *(float4*)&xh[(size_t)row * DINNER + c4] = acc;
    } else if (c4 < DINNER + DSTATE) {
        *(float4*)&Bb[(size_t)row * DSTATE + (c4 - DINNER)] = acc;
    } else {
        *(float4*)&Cb[(size_t)row * DSTATE + (c4 - DINNER - DSTATE)] = acc;
    }

    if (threadIdx.x < NHEADS) {
        const int hh = threadIdx.x;
        const float raw = zx[(size_t)row * DINPROJ + (DINNER + CONVDIM) + hh] + dtbias[hh];
        const float dtv = (raw > 20.0f) ? raw : log1pf(expf(raw));
        const float a = expf(alog[hh]);
        dtb[row * NHEADS + hh] = dtv;
        dAb[row * NHEADS + hh] = expf(-a * dtv);
    }
}

// ---------------------------------------------------------------------------
// Pass 1: local scan per (b,h4,seg): 512 thr (8 waves = n-eighths), 4 heads
// per wave, hs0..hs3[16]/lane (64 state VGPRs), h0 = 0. B/x dbuf LDS (CH=4).
// ---------------------------------------------------------------------------
__global__ __launch_bounds__(512, 2)
void scan_local(const float* __restrict__ xh,
                const float* __restrict__ Bb,
                const float* __restrict__ dtb,
                const float* __restrict__ dAb,
                float* __restrict__ hloc,   // (b,h,seg) x (128n x 64p)
                float* __restrict__ ptot)   // (b,h,seg)
{
    const int bid  = blockIdx.x;
    const int seg  = bid & (NSEG - 1);
    const int h4   = (bid >> 5) & 3;
    const int b    = bid >> 7;
    const int tid  = threadIdx.x;
    const int q8   = tid >> 6;          // n-eighth 0..7
    const int lane = tid & 63;          // p

    __shared__ __align__(16) float Bs[2][CH * 128];
    __shared__ __align__(16) float xs[2][CH * 256];   // [ts][head*64+p]
    __shared__ float dAs[2][CH * 4];
    __shared__ float dts[2][CH * 4];

    float hs0[16], hs1[16], hs2[16], hs3[16];
#pragma unroll
    for (int j = 0; j < 16; ++j) { hs0[j] = 0.f; hs1[j] = 0.f; hs2[j] = 0.f; hs3[j] = 0.f; }
    float pr0 = 1.f, pr1 = 1.f, pr2 = 1.f, pr3 = 1.f;

    const size_t row0 = (size_t)b * SEQ + (size_t)seg * TSEG;
    const float* __restrict__ Bp = Bb + row0 * DSTATE;
    const float* __restrict__ xp = xh + row0 * DINNER + h4 * 256;

    // staging roles
    const int bts = tid >> 5, bn4 = (tid & 31) * 4;           // B: tid<128
    const int xs_ = tid - 128;                                 // x: tid in [128,384)
    const int xts = xs_ >> 6, xc4 = (xs_ & 63) * 4;
    const int sc  = tid - 384;                                 // scalars: [384,416)

    float4 rb, rx;
    float rsc = 0.0f;

    // prefetch chunk 0
    if (tid < 128) rb = *(const float4*)&Bp[(size_t)bts * DSTATE + bn4];
    else if (tid < 384) rx = *(const float4*)&xp[(size_t)xts * DINNER + xc4];
    else if (sc < 16)  rsc = dAb[(row0 + (sc >> 2)) * NHEADS + h4 * 4 + (sc & 3)];
    else if (sc < 32)  rsc = dtb[(row0 + ((sc - 16) >> 2)) * NHEADS + h4 * 4 + (sc & 3)];

    for (int c = 0; c < NCH; ++c) {
        const int cur = c & 1;
        if (tid < 128)      *(float4*)&Bs[cur][bts * 128 + bn4] = rb;
        else if (tid < 384) *(float4*)&xs[cur][xts * 256 + xc4] = rx;
        else if (sc < 16)   dAs[cur][sc] = rsc;
        else if (sc < 32)   dts[cur][sc - 16] = rsc;
        __syncthreads();

        if (c + 1 < NCH) {
            const int t0 = (c + 1) * CH;
            if (tid < 128) rb = *(const float4*)&Bp[(size_t)(t0 + bts) * DSTATE + bn4];
            else if (tid < 384) rx = *(const float4*)&xp[(size_t)(t0 + xts) * DINNER + xc4];
            else if (sc < 16)  rsc = dAb[(row0 + t0 + (sc >> 2)) * NHEADS + h4 * 4 + (sc & 3)];
            else if (sc < 32)  rsc = dtb[(row0 + t0 + ((sc - 16) >> 2)) * NHEADS + h4 * 4 + (sc & 3)];
        }

#pragma unroll
        for (int ts = 0; ts < CH; ++ts) {
            const float dA0 = dAs[cur][ts * 4 + 0];
            const float dA1 = dAs[cur][ts * 4 + 1];
            const float dA2 = dAs[cur][ts * 4 + 2];
            const float dA3 = dAs[cur][ts * 4 + 3];
            const float dtx0 = dts[cur][ts * 4 + 0] * xs[cur][ts * 256 + 0 * 64 + lane];
            const float dtx1 = dts[cur][ts * 4 + 1] * xs[cur][ts * 256 + 1 * 64 + lane];
            const float dtx2 = dts[cur][ts * 4 + 2] * xs[cur][ts * 256 + 2 * 64 + lane];
            const float dtx3 = dts[cur][ts * 4 + 3] * xs[cur][ts * 256 + 3 * 64 + lane];
            pr0 *= dA0; pr1 *= dA1; pr2 *= dA2; pr3 *= dA3;
#pragma unroll
            for (int j4 = 0; j4 < 4; ++j4) {
                const float4 b4 = *(const float4*)&Bs[cur][ts * 128 + q8 * 16 + j4 * 4];
#pragma unroll
                for (int k = 0; k < 4; ++k) {
                    const float bv = (&b4.x)[k];
                    hs0[j4 * 4 + k] = fmaf(dA0, hs0[j4 * 4 + k], dtx0 * bv);
                    hs1[j4 * 4 + k] = fmaf(dA1, hs1[j4 * 4 + k], dtx1 * bv);
                    hs2[j4 * 4 + k] = fmaf(dA2, hs2[j4 * 4 + k], dtx2 * bv);
                    hs3[j4 * 4 + k] = fmaf(dA3, hs3[j4 * 4 + k], dtx3 * bv);
                }
            }
        }
        __syncthreads();
    }

    {
        const size_t s0 = ((size_t)(b * NHEADS + h4 * 4 + 0) * NSEG + seg) * (DSTATE * HEADDIM);
        const size_t s1 = ((size_t)(b * NHEADS + h4 * 4 + 1) * NSEG + seg) * (DSTATE * HEADDIM);
        const size_t s2 = ((size_t)(b * NHEADS + h4 * 4 + 2) * NSEG + seg) * (DSTATE * HEADDIM);
        const size_t s3 = ((size_t)(b * NHEADS + h4 * 4 + 3) * NSEG + seg) * (DSTATE * HEADDIM);
#pragma unroll
        for (int j = 0; j < 16; ++j) {
            const size_t o = (size_t)(q8 * 16 + j) * HEADDIM + lane;
            hloc[s0 + o] = hs0[j];
            hloc[s1 + o] = hs1[j];
            hloc[s2 + o] = hs2[j];
            hloc[s3 + o] = hs3[j];
        }
    }
    if (tid == 0) {
        ptot[(b * NHEADS + h4 * 4 + 0) * NSEG + seg] = pr0;
        ptot[(b * NHEADS + h4 * 4 + 1) * NSEG + seg] = pr1;
        ptot[(b * NHEADS + h4 * 4 + 2) * NSEG + seg] = pr2;
        ptot[(b * NHEADS + h4 * 4 + 3) * NSEG + seg] = pr3;
    }
}

// ---------------------------------------------------------------------------
// Pass 2: sequential combine over 32 segments (in-place: hloc becomes h0).
// ---------------------------------------------------------------------------
__global__ __launch_bounds__(256)
void combine_kernel(float* __restrict__ hloc,
                    const float* __restrict__ ptot)
{
    const int bid = blockIdx.x;
    const int bh = bid >> 3;
    const int chunk = bid & 7;
    const int e0 = chunk * 1024 + threadIdx.x * 4;

    float4 s = make_float4(0.f, 0.f, 0.f, 0.f);
    for (int k = 0; k < NSEG; ++k) {
        float* p = &hloc[((size_t)bh * NSEG + k) * (DSTATE * HEADDIM) + e0];
        const float4 v = *(const float4*)p;
        *(float4*)p = s;
        const float pt = ptot[bh * NSEG + k];
        s.x = fmaf(pt, s.x, v.x);
        s.y = fmaf(pt, s.y, v.y);
        s.z = fmaf(pt, s.z, v.z);
        s.w = fmaf(pt, s.w, v.w);
    }
}

// ---------------------------------------------------------------------------
// Pass 3: full scan per (b,h4,seg), true h0. 8 waves = n-eighths, 4 heads
// per wave; y merged 8-way via LDS (2 barriers/chunk, no atomics).
// ---------------------------------------------------------------------------
__global__ __launch_bounds__(512, 2)
void scan_full(const float* __restrict__ xh,
               const float* __restrict__ Bb,
               const float* __restrict__ Cb,
               const float* __restrict__ dtb,
               const float* __restrict__ dAb,
               const float* __restrict__ h0,    // (b,h,seg) x (128n x 64p)
               float* __restrict__ yb)          // (rows, 1024)
{
    const int bid  = blockIdx.x;
    const int seg  = bid & (NSEG - 1);
    const int h4   = (bid >> 5) & 3;
    const int b    = bid >> 7;
    const int tid  = threadIdx.x;
    const int q8   = tid >> 6;          // n-eighth 0..7
    const int lane = tid & 63;          // p

    __shared__ __align__(16) float Bs[2][CH * 128];
    __shared__ __align__(16) float Cs[2][CH * 128];
    __shared__ __align__(16) float xs[2][CH * 256];     // [ts][head*64+p]
    __shared__ __align__(16) float ys[8][4][CH * 64];   // [q8][head][ts*64+p]
    __shared__ float dAs[2][CH * 4];
    __shared__ float dts[2][CH * 4];

    const size_t s0 = ((size_t)(b * NHEADS + h4 * 4 + 0) * NSEG + seg) * (DSTATE * HEADDIM);
    const size_t s1 = ((size_t)(b * NHEADS + h4 * 4 + 1) * NSEG + seg) * (DSTATE * HEADDIM);
    const size_t s2 = ((size_t)(b * NHEADS + h4 * 4 + 2) * NSEG + seg) * (DSTATE * HEADDIM);
    const size_t s3 = ((size_t)(b * NHEADS + h4 * 4 + 3) * NSEG + seg) * (DSTATE * HEADDIM);
    float hs0[16], hs1[16], hs2[16], hs3[16];
#pragma unroll
    for (int j = 0; j < 16; ++j) {
        const size_t o = (size_t)(q8 * 16 + j) * HEADDIM + lane;
        hs0[j] = h0[s0 + o];
        hs1[j] = h0[s1 + o];
        hs2[j] = h0[s2 + o];
        hs3[j] = h0[s3 + o];
    }

    const size_t row0 = (size_t)b * SEQ + (size_t)seg * TSEG;
    const float* __restrict__ Bp = Bb + row0 * DSTATE;
    const float* __restrict__ Cp = Cb + row0 * DSTATE;
    const float* __restrict__ xp = xh + row0 * DINNER + h4 * 256;
    float* __restrict__ yo = yb + row0 * DINNER + h4 * 256;

    // staging roles
    const int bts = tid >> 5, bn4 = (tid & 31) * 4;           // B: tid<128 (also scalars tid<32)
    const int cs_ = tid - 128;                                 // C: [128,256)
    const int cts = cs_ >> 5, cn4 = (cs_ & 31) * 4;
    const int xs_ = tid - 256;                                 // x: [256,512)
    const int xts = xs_ >> 6, xc4 = (xs_ & 63) * 4;

    // y merge mapping (tid<256): 256 f4 slots per chunk
    const int mts = tid >> 6;              // 0..3
    const int me  = (tid & 63) >> 4;       // head 0..3
    const int mp4 = (tid & 15) * 4;        // p offset
    const int mch4 = (tid & 63) * 4;       // channel offset within 256

    float4 rb, rc, rx;
    float rscA = 0.0f, rscT = 0.0f;

    // prefetch chunk 0
    if (tid < 128) {
        rb = *(const float4*)&Bp[(size_t)bts * DSTATE + bn4];
        if (tid < 16)      rscA = dAb[(row0 + (tid >> 2)) * NHEADS + h4 * 4 + (tid & 3)];
        else if (tid < 32) rscT = dtb[(row0 + ((tid - 16) >> 2)) * NHEADS + h4 * 4 + (tid & 3)];
    } else if (tid < 256) {
        rc = *(const float4*)&Cp[(size_t)cts * DSTATE + cn4];
    } else {
        rx = *(const float4*)&xp[(size_t)xts * DINNER + xc4];
    }

    for (int c = 0; c < NCH; ++c) {
        const int cur = c & 1;
        if (tid < 128) {
            *(float4*)&Bs[cur][bts * 128 + bn4] = rb;
            if (tid < 16)      dAs[cur][tid] = rscA;
            else if (tid < 32) dts[cur][tid - 16] = rscT;
        } else if (tid < 256) {
            *(float4*)&Cs[cur][cts * 128 + cn4] = rc;
        } else {
            *(float4*)&xs[cur][xts * 256 + xc4] = rx;
        }
        __syncthreads();                      // [1] staging visible; prev compute done

        // merge-store chunk c-1 (reads ys of all 8 eighths)
        if (c > 0 && tid < 256) {
            float4 a = *(const float4*)&ys[0][me][mts * 64 + mp4];
#pragma unroll
            for (int qq = 1; qq < 8; ++qq) {
                const float4 t = *(const float4*)&ys[qq][me][mts * 64 + mp4];
                a.x += t.x; a.y += t.y; a.z += t.z; a.w += t.w;
            }
            *(float4*)&yo[(size_t)((c - 1) * CH + mts) * DINNER + mch4] = a;
        }
        __syncthreads();                      // [2] merges done before ys overwrite

        if (c + 1 < NCH) {
            const int t0 = (c + 1) * CH;
            if (tid < 128) {
                rb = *(const float4*)&Bp[(size_t)(t0 + bts) * DSTATE + bn4];
                if (tid < 16)      rscA = dAb[(row0 + t0 + (tid >> 2)) * NHEADS + h4 * 4 + (tid & 3)];
                else if (tid < 32) rscT = dtb[(row0 + t0 + ((tid - 16) >> 2)) * NHEADS + h4 * 4 + (tid & 3)];
            } else if (tid < 256) {
                rc = *(const float4*)&Cp[(size_t)(t0 + cts) * DSTATE + cn4];
            } else {
                rx = *(const float4*)&xp[(size_t)(t0 + xts) * DINNER + xc4];
            }
        }

#pragma unroll
        for (int ts = 0; ts < CH; ++ts) {
            const float dA0 = dAs[cur][ts * 4 + 0];
            const float dA1 = dAs[cur][ts * 4 + 1];
            const float dA2 = dAs[cur][ts * 4 + 2];
            const float dA3 = dAs[cur][ts * 4 + 3];
            const float dtx0 = dts[cur][ts * 4 + 0] * xs[cur][ts * 256 + 0 * 64 + lane];
            const float dtx1 = dts[cur][ts * 4 + 1] * xs[cur][ts * 256 + 1 * 64 + lane];
            const float dtx2 = dts[cur][ts * 4 + 2] * xs[cur][ts * 256 + 2 * 64 + lane];
            const float dtx3 = dts[cur][ts * 4 + 3] * xs[cur][ts * 256 + 3 * 64 + lane];
            float ya0 = 0.f, ya1 = 0.f;
            float yb0 = 0.f, yb1 = 0.f;
            float yc0 = 0.f, yc1 = 0.f;
            float yd0 = 0.f, yd1 = 0.f;
#pragma unroll
            for (int j4 = 0; j4 < 4; ++j4) {
                const float4 b4 = *(const float4*)&Bs[cur][ts * 128 + q8 * 16 + j4 * 4];
                const float4 c4 = *(const float4*)&Cs[cur][ts * 128 + q8 * 16 + j4 * 4];
                hs0[j4 * 4 + 0] = fmaf(dA0, hs0[j4 * 4 + 0], dtx0 * b4.x);
                hs0[j4 * 4 + 1] = fmaf(dA0, hs0[j4 * 4 + 1], dtx0 * b4.y);
                hs0[j4 * 4 + 2] = fmaf(dA0, hs0[j4 * 4 + 2], dtx0 * b4.z);
                hs0[j4 * 4 + 3] = fmaf(dA0, hs0[j4 * 4 + 3], dtx0 * b4.w);
                ya0 = fmaf(hs0[j4 * 4 + 0], c4.x, ya0);
                ya1 = fmaf(hs0[j4 * 4 + 1], c4.y, ya1);
                ya0 = fmaf(hs0[j4 * 4 + 2], c4.z, ya0);
                ya1 = fmaf(hs0[j4 * 4 + 3], c4.w, ya1);
                hs1[j4 * 4 + 0] = fmaf(dA1, hs1[j4 * 4 + 0], dtx1 * b4.x);
                hs1[j4 * 4 + 1] = fmaf(dA1, hs1[j4 * 4 + 1], dtx1 * b4.y);
                hs1[j4 * 4 + 2] = fmaf(dA1, hs1[j4 * 4 + 2], dtx1 * b4.z);
                hs1[j4 * 4 + 3] = fmaf(dA1, hs1[j4 * 4 + 3], dtx1 * b4.w);
                yb0 = fmaf(hs1[j4 * 4 + 0], c4.x, yb0);
                yb1 = fmaf(hs1[j4 * 4 + 1], c4.y, yb1);
                yb0 = fmaf(hs1[j4 * 4 + 2], c4.z, yb0);
                yb1 = fmaf(hs1[j4 * 4 + 3], c4.w, yb1);
                hs2[j4 * 4 + 0] = fmaf(dA2, hs2[j4 * 4 + 0], dtx2 * b4.x);
                hs2[j4 * 4 + 1] = fmaf(dA2, hs2[j4 * 4 + 1], dtx2 * b4.y);
                hs2[j4 * 4 + 2] = fmaf(dA2, hs2[j4 * 4 + 2], dtx2 * b4.z);
                hs2[j4 * 4 + 3] = fmaf(dA2, hs2[j4 * 4 + 3], dtx2 * b4.w);
                yc0 = fmaf(hs2[j4 * 4 + 0], c4.x, yc0);
                yc1 = fmaf(hs2[j4 * 4 + 1], c4.y, yc1);
                yc0 = fmaf(hs2[j4 * 4 + 2], c4.z, yc0);
                yc1 = fmaf(hs2[j4 * 4 + 3], c4.w, yc1);
                hs3[j4 * 4 + 0] = fmaf(dA3, hs3[j4 * 4 + 0], dtx3 * b4.x);
                hs3[j4 * 4 + 1] = fmaf(dA3, hs3[j4 * 4 + 1], dtx3 * b4.y);
                hs3[j4 * 4 + 2] = fmaf(dA3, hs3[j4 * 4 + 2], dtx3 * b4.z);
                hs3[j4 * 4 + 3] = fmaf(dA3, hs3[j4 * 4 + 3], dtx3 * b4.w);
                yd0 = fmaf(hs3[j4 * 4 + 0], c4.x, yd0);
                yd1 = fmaf(hs3[j4 * 4 + 1], c4.y, yd1);
                yd0 = fmaf(hs3[j4 * 4 + 2], c4.z, yd0);
                yd1 = fmaf(hs3[j4 * 4 + 3], c4.w, yd1);
            }
            ys[q8][0][ts * 64 + lane] = ya0 + ya1;
            ys[q8][1][ts * 64 + lane] = yb0 + yb1;
            ys[q8][2][ts * 64 + lane] = yc0 + yc1;
            ys[q8][3][ts * 64 + lane] = yd0 + yd1;
        }
    }

    __syncthreads();
    if (tid < 256) {   // store last chunk
        float4 a = *(const float4*)&ys[0][me][mts * 64 + mp4];
#pragma unroll
        for (int qq = 1; qq < 8; ++qq) {
            const float4 t = *(const float4*)&ys[qq][me][mts * 64 + mp4];
            a.x += t.x; a.y += t.y; a.z += t.z; a.w += t.w;
        }
        *(float4*)&yo[(size_t)((NCH - 1) * CH + mts) * DINNER + mch4] = a;
    }
}

// ---------------------------------------------------------------------------
// Gate + D-skip + RMSNorm; writes ynorm as split-bf16 planes.
// ---------------------------------------------------------------------------
__global__ __launch_bounds__(256)
void gate_kernel(const float* __restrict__ yb,
                 const float* __restrict__ xh,
                 const float* __restrict__ dskip,
                 const float* __restrict__ zx,
                 const float* __restrict__ nw,
                 unsigned short* __restrict__ yh,
                 unsigned short* __restrict__ yl)
{
    const int row = blockIdx.x;
    const int c4 = threadIdx.x * 4;

    float4 y = *(const float4*)&yb[(size_t)row * DINNER + c4];
    const float4 xv = *(const float4*)&xh[(size_t)row * DINNER + c4];
    const float dsk = dskip[c4 >> 6];
    y.x = fmaf(dsk, xv.x, y.x);
    y.y = fmaf(dsk, xv.y, y.y);
    y.z = fmaf(dsk, xv.z, y.z);
    y.w = fmaf(dsk, xv.w, y.w);

    const float4 z = *(const float4*)&zx[(size_t)row * DINPROJ + c4];
    float4 g;
    g.x = y.x * silu_f(z.x);
    g.y = y.y * silu_f(z.y);
    g.z = y.z * silu_f(z.z);
    g.w = y.w * silu_f(z.w);

    float local = g.x * g.x + g.y * g.y + g.z * g.z + g.w * g.w;
#pragma unroll
    for (int m = 32; m >= 1; m >>= 1) local += __shfl_xor(local, m, 64);

    __shared__ float red[4];
    if ((threadIdx.x & 63) == 0) red[threadIdx.x >> 6] = local;
    __syncthreads();
    const float total = red[0] + red[1] + red[2] + red[3];
    const float scale = rsqrtf(total * (1.0f / (float)DINNER) + 1e-5f);

    const float4 w = *(const float4*)&nw[c4];
    float o[4];
    o[0] = g.x * scale * w.x;
    o[1] = g.y * scale * w.y;
    o[2] = g.z * scale * w.z;
    o[3] = g.w * scale * w.w;

    unsigned hv[4], lv[4];
#pragma unroll
    for (int j = 0; j < 4; ++j) {
        hv[j] = f2bfu(o[j]);
        lv[j] = f2bfu(o[j] - bfu2f((unsigned short)hv[j]));
    }
    const size_t oi = (size_t)row * DINNER + c4;
    *(uint2*)&yh[oi] = make_uint2(hv[0] | (hv[1] << 16), hv[2] | (hv[3] << 16));
    *(uint2*)&yl[oi] = make_uint2(lv[0] | (lv[1] << 16), lv[2] | (lv[3] << 16));
}

// ---------------------------------------------------------------------------
extern "C" void kernel_launch(void* const* d_in, const int* in_sizes, int n_in,
                              void* d_out, int out_size, void* d_ws, size_t ws_size,
                              hipStream_t stream)
{
    const float* x_in    = (const float*)d_in[0];
    const float* in_w    = (const float*)d_in[1];
    const float* conv_w  = (const float*)d_in[2];
    const float* conv_b  = (const float*)d_in[3];
    const float* dt_bias = (const float*)d_in[4];
    const float* A_log   = (const float*)d_in[5];
    const float* D_skip  = (const float*)d_in[6];
    const float* norm_w  = (const float*)d_in[7];
    const float* out_w   = (const float*)d_in[8];
    float* out = (float*)d_out;

    float* ws   = (float*)d_ws;
    float* zx   = ws;                               // 19,005,440 f
    float* xh   = zx   + (size_t)ROWS * DINPROJ;    //  8,388,608 f
    float* Bb   = xh   + (size_t)ROWS * DINNER;     //  1,048,576 f
    float* Cb   = Bb   + (size_t)ROWS * DSTATE;     //  1,048,576 f
    float* dtb  = Cb   + (size_t)ROWS * DSTATE;     //    131,072 f
    float* dAb  = dtb  + (size_t)ROWS * NHEADS;     //    131,072 f
    float* yb   = dAb  + (size_t)ROWS * NHEADS;     //  8,388,608 f
    float* UN   = yb   + (size_t)ROWS * DINNER;     // 16,777,216 f (union)
    float* BtF  = UN   + (size_t)16777216;          //  1,245,184 f
    float* WtF  = BtF  + (size_t)1245184;           //    524,288 f
    float* ptot = WtF  + (size_t)524288;            //      2,048 f

    unsigned short* Ah = (unsigned short*)UN;                 // [8192][512]
    unsigned short* Al = Ah + (size_t)ROWS * DMODEL;
    float*          hloc = UN;                                // 16.78M f
    unsigned short* yh = (unsigned short*)UN;                 // [8192][1024]
    unsigned short* yl = yh + (size_t)ROWS * DINNER;

    unsigned short* Bth = (unsigned short*)BtF;               // [2432][512]
    unsigned short* Btl = Bth + (size_t)NPAD_IN * DMODEL;
    unsigned short* Wth = (unsigned short*)WtF;               // [512][1024]
    unsigned short* Wtl = Wth + (size_t)DMODEL * DINNER;

    for (int layer = 0; layer < 2; ++layer) {
        const float* xl = (layer == 0) ? x_in : out;

        split_a_kernel<<<(ROWS * DMODEL) / (256 * 8), 256, 0, stream>>>(xl, Ah, Al);

        tsplit_w_kernel<<<dim3(NPAD_IN / 32, DMODEL / 32), 256, 0, stream>>>(
            in_w + (size_t)layer * DMODEL * DINPROJ, DMODEL, DINPROJ, Bth, Btl);

        gemm_bf16s<<<dim3(NPAD_IN / 128, ROWS / 128), 256, 0, stream>>>(
            Ah, Al, Bth, Btl, zx, DINPROJ, DINPROJ, DMODEL);

        conv_kernel<<<ROWS, CONVDIM / 4, 0, stream>>>(
            zx,
            conv_w + (size_t)layer * DCONV * CONVDIM,
            conv_b + (size_t)layer * CONVDIM,
            dt_bias + (size_t)layer * NHEADS,
            A_log + (size_t)layer * NHEADS,
            xh, Bb, Cb, dtb, dAb);

        scan_local<<<BATCH * (NHEADS / 4) * NSEG, 512, 0, stream>>>(
            xh, Bb, dtb, dAb, hloc, ptot);

        combine_kernel<<<BATCH * NHEADS * 8, 256, 0, stream>>>(hloc, ptot);

        scan_full<<<BATCH * (NHEADS / 4) * NSEG, 512, 0, stream>>>(
            xh, Bb, Cb, dtb, dAb, hloc, yb);

        gate_kernel<<<ROWS, 256, 0, stream>>>(
            yb, xh, D_skip + (size_t)layer * NHEADS,
            zx, norm_w + (size_t)layer * DINNER, yh, yl);

        tsplit_w_kernel<<<dim3(DMODEL / 32, DINNER / 32), 256, 0, stream>>>(
            out_w + (size_t)layer * DINNER * DMODEL, DINNER, DMODEL, Wth, Wtl);

        gemm_bf16s<<<dim3(DMODEL / 128, ROWS / 128), 256, 0, stream>>>(
            yh, yl, Wth, Wtl, out, DMODEL, DMODEL, DINNER);
    }
}

// Round 11
// 627.193 us; speedup vs baseline: 1.2646x; 1.1649x over previous
//
#include <hip/hip_runtime.h>
#include <hip/hip_bf16.h>
#include <cstddef>
#include <cstdint>

// Mamba2 (2 layers). GEMMs via split-bf16 MFMA (C = AhBh + AhBl + AlBh).
// Selective scan via CHUNKED SSD (chunk Q=64): all heavy ops are MFMA.
//   meta:  l[t] = cumsum(-a*dt) per (b,h,chunk); w[t]=exp(l63-lt)*dt; ptot=exp(l63)
//   state: S[n,p] = sum_t (B[t,n]*w[t]) x[t,p]          (MFMA, -> hloc)
//   combine: sequential over 32 chunks -> h0 (unchanged from verified rounds)
//   cb:    CB[t,s] = C_chunk @ B_chunk^T                 (MFMA, shared by heads)
//   y:     y = diag(exp l)*(C@h0) + (M)@x, M[t,s]=CB*dt[s]*exp(lt-ls)*causal
// Round-11 fix: cb_kernel and y_kernel staged only HALF their LDS tiles
// (512 of 1024 uint4) -> garbage bf16 -> NaN. Loads completed; nothing else
// changed. Workspace: 242.5 MB (< 253 MB proven safe).

#define BATCH 4
#define SEQ   2048
#define DMODEL 512
#define DINNER 1024
#define DSTATE 128
#define HEADDIM 64
#define NHEADS 16
#define DCONV 4
#define CONVDIM 1280
#define DINPROJ 2320
#define NPAD_IN 2432          // 19 * 128
#define ROWS (BATCH * SEQ)    // 8192
#define NSEG 32               // chunks per sequence
#define TSEG 64               // chunk length

typedef __attribute__((ext_vector_type(8))) short bf16x8;
typedef __attribute__((ext_vector_type(4))) float f32x4;

__device__ __forceinline__ float silu_f(float x) {
    return x * (1.0f / (1.0f + __expf(-x)));
}
__device__ __forceinline__ unsigned short f2bfu(float f) {  // RNE fp32->bf16
    unsigned u = __float_as_uint(f);
    unsigned r = u + 0x7FFFu + ((u >> 16) & 1u);
    return (unsigned short)(r >> 16);
}
__device__ __forceinline__ float bfu2f(unsigned short h) {
    return __uint_as_float(((unsigned)h) << 16);
}

// ---------------------------------------------------------------------------
// Split fp32 flat array -> hi/lo bf16. 8 elems/thread.
// ---------------------------------------------------------------------------
__global__ __launch_bounds__(256)
void split_a_kernel(const float* __restrict__ A,
                    unsigned short* __restrict__ Ah,
                    unsigned short* __restrict__ Al)
{
    const size_t i = ((size_t)blockIdx.x * 256 + threadIdx.x) * 8;
    const float4 a = *(const float4*)&A[i];
    const float4 b = *(const float4*)&A[i + 4];
    float v[8] = {a.x, a.y, a.z, a.w, b.x, b.y, b.z, b.w};
    unsigned hv[8], lv[8];
#pragma unroll
    for (int j = 0; j < 8; ++j) {
        hv[j] = f2bfu(v[j]);
        lv[j] = f2bfu(v[j] - bfu2f((unsigned short)hv[j]));
    }
    uint4 ph = make_uint4(hv[0] | (hv[1] << 16), hv[2] | (hv[3] << 16),
                          hv[4] | (hv[5] << 16), hv[6] | (hv[7] << 16));
    uint4 pl = make_uint4(lv[0] | (lv[1] << 16), lv[2] | (lv[3] << 16),
                          lv[4] | (lv[5] << 16), lv[6] | (lv[7] << 16));
    *(uint4*)&Ah[i] = ph;
    *(uint4*)&Al[i] = pl;
}

// ---------------------------------------------------------------------------
// Transpose + split weight W[K][N] fp32 -> Oh/Ol[Npad][K] bf16 (n >= N -> 0).
// ---------------------------------------------------------------------------
__global__ __launch_bounds__(256)
void tsplit_w_kernel(const float* __restrict__ W, int K, int N,
                     unsigned short* __restrict__ Oh,
                     unsigned short* __restrict__ Ol)
{
    __shared__ float tile[32][33];
    const int n0 = blockIdx.x * 32, k0 = blockIdx.y * 32;
    const int c = threadIdx.x & 31, r8 = threadIdx.x >> 5;
    const int n = n0 + c;
#pragma unroll
    for (int i = 0; i < 4; ++i) {
        const int k = r8 + i * 8;
        float v = 0.0f;
        if (n < N) v = W[(size_t)(k0 + k) * N + n];
        tile[c][k] = v;
    }
    __syncthreads();
#pragma unroll
    for (int i = 0; i < 4; ++i) {
        const int nl = r8 + i * 8;
        const float v = tile[nl][c];
        const unsigned short h = f2bfu(v);
        const unsigned short l = f2bfu(v - bfu2f(h));
        const size_t o = (size_t)(n0 + nl) * K + k0 + c;
        Oh[o] = h;
        Ol[o] = l;
    }
}

// ---------------------------------------------------------------------------
// Chunked transpose+split: per z, fp32 [K][N] (rowstride rs) -> bf16 [N][K].
// ---------------------------------------------------------------------------
__global__ __launch_bounds__(256)
void tsplit_chunk_kernel(const float* __restrict__ src, int K, int N, int rs,
                         size_t chunkStride,
                         unsigned short* __restrict__ Oh,
                         unsigned short* __restrict__ Ol)
{
    __shared__ float tile[32][33];
    const int z = blockIdx.z;
    const float* W = src + (size_t)z * chunkStride;
    const int n0 = blockIdx.x * 32, k0 = blockIdx.y * 32;
    const int c = threadIdx.x & 31, r8 = threadIdx.x >> 5;
#pragma unroll
    for (int i = 0; i < 4; ++i) {
        const int k = r8 + i * 8;
        tile[c][k] = W[(size_t)(k0 + k) * rs + n0 + c];
    }
    __syncthreads();
#pragma unroll
    for (int i = 0; i < 4; ++i) {
        const int nl = r8 + i * 8;
        const float v = tile[nl][c];
        const unsigned short h = f2bfu(v);
        const unsigned short l = f2bfu(v - bfu2f(h));
        const size_t o = (size_t)z * N * K + (size_t)(n0 + nl) * K + k0 + c;
        Oh[o] = h;
        Ol[o] = l;
    }
}

// ---------------------------------------------------------------------------
// Split-bf16 MFMA GEMM (unchanged, verified).
// ---------------------------------------------------------------------------
__global__ __launch_bounds__(256)
void gemm_bf16s(const unsigned short* __restrict__ Ah,
                const unsigned short* __restrict__ Al,
                const unsigned short* __restrict__ Bh,
                const unsigned short* __restrict__ Bl,
                float* __restrict__ C, int ldc, int N, int K)
{
    __shared__ __align__(16) unsigned short As[2][128 * 32];
    __shared__ __align__(16) unsigned short Bs[2][128 * 32];

    const int tid = threadIdx.x;
    const int w = tid >> 6, lane = tid & 63;
    const int wm = w >> 1, wn = w & 1;
    const int row0 = blockIdx.y * 128, col0 = blockIdx.x * 128;

    const int srow = tid >> 1;
    const int sk   = (tid & 1) * 16;

    const int lr = lane & 15;
    const int lk = (lane >> 4) * 8;

    f32x4 acc[4][4];
#pragma unroll
    for (int i = 0; i < 4; ++i)
#pragma unroll
        for (int j = 0; j < 4; ++j) acc[i][j] = (f32x4){0.f, 0.f, 0.f, 0.f};

    for (int k0 = 0; k0 < K; k0 += 32) {
        const size_t ga = (size_t)(row0 + srow) * K + k0 + sk;
        const size_t gb = (size_t)(col0 + srow) * K + k0 + sk;
        const uint4 vah0 = *(const uint4*)&Ah[ga];
        const uint4 vah1 = *(const uint4*)&Ah[ga + 8];
        const uint4 val0 = *(const uint4*)&Al[ga];
        const uint4 val1 = *(const uint4*)&Al[ga + 8];
        const uint4 vbh0 = *(const uint4*)&Bh[gb];
        const uint4 vbh1 = *(const uint4*)&Bh[gb + 8];
        const uint4 vbl0 = *(const uint4*)&Bl[gb];
        const uint4 vbl1 = *(const uint4*)&Bl[gb + 8];
        __syncthreads();
        const int so = srow * 32 + sk;
        *(uint4*)&As[0][so] = vah0;  *(uint4*)&As[0][so + 8] = vah1;
        *(uint4*)&As[1][so] = val0;  *(uint4*)&As[1][so + 8] = val1;
        *(uint4*)&Bs[0][so] = vbh0;  *(uint4*)&Bs[0][so + 8] = vbh1;
        *(uint4*)&Bs[1][so] = vbl0;  *(uint4*)&Bs[1][so + 8] = vbl1;
        __syncthreads();

        bf16x8 a_h[4], a_l[4], b_h[4], b_l[4];
#pragma unroll
        for (int mt = 0; mt < 4; ++mt) {
            const int r = wm * 64 + mt * 16 + lr;
            a_h[mt] = *(const bf16x8*)&As[0][r * 32 + lk];
            a_l[mt] = *(const bf16x8*)&As[1][r * 32 + lk];
        }
#pragma unroll
        for (int nt = 0; nt < 4; ++nt) {
            const int c = wn * 64 + nt * 16 + lr;
            b_h[nt] = *(const bf16x8*)&Bs[0][c * 32 + lk];
            b_l[nt] = *(const bf16x8*)&Bs[1][c * 32 + lk];
        }
#pragma unroll
        for (int mt = 0; mt < 4; ++mt)
#pragma unroll
            for (int nt = 0; nt < 4; ++nt) {
                acc[mt][nt] = __builtin_amdgcn_mfma_f32_16x16x32_bf16(a_h[mt], b_h[nt], acc[mt][nt], 0, 0, 0);
                acc[mt][nt] = __builtin_amdgcn_mfma_f32_16x16x32_bf16(a_h[mt], b_l[nt], acc[mt][nt], 0, 0, 0);
                acc[mt][nt] = __builtin_amdgcn_mfma_f32_16x16x32_bf16(a_l[mt], b_h[nt], acc[mt][nt], 0, 0, 0);
            }
    }

    const int crow = (lane >> 4) * 4;
#pragma unroll
    for (int mt = 0; mt < 4; ++mt)
#pragma unroll
        for (int nt = 0; nt < 4; ++nt) {
            const int cc = col0 + wn * 64 + nt * 16 + lr;
            if (cc < N) {
#pragma unroll
                for (int r = 0; r < 4; ++r)
                    C[(size_t)(row0 + wm * 64 + mt * 16 + crow + r) * ldc + cc] = acc[mt][nt][r];
            }
        }
}

// ---------------------------------------------------------------------------
// Depthwise causal conv (4 taps) + bias + SiLU + dt/dA precompute. (unchanged)
// ---------------------------------------------------------------------------
__global__ __launch_bounds__(320)
void conv_kernel(const float* __restrict__ zx,
                 const float* __restrict__ cw,
                 const float* __restrict__ cb,
                 const float* __restrict__ dtbias,
                 const float* __restrict__ alog,
                 float* __restrict__ xh,
                 float* __restrict__ Bb,
                 float* __restrict__ Cb,
                 float* __restrict__ dtb,
                 float* __restrict__ dAb)
{
    const int row = blockIdx.x;
    const int l   = row & (SEQ - 1);
    const int c4  = threadIdx.x * 4;

    float4 acc = *(const float4*)&cb[c4];
#pragma unroll
    for (int k = 0; k < DCONV; ++k) {
        const int lk = l - (DCONV - 1) + k;
        if (lk >= 0) {
            const float4 v = *(const float4*)&zx[(size_t)(row - (DCONV - 1) + k) * DINPROJ + DINNER + c4];
            const float4 w = *(const float4*)&cw[k * CONVDIM + c4];
            acc.x = fmaf(v.x, w.x, acc.x);
            acc.y = fmaf(v.y, w.y, acc.y);
            acc.z = fmaf(v.z, w.z, acc.z);
            acc.w = fmaf(v.w, w.w, acc.w);
        }
    }
    acc.x = silu_f(acc.x);
    acc.y = silu_f(acc.y);
    acc.z = silu_f(acc.z);
    acc.w = silu_f(acc.w);

    if (c4 < DINNER) {
        *(float4*)&xh[(size_t)row * DINNER + c4] = acc;
    } else if (c4 < DINNER + DSTATE) {
        *(float4*)&Bb[(size_t)row * DSTATE + (c4 - DINNER)] = acc;
    } else {
        *(float4*)&Cb[(size_t)row * DSTATE + (c4 - DINNER - DSTATE)] = acc;
    }

    if (threadIdx.x < NHEADS) {
        const int hh = threadIdx.x;
        const float raw = zx[(size_t)row * DINPROJ + (DINNER + CONVDIM) + hh] + dtbias[hh];
        const float dtv = (raw > 20.0f) ? raw : log1pf(expf(raw));
        const float a = expf(alog[hh]);
        dtb[row * NHEADS + hh] = dtv;
        dAb[row * NHEADS + hh] = expf(-a * dtv);
    }
}

// ---------------------------------------------------------------------------
// meta: per (b,h,chunk) wave: l[t] = inclusive cumsum(-a*dt); w; ptot.
// ---------------------------------------------------------------------------
__global__ __launch_bounds__(64)
void meta_kernel(const float* __restrict__ dtb,
                 const float* __restrict__ alog,
                 float* __restrict__ lB, float* __restrict__ wB,
                 float* __restrict__ ptot)
{
    const int bhc = blockIdx.x;
    const int chunk = bhc & 31;
    const int h = (bhc >> 5) & 15;
    const int b = bhc >> 9;
    const int t = threadIdx.x;
    const size_t row0 = (size_t)b * SEQ + (size_t)chunk * TSEG;

    const float a = __expf(alog[h]);
    const float dtv = dtb[(row0 + t) * NHEADS + h];
    float v = -a * dtv;
#pragma unroll
    for (int off = 1; off < 64; off <<= 1) {
        const float u = __shfl_up(v, off, 64);
        if (t >= off) v += u;
    }
    const float l63 = __shfl(v, 63, 64);
    lB[(size_t)bhc * 64 + t] = v;
    wB[(size_t)bhc * 64 + t] = __expf(l63 - v) * dtv;
    if (t == 0) ptot[bhc] = __expf(l63);
}

// ---------------------------------------------------------------------------
// cb: CB[t][s] = C_chunk @ B_chunk^T per (b,chunk). grid=128, 256 thr.
// ---------------------------------------------------------------------------
__global__ __launch_bounds__(256)
void cb_kernel(const unsigned short* __restrict__ Ch,
               const unsigned short* __restrict__ Cl,
               const unsigned short* __restrict__ Bh_,
               const unsigned short* __restrict__ Bl_,
               float* __restrict__ CBo)
{
    __shared__ __align__(16) unsigned short Cs[2][64 * 128];
    __shared__ __align__(16) unsigned short Bs2[2][64 * 128];
    const int bc = blockIdx.x;
    const size_t base = (size_t)bc * 8192;
    const int tid = threadIdx.x;
#pragma unroll
    for (int i = 0; i < 4; ++i) {           // FIX: 1024 uint4 per plane
        const int s = tid + i * 256;
        ((uint4*)Cs[0])[s]  = ((const uint4*)(Ch  + base))[s];
        ((uint4*)Cs[1])[s]  = ((const uint4*)(Cl  + base))[s];
        ((uint4*)Bs2[0])[s] = ((const uint4*)(Bh_ + base))[s];
        ((uint4*)Bs2[1])[s] = ((const uint4*)(Bl_ + base))[s];
    }
    __syncthreads();

    const int w = tid >> 6, lane = tid & 63;
    const int lr = lane & 15, lk = (lane >> 4) * 8;
    f32x4 acc[4];
#pragma unroll
    for (int i = 0; i < 4; ++i) acc[i] = (f32x4){0.f, 0.f, 0.f, 0.f};

#pragma unroll
    for (int kk = 0; kk < 4; ++kk) {
        const int k0 = kk * 32;
        const bf16x8 ah = *(const bf16x8*)&Cs[0][(w * 16 + lr) * 128 + k0 + lk];
        const bf16x8 al = *(const bf16x8*)&Cs[1][(w * 16 + lr) * 128 + k0 + lk];
#pragma unroll
        for (int st = 0; st < 4; ++st) {
            const bf16x8 bh = *(const bf16x8*)&Bs2[0][(st * 16 + lr) * 128 + k0 + lk];
            const bf16x8 bl = *(const bf16x8*)&Bs2[1][(st * 16 + lr) * 128 + k0 + lk];
            acc[st] = __builtin_amdgcn_mfma_f32_16x16x32_bf16(ah, bh, acc[st], 0, 0, 0);
            acc[st] = __builtin_amdgcn_mfma_f32_16x16x32_bf16(ah, bl, acc[st], 0, 0, 0);
            acc[st] = __builtin_amdgcn_mfma_f32_16x16x32_bf16(al, bh, acc[st], 0, 0, 0);
        }
    }
    const int crow = (lane >> 4) * 4;
#pragma unroll
    for (int st = 0; st < 4; ++st)
#pragma unroll
        for (int r = 0; r < 4; ++r)
            CBo[(size_t)bc * 4096 + (size_t)(w * 16 + crow + r) * 64 + st * 16 + lr] = acc[st][r];
}

// ---------------------------------------------------------------------------
// state: S[n][p] = sum_t (B[t,n]*w[t]) * x[t,p] per (b,h,chunk) -> hloc
// ---------------------------------------------------------------------------
__global__ __launch_bounds__(256)
void state_kernel(const unsigned short* __restrict__ BTh,
                  const unsigned short* __restrict__ BTl,
                  const float* __restrict__ xh,
                  const float* __restrict__ wB,
                  float* __restrict__ hloc)
{
    __shared__ __align__(16) unsigned short BTs[2][128 * 64];
    __shared__ float xsf[64 * 65];
    __shared__ __align__(16) unsigned short xwT[2][64 * 64];
    __shared__ float wsl[64];

    const int bhc = blockIdx.x;
    const int chunk = bhc & 31;
    const int h = (bhc >> 5) & 15;
    const int b = bhc >> 9;
    const int bc = b * 32 + chunk;
    const size_t row0 = (size_t)b * SEQ + (size_t)chunk * TSEG;
    const int tid = threadIdx.x;

    const size_t bbase = (size_t)bc * 8192;
#pragma unroll
    for (int i = 0; i < 4; ++i) {
        const int s = tid + i * 256;
        ((uint4*)BTs[0])[s] = ((const uint4*)(BTh + bbase))[s];
        ((uint4*)BTs[1])[s] = ((const uint4*)(BTl + bbase))[s];
    }
#pragma unroll
    for (int i = 0; i < 4; ++i) {
        const int l4 = tid + i * 256;           // 0..1023
        const int s = l4 >> 4, c4 = (l4 & 15) * 4;
        const float4 v = *(const float4*)&xh[(row0 + s) * DINNER + h * HEADDIM + c4];
        xsf[s * 65 + c4 + 0] = v.x;
        xsf[s * 65 + c4 + 1] = v.y;
        xsf[s * 65 + c4 + 2] = v.z;
        xsf[s * 65 + c4 + 3] = v.w;
    }
    if (tid < 64) wsl[tid] = wB[(size_t)bhc * 64 + tid];
    __syncthreads();

    {
        const int t = tid & 63;
        const int pb = (tid >> 6) * 16;
#pragma unroll
        for (int i = 0; i < 16; ++i) {
            const int p = pb + i;
            const float v = xsf[t * 65 + p] * wsl[t];
            const unsigned short hh = f2bfu(v);
            xwT[0][p * 64 + t] = hh;
            xwT[1][p * 64 + t] = f2bfu(v - bfu2f(hh));
        }
    }
    __syncthreads();

    const int w = tid >> 6, lane = tid & 63;
    const int lr = lane & 15, lk = (lane >> 4) * 8;
    f32x4 acc[2][4];
#pragma unroll
    for (int i = 0; i < 2; ++i)
#pragma unroll
        for (int j = 0; j < 4; ++j) acc[i][j] = (f32x4){0.f, 0.f, 0.f, 0.f};

#pragma unroll
    for (int kk = 0; kk < 2; ++kk) {
        const int k0 = kk * 32;
        bf16x8 ah[2], al[2];
#pragma unroll
        for (int nt = 0; nt < 2; ++nt) {
            const int n = w * 32 + nt * 16 + lr;
            ah[nt] = *(const bf16x8*)&BTs[0][n * 64 + k0 + lk];
            al[nt] = *(const bf16x8*)&BTs[1][n * 64 + k0 + lk];
        }
#pragma unroll
        for (int pt = 0; pt < 4; ++pt) {
            const bf16x8 bh = *(const bf16x8*)&xwT[0][(pt * 16 + lr) * 64 + k0 + lk];
            const bf16x8 bl = *(const bf16x8*)&xwT[1][(pt * 16 + lr) * 64 + k0 + lk];
#pragma unroll
            for (int nt = 0; nt < 2; ++nt) {
                acc[nt][pt] = __builtin_amdgcn_mfma_f32_16x16x32_bf16(ah[nt], bh, acc[nt][pt], 0, 0, 0);
                acc[nt][pt] = __builtin_amdgcn_mfma_f32_16x16x32_bf16(ah[nt], bl, acc[nt][pt], 0, 0, 0);
                acc[nt][pt] = __builtin_amdgcn_mfma_f32_16x16x32_bf16(al[nt], bh, acc[nt][pt], 0, 0, 0);
            }
        }
    }

    const int crow = (lane >> 4) * 4;
#pragma unroll
    for (int nt = 0; nt < 2; ++nt)
#pragma unroll
        for (int pt = 0; pt < 4; ++pt)
#pragma unroll
            for (int r = 0; r < 4; ++r) {
                const int n = w * 32 + nt * 16 + crow + r;
                hloc[(size_t)bhc * 8192 + (size_t)n * 64 + pt * 16 + lr] = acc[nt][pt][r];
            }
}

// ---------------------------------------------------------------------------
// combine: sequential over 32 chunks (in-place: hloc becomes h0). (unchanged)
// ---------------------------------------------------------------------------
__global__ __launch_bounds__(256)
void combine_kernel(float* __restrict__ hloc,
                    const float* __restrict__ ptot)
{
    const int bid = blockIdx.x;
    const int bh = bid >> 3;
    const int chunk = bid & 7;
    const int e0 = chunk * 1024 + threadIdx.x * 4;

    float4 s = make_float4(0.f, 0.f, 0.f, 0.f);
    for (int k = 0; k < NSEG; ++k) {
        float* p = &hloc[((size_t)bh * NSEG + k) * (DSTATE * HEADDIM) + e0];
        const float4 v = *(const float4*)p;
        *(float4*)p = s;
        const float pt = ptot[bh * NSEG + k];
        s.x = fmaf(pt, s.x, v.x);
        s.y = fmaf(pt, s.y, v.y);
        s.z = fmaf(pt, s.z, v.z);
        s.w = fmaf(pt, s.w, v.w);
    }
}

// ---------------------------------------------------------------------------
// y: per (b,chunk,headgroup-of-4), 512 thr. For each head (sequential):
//   acc  = C @ h0  (K=128), rows scaled by exp(l[t])
//   acc += M @ x   (K=64), M[t,s] = CB[t,s]*dt[s]*exp(l[t]-l[s])*[s<=t]
// ---------------------------------------------------------------------------
__global__ __launch_bounds__(512)
void y_kernel(const unsigned short* __restrict__ Ch,
              const unsigned short* __restrict__ Cl,
              const float* __restrict__ CBg,
              const float* __restrict__ lB,
              const float* __restrict__ dtb,
              const float* __restrict__ xh,
              const float* __restrict__ hloc,
              float* __restrict__ yb)
{
    __shared__ __align__(16) unsigned short CsA[2][64 * 128];  // C [t][n]
    __shared__ float scr[128 * 65];                            // padded scratch
    __shared__ __align__(16) unsigned short opB[2][64 * 128];  // phaseA h0T / phaseB xT
    __shared__ __align__(16) unsigned short Ms[2][64 * 64];    // M [t][s]
    __shared__ float ls4[256], dt4[256];

    const int gid = blockIdx.x;
    const int hg = gid & 3, bc = gid >> 2;
    const int chunk = bc & 31, b = bc >> 5;
    const size_t row0 = (size_t)b * SEQ + (size_t)chunk * TSEG;
    const int tid = threadIdx.x;

    const size_t cbase = (size_t)bc * 8192;
    ((uint4*)CsA[0])[tid]       = ((const uint4*)(Ch + cbase))[tid];         // FIX:
    ((uint4*)CsA[0])[tid + 512] = ((const uint4*)(Ch + cbase))[tid + 512];   //  full
    ((uint4*)CsA[1])[tid]       = ((const uint4*)(Cl + cbase))[tid];         //  1024
    ((uint4*)CsA[1])[tid + 512] = ((const uint4*)(Cl + cbase))[tid + 512];   //  uint4
    if (tid < 256) {
        const int e = tid >> 6, t = tid & 63;
        const int h = hg * 4 + e;
        const int bhc = (b * NHEADS + h) * NSEG + chunk;
        ls4[tid] = lB[(size_t)bhc * 64 + t];
        dt4[tid] = dtb[(row0 + t) * NHEADS + h];
    }
    __syncthreads();

    const int w = tid >> 6, lane = tid & 63;
    const int lr = lane & 15, lk = (lane >> 4) * 8;
    const int tt = w & 3, ph = w >> 2;
    const int crow = (lane >> 4) * 4;
    const float* CBc = CBg + (size_t)bc * 4096;

    for (int e = 0; e < 4; ++e) {
        const int h = hg * 4 + e;
        const int bhc = (b * NHEADS + h) * NSEG + chunk;
        const float* h0p = hloc + (size_t)bhc * 8192;

        // stage h0 (n-major [128][64]) into padded scr
#pragma unroll
        for (int i = 0; i < 4; ++i) {
            const int l4 = tid + i * 512;      // 0..2047
            const int n = l4 >> 4, c4 = (l4 & 15) * 4;
            const float4 v = *(const float4*)&h0p[(size_t)l4 * 4];
            scr[n * 65 + c4 + 0] = v.x;
            scr[n * 65 + c4 + 1] = v.y;
            scr[n * 65 + c4 + 2] = v.z;
            scr[n * 65 + c4 + 3] = v.w;
        }
        __syncthreads();

        // transpose-split h0 -> opB [p][n] (k=n contig)
        {
            const int n = tid & 127;
            const int pb = (tid >> 7) * 4;
#pragma unroll
            for (int i = 0; i < 16; ++i) {
                const int p = pb + (i & 3) + (i >> 2) * 16;
                const float v = scr[n * 65 + p];
                const unsigned short hh = f2bfu(v);
                opB[0][p * 128 + n] = hh;
                opB[1][p * 128 + n] = f2bfu(v - bfu2f(hh));
            }
        }
        __syncthreads();

        // MFMA phase A: acc = C @ h0  (K=128)
        f32x4 acc[2];
        acc[0] = (f32x4){0.f, 0.f, 0.f, 0.f};
        acc[1] = (f32x4){0.f, 0.f, 0.f, 0.f};
#pragma unroll
        for (int kk = 0; kk < 4; ++kk) {
            const int k0 = kk * 32;
            const bf16x8 ah = *(const bf16x8*)&CsA[0][(tt * 16 + lr) * 128 + k0 + lk];
            const bf16x8 al = *(const bf16x8*)&CsA[1][(tt * 16 + lr) * 128 + k0 + lk];
#pragma unroll
            for (int pt = 0; pt < 2; ++pt) {
                const int pc = (ph * 2 + pt) * 16 + lr;
                const bf16x8 bh = *(const bf16x8*)&opB[0][pc * 128 + k0 + lk];
                const bf16x8 bl = *(const bf16x8*)&opB[1][pc * 128 + k0 + lk];
                acc[pt] = __builtin_amdgcn_mfma_f32_16x16x32_bf16(ah, bh, acc[pt], 0, 0, 0);
                acc[pt] = __builtin_amdgcn_mfma_f32_16x16x32_bf16(ah, bl, acc[pt], 0, 0, 0);
                acc[pt] = __builtin_amdgcn_mfma_f32_16x16x32_bf16(al, bh, acc[pt], 0, 0, 0);
            }
        }
        // row scale by exp(l[t])
        {
            float el[4];
#pragma unroll
            for (int r = 0; r < 4; ++r) el[r] = __expf(ls4[e * 64 + tt * 16 + crow + r]);
#pragma unroll
            for (int pt = 0; pt < 2; ++pt)
#pragma unroll
                for (int r = 0; r < 4; ++r) acc[pt][r] *= el[r];
        }

        // stage x [64s][64p] into scr  +  form M hi/lo
#pragma unroll
        for (int i = 0; i < 2; ++i) {
            const int l4 = tid + i * 512;      // 0..1023
            const int s = l4 >> 4, c4 = (l4 & 15) * 4;
            const float4 v = *(const float4*)&xh[(row0 + s) * DINNER + h * HEADDIM + c4];
            scr[s * 65 + c4 + 0] = v.x;
            scr[s * 65 + c4 + 1] = v.y;
            scr[s * 65 + c4 + 2] = v.z;
            scr[s * 65 + c4 + 3] = v.w;
        }
#pragma unroll
        for (int i = 0; i < 8; ++i) {
            const int lin = tid * 8 + i;
            const int t = lin >> 6, s = lin & 63;
            float m = 0.0f;
            if (s <= t)
                m = CBc[t * 64 + s] * dt4[e * 64 + s] * __expf(ls4[e * 64 + t] - ls4[e * 64 + s]);
            const unsigned short mh = f2bfu(m);
            Ms[0][t * 64 + s] = mh;
            Ms[1][t * 64 + s] = f2bfu(m - bfu2f(mh));
        }
        __syncthreads();

        // transpose-split x -> opB [p][s] (k=s contig, stride 64)
        {
            const int s = tid & 63;
            const int pb = (tid >> 6) * 8;
#pragma unroll
            for (int i = 0; i < 8; ++i) {
                const int p = pb + i;
                const float v = scr[s * 65 + p];
                const unsigned short hh = f2bfu(v);
                opB[0][p * 64 + s] = hh;
                opB[1][p * 64 + s] = f2bfu(v - bfu2f(hh));
            }
        }
        __syncthreads();

        // MFMA phase B: acc += M @ x  (K=64)
#pragma unroll
        for (int kk = 0; kk < 2; ++kk) {
            const int k0 = kk * 32;
            const bf16x8 ah = *(const bf16x8*)&Ms[0][(tt * 16 + lr) * 64 + k0 + lk];
            const bf16x8 al = *(const bf16x8*)&Ms[1][(tt * 16 + lr) * 64 + k0 + lk];
#pragma unroll
            for (int pt = 0; pt < 2; ++pt) {
                const int pc = (ph * 2 + pt) * 16 + lr;
                const bf16x8 bh = *(const bf16x8*)&opB[0][pc * 64 + k0 + lk];
                const bf16x8 bl = *(const bf16x8*)&opB[1][pc * 64 + k0 + lk];
                acc[pt] = __builtin_amdgcn_mfma_f32_16x16x32_bf16(ah, bh, acc[pt], 0, 0, 0);
                acc[pt] = __builtin_amdgcn_mfma_f32_16x16x32_bf16(ah, bl, acc[pt], 0, 0, 0);
                acc[pt] = __builtin_amdgcn_mfma_f32_16x16x32_bf16(al, bh, acc[pt], 0, 0, 0);
            }
        }

        // write y
#pragma unroll
        for (int pt = 0; pt < 2; ++pt)
#pragma unroll
            for (int r = 0; r < 4; ++r)
                yb[(row0 + tt * 16 + crow + r) * DINNER + h * HEADDIM + (ph * 2 + pt) * 16 + lr] = acc[pt][r];
        __syncthreads();
    }
}

// ---------------------------------------------------------------------------
// Gate + D-skip + RMSNorm; writes ynorm as split-bf16 planes. (unchanged)
// ---------------------------------------------------------------------------
__global__ __launch_bounds__(256)
void gate_kernel(const float* __restrict__ yb,
                 const float* __restrict__ xh,
                 const float* __restrict__ dskip,
                 const float* __restrict__ zx,
                 const float* __restrict__ nw,
                 unsigned short* __restrict__ yh,
                 unsigned short* __restrict__ yl)
{
    const int row = blockIdx.x;
    const int c4 = threadIdx.x * 4;

    float4 y = *(const float4*)&yb[(size_t)row * DINNER + c4];
    const float4 xv = *(const float4*)&xh[(size_t)row * DINNER + c4];
    const float dsk = dskip[c4 >> 6];
    y.x = fmaf(dsk, xv.x, y.x);
    y.y = fmaf(dsk, xv.y, y.y);
    y.z = fmaf(dsk, xv.z, y.z);
    y.w = fmaf(dsk, xv.w, y.w);

    const float4 z = *(const float4*)&zx[(size_t)row * DINPROJ + c4];
    float4 g;
    g.x = y.x * silu_f(z.x);
    g.y = y.y * silu_f(z.y);
    g.z = y.z * silu_f(z.z);
    g.w = y.w * silu_f(z.w);

    float local = g.x * g.x + g.y * g.y + g.z * g.z + g.w * g.w;
#pragma unroll
    for (int m = 32; m >= 1; m >>= 1) local += __shfl_xor(local, m, 64);

    __shared__ float red[4];
    if ((threadIdx.x & 63) == 0) red[threadIdx.x >> 6] = local;
    __syncthreads();
    const float total = red[0] + red[1] + red[2] + red[3];
    const float scale = rsqrtf(total * (1.0f / (float)DINNER) + 1e-5f);

    const float4 w = *(const float4*)&nw[c4];
    float o[4];
    o[0] = g.x * scale * w.x;
    o[1] = g.y * scale * w.y;
    o[2] = g.z * scale * w.z;
    o[3] = g.w * scale * w.w;

    unsigned hv[4], lv[4];
#pragma unroll
    for (int j = 0; j < 4; ++j) {
        hv[j] = f2bfu(o[j]);
        lv[j] = f2bfu(o[j] - bfu2f((unsigned short)hv[j]));
    }
    const size_t oi = (size_t)row * DINNER + c4;
    *(uint2*)&yh[oi] = make_uint2(hv[0] | (hv[1] << 16), hv[2] | (hv[3] << 16));
    *(uint2*)&yl[oi] = make_uint2(lv[0] | (lv[1] << 16), lv[2] | (lv[3] << 16));
}

// ---------------------------------------------------------------------------
extern "C" void kernel_launch(void* const* d_in, const int* in_sizes, int n_in,
                              void* d_out, int out_size, void* d_ws, size_t ws_size,
                              hipStream_t stream)
{
    const float* x_in    = (const float*)d_in[0];
    const float* in_w    = (const float*)d_in[1];
    const float* conv_w  = (const float*)d_in[2];
    const float* conv_b  = (const float*)d_in[3];
    const float* dt_bias = (const float*)d_in[4];
    const float* A_log   = (const float*)d_in[5];
    const float* D_skip  = (const float*)d_in[6];
    const float* norm_w  = (const float*)d_in[7];
    const float* out_w   = (const float*)d_in[8];
    float* out = (float*)d_out;

    float* ws   = (float*)d_ws;
    float* zx   = ws;                               // 19,005,440 f
    float* xh   = zx   + (size_t)ROWS * DINPROJ;    //  8,388,608 f
    float* Bb   = xh   + (size_t)ROWS * DINNER;     //  1,048,576 f
    float* Cb   = Bb   + (size_t)ROWS * DSTATE;     //  1,048,576 f
    float* dtb  = Cb   + (size_t)ROWS * DSTATE;     //    131,072 f
    float* dAb  = dtb  + (size_t)ROWS * NHEADS;     //    131,072 f
    float* yb   = dAb  + (size_t)ROWS * NHEADS;     //  8,388,608 f
    float* UN   = yb   + (size_t)ROWS * DINNER;     // 16,777,216 f (union)
    float* BtF  = UN   + (size_t)16777216;          //  1,245,184 f
    float* WtF  = BtF  + (size_t)1245184;           //    524,288 f
    float* ptot = WtF  + (size_t)524288;            //      2,048 f
    float* lB   = ptot + (size_t)2048;              //    131,072 f
    float* wB   = lB   + (size_t)131072;            //    131,072 f
    float* BTf  = wB   + (size_t)131072;            //  1,048,576 f (bf16 x2 planes)
    float* Bspf = BTf  + (size_t)1048576;           //  1,048,576 f
    float* Cspf = Bspf + (size_t)1048576;           //  1,048,576 f
    float* CBb  = Cspf + (size_t)1048576;           //    524,288 f
    // total 60,622,848 f = 242.5 MB

    unsigned short* Ah = (unsigned short*)UN;                 // [8192][512]
    unsigned short* Al = Ah + (size_t)ROWS * DMODEL;
    float*          hloc = UN;                                // 16.78M f
    unsigned short* yh = (unsigned short*)UN;                 // [8192][1024]
    unsigned short* yl = yh + (size_t)ROWS * DINNER;

    unsigned short* Bth = (unsigned short*)BtF;               // [2432][512]
    unsigned short* Btl = Bth + (size_t)NPAD_IN * DMODEL;
    unsigned short* Wth = (unsigned short*)WtF;               // [512][1024]
    unsigned short* Wtl = Wth + (size_t)DMODEL * DINNER;

    unsigned short* BTh = (unsigned short*)BTf;               // [128][128][64]
    unsigned short* BTl = BTh + (size_t)128 * 8192;
    unsigned short* Bsph = (unsigned short*)Bspf;             // [8192][128]
    unsigned short* Bspl = Bsph + (size_t)ROWS * DSTATE;
    unsigned short* Csph = (unsigned short*)Cspf;             // [8192][128]
    unsigned short* Cspl = Csph + (size_t)ROWS * DSTATE;

    for (int layer = 0; layer < 2; ++layer) {
        const float* xl = (layer == 0) ? x_in : out;

        split_a_kernel<<<(ROWS * DMODEL) / (256 * 8), 256, 0, stream>>>(xl, Ah, Al);

        tsplit_w_kernel<<<dim3(NPAD_IN / 32, DMODEL / 32), 256, 0, stream>>>(
            in_w + (size_t)layer * DMODEL * DINPROJ, DMODEL, DINPROJ, Bth, Btl);

        gemm_bf16s<<<dim3(NPAD_IN / 128, ROWS / 128), 256, 0, stream>>>(
            Ah, Al, Bth, Btl, zx, DINPROJ, DINPROJ, DMODEL);

        conv_kernel<<<ROWS, CONVDIM / 4, 0, stream>>>(
            zx,
            conv_w + (size_t)layer * DCONV * CONVDIM,
            conv_b + (size_t)layer * CONVDIM,
            dt_bias + (size_t)layer * NHEADS,
            A_log + (size_t)layer * NHEADS,
            xh, Bb, Cb, dtb, dAb);

        meta_kernel<<<BATCH * NHEADS * NSEG, 64, 0, stream>>>(
            dtb, A_log + (size_t)layer * NHEADS, lB, wB, ptot);

        split_a_kernel<<<(ROWS * DSTATE) / (256 * 8), 256, 0, stream>>>(Bb, Bsph, Bspl);
        split_a_kernel<<<(ROWS * DSTATE) / (256 * 8), 256, 0, stream>>>(Cb, Csph, Cspl);

        tsplit_chunk_kernel<<<dim3(128 / 32, 64 / 32, BATCH * NSEG), 256, 0, stream>>>(
            Bb, TSEG, DSTATE, DSTATE, (size_t)TSEG * DSTATE, BTh, BTl);

        cb_kernel<<<BATCH * NSEG, 256, 0, stream>>>(Csph, Cspl, Bsph, Bspl, CBb);

        state_kernel<<<BATCH * NHEADS * NSEG, 256, 0, stream>>>(
            BTh, BTl, xh, wB, hloc);

        combine_kernel<<<BATCH * NHEADS * 8, 256, 0, stream>>>(hloc, ptot);

        y_kernel<<<BATCH * NSEG * 4, 512, 0, stream>>>(
            Csph, Cspl, CBb, lB, dtb, xh, hloc, yb);

        gate_kernel<<<ROWS, 256, 0, stream>>>(
            yb, xh, D_skip + (size_t)layer * NHEADS,
            zx, norm_w + (size_t)layer * DINNER, yh, yl);

        tsplit_w_kernel<<<dim3(DMODEL / 32, DINNER / 32), 256, 0, stream>>>(
            out_w + (size_t)layer * DINNER * DMODEL, DINNER, DMODEL, Wth, Wtl);

        gemm_bf16s<<<dim3(DMODEL / 128, ROWS / 128), 256, 0, stream>>>(
            yh, yl, Wth, Wtl, out, DMODEL, DMODEL, DINNER);
    }
}

// Round 12
// 581.004 us; speedup vs baseline: 1.3652x; 1.0795x over previous
//
#include <hip/hip_runtime.h>
#include <hip/hip_bf16.h>
#include <cstddef>
#include <cstdint>

// Mamba2 (2 layers). GEMMs via split-bf16 MFMA (C = AhBh + AhBl + AlBh).
// Selective scan via CHUNKED SSD (chunk Q=64): all heavy ops are MFMA.
// Round-12: T2 XOR-swizzle on ALL bf16 LDS tiles (gemm 64B rows: slot^=(r>>1)&3;
// cb/state/y 128/256B rows: slot^=r&7) — kills the 8/16-way bank conflicts
// (gemm measured 9.96M conflict cycles). Math unchanged.

#define BATCH 4
#define SEQ   2048
#define DMODEL 512
#define DINNER 1024
#define DSTATE 128
#define HEADDIM 64
#define NHEADS 16
#define DCONV 4
#define CONVDIM 1280
#define DINPROJ 2320
#define NPAD_IN 2432          // 19 * 128
#define ROWS (BATCH * SEQ)    // 8192
#define NSEG 32               // chunks per sequence
#define TSEG 64               // chunk length

// swizzled index into a [rows][32/64/128]-ushort LDS tile (16B-slot XOR)
#define SWZ32(r, c)  ((r) * 32  + (((((c) >> 3) ^ (((r) >> 1) & 3)) << 3) | ((c) & 7)))
#define SWZ64(r, c)  ((r) * 64  + (((((c) >> 3) ^ ((r) & 7)) << 3) | ((c) & 7)))
#define SWZ128(r, c) ((r) * 128 + (((((c) >> 3) ^ ((r) & 7)) << 3) | ((c) & 7)))

typedef __attribute__((ext_vector_type(8))) short bf16x8;
typedef __attribute__((ext_vector_type(4))) float f32x4;

__device__ __forceinline__ float silu_f(float x) {
    return x * (1.0f / (1.0f + __expf(-x)));
}
__device__ __forceinline__ unsigned short f2bfu(float f) {  // RNE fp32->bf16
    unsigned u = __float_as_uint(f);
    unsigned r = u + 0x7FFFu + ((u >> 16) & 1u);
    return (unsigned short)(r >> 16);
}
__device__ __forceinline__ float bfu2f(unsigned short h) {
    return __uint_as_float(((unsigned)h) << 16);
}

// ---------------------------------------------------------------------------
// Split fp32 flat array -> hi/lo bf16. 8 elems/thread.
// ---------------------------------------------------------------------------
__global__ __launch_bounds__(256)
void split_a_kernel(const float* __restrict__ A,
                    unsigned short* __restrict__ Ah,
                    unsigned short* __restrict__ Al)
{
    const size_t i = ((size_t)blockIdx.x * 256 + threadIdx.x) * 8;
    const float4 a = *(const float4*)&A[i];
    const float4 b = *(const float4*)&A[i + 4];
    float v[8] = {a.x, a.y, a.z, a.w, b.x, b.y, b.z, b.w};
    unsigned hv[8], lv[8];
#pragma unroll
    for (int j = 0; j < 8; ++j) {
        hv[j] = f2bfu(v[j]);
        lv[j] = f2bfu(v[j] - bfu2f((unsigned short)hv[j]));
    }
    uint4 ph = make_uint4(hv[0] | (hv[1] << 16), hv[2] | (hv[3] << 16),
                          hv[4] | (hv[5] << 16), hv[6] | (hv[7] << 16));
    uint4 pl = make_uint4(lv[0] | (lv[1] << 16), lv[2] | (lv[3] << 16),
                          lv[4] | (lv[5] << 16), lv[6] | (lv[7] << 16));
    *(uint4*)&Ah[i] = ph;
    *(uint4*)&Al[i] = pl;
}

// ---------------------------------------------------------------------------
// Transpose + split weight W[K][N] fp32 -> Oh/Ol[Npad][K] bf16 (n >= N -> 0).
// ---------------------------------------------------------------------------
__global__ __launch_bounds__(256)
void tsplit_w_kernel(const float* __restrict__ W, int K, int N,
                     unsigned short* __restrict__ Oh,
                     unsigned short* __restrict__ Ol)
{
    __shared__ float tile[32][33];
    const int n0 = blockIdx.x * 32, k0 = blockIdx.y * 32;
    const int c = threadIdx.x & 31, r8 = threadIdx.x >> 5;
    const int n = n0 + c;
#pragma unroll
    for (int i = 0; i < 4; ++i) {
        const int k = r8 + i * 8;
        float v = 0.0f;
        if (n < N) v = W[(size_t)(k0 + k) * N + n];
        tile[c][k] = v;
    }
    __syncthreads();
#pragma unroll
    for (int i = 0; i < 4; ++i) {
        const int nl = r8 + i * 8;
        const float v = tile[nl][c];
        const unsigned short h = f2bfu(v);
        const unsigned short l = f2bfu(v - bfu2f(h));
        const size_t o = (size_t)(n0 + nl) * K + k0 + c;
        Oh[o] = h;
        Ol[o] = l;
    }
}

// ---------------------------------------------------------------------------
// Chunked transpose+split: per z, fp32 [K][N] (rowstride rs) -> bf16 [N][K].
// ---------------------------------------------------------------------------
__global__ __launch_bounds__(256)
void tsplit_chunk_kernel(const float* __restrict__ src, int K, int N, int rs,
                         size_t chunkStride,
                         unsigned short* __restrict__ Oh,
                         unsigned short* __restrict__ Ol)
{
    __shared__ float tile[32][33];
    const int z = blockIdx.z;
    const float* W = src + (size_t)z * chunkStride;
    const int n0 = blockIdx.x * 32, k0 = blockIdx.y * 32;
    const int c = threadIdx.x & 31, r8 = threadIdx.x >> 5;
#pragma unroll
    for (int i = 0; i < 4; ++i) {
        const int k = r8 + i * 8;
        tile[c][k] = W[(size_t)(k0 + k) * rs + n0 + c];
    }
    __syncthreads();
#pragma unroll
    for (int i = 0; i < 4; ++i) {
        const int nl = r8 + i * 8;
        const float v = tile[nl][c];
        const unsigned short h = f2bfu(v);
        const unsigned short l = f2bfu(v - bfu2f(h));
        const size_t o = (size_t)z * N * K + (size_t)(n0 + nl) * K + k0 + c;
        Oh[o] = h;
        Ol[o] = l;
    }
}

// ---------------------------------------------------------------------------
// Split-bf16 MFMA GEMM + T2 swizzle (SWZ32 on 64B rows).
// ---------------------------------------------------------------------------
__global__ __launch_bounds__(256)
void gemm_bf16s(const unsigned short* __restrict__ Ah,
                const unsigned short* __restrict__ Al,
                const unsigned short* __restrict__ Bh,
                const unsigned short* __restrict__ Bl,
                float* __restrict__ C, int ldc, int N, int K)
{
    __shared__ __align__(16) unsigned short As[2][128 * 32];
    __shared__ __align__(16) unsigned short Bs[2][128 * 32];

    const int tid = threadIdx.x;
    const int w = tid >> 6, lane = tid & 63;
    const int wm = w >> 1, wn = w & 1;
    const int row0 = blockIdx.y * 128, col0 = blockIdx.x * 128;

    const int srow = tid >> 1;
    const int sk   = (tid & 1) * 16;

    const int lr = lane & 15;
    const int lk = (lane >> 4) * 8;

    f32x4 acc[4][4];
#pragma unroll
    for (int i = 0; i < 4; ++i)
#pragma unroll
        for (int j = 0; j < 4; ++j) acc[i][j] = (f32x4){0.f, 0.f, 0.f, 0.f};

    const int sw0 = SWZ32(srow, sk);
    const int sw1 = SWZ32(srow, sk + 8);

    for (int k0 = 0; k0 < K; k0 += 32) {
        const size_t ga = (size_t)(row0 + srow) * K + k0 + sk;
        const size_t gb = (size_t)(col0 + srow) * K + k0 + sk;
        const uint4 vah0 = *(const uint4*)&Ah[ga];
        const uint4 vah1 = *(const uint4*)&Ah[ga + 8];
        const uint4 val0 = *(const uint4*)&Al[ga];
        const uint4 val1 = *(const uint4*)&Al[ga + 8];
        const uint4 vbh0 = *(const uint4*)&Bh[gb];
        const uint4 vbh1 = *(const uint4*)&Bh[gb + 8];
        const uint4 vbl0 = *(const uint4*)&Bl[gb];
        const uint4 vbl1 = *(const uint4*)&Bl[gb + 8];
        __syncthreads();
        *(uint4*)&As[0][sw0] = vah0;  *(uint4*)&As[0][sw1] = vah1;
        *(uint4*)&As[1][sw0] = val0;  *(uint4*)&As[1][sw1] = val1;
        *(uint4*)&Bs[0][sw0] = vbh0;  *(uint4*)&Bs[0][sw1] = vbh1;
        *(uint4*)&Bs[1][sw0] = vbl0;  *(uint4*)&Bs[1][sw1] = vbl1;
        __syncthreads();

        bf16x8 a_h[4], a_l[4], b_h[4], b_l[4];
#pragma unroll
        for (int mt = 0; mt < 4; ++mt) {
            const int r = wm * 64 + mt * 16 + lr;
            a_h[mt] = *(const bf16x8*)&As[0][SWZ32(r, lk)];
            a_l[mt] = *(const bf16x8*)&As[1][SWZ32(r, lk)];
        }
#pragma unroll
        for (int nt = 0; nt < 4; ++nt) {
            const int c = wn * 64 + nt * 16 + lr;
            b_h[nt] = *(const bf16x8*)&Bs[0][SWZ32(c, lk)];
            b_l[nt] = *(const bf16x8*)&Bs[1][SWZ32(c, lk)];
        }
#pragma unroll
        for (int mt = 0; mt < 4; ++mt)
#pragma unroll
            for (int nt = 0; nt < 4; ++nt) {
                acc[mt][nt] = __builtin_amdgcn_mfma_f32_16x16x32_bf16(a_h[mt], b_h[nt], acc[mt][nt], 0, 0, 0);
                acc[mt][nt] = __builtin_amdgcn_mfma_f32_16x16x32_bf16(a_h[mt], b_l[nt], acc[mt][nt], 0, 0, 0);
                acc[mt][nt] = __builtin_amdgcn_mfma_f32_16x16x32_bf16(a_l[mt], b_h[nt], acc[mt][nt], 0, 0, 0);
            }
    }

    const int crow = (lane >> 4) * 4;
#pragma unroll
    for (int mt = 0; mt < 4; ++mt)
#pragma unroll
        for (int nt = 0; nt < 4; ++nt) {
            const int cc = col0 + wn * 64 + nt * 16 + lr;
            if (cc < N) {
#pragma unroll
                for (int r = 0; r < 4; ++r)
                    C[(size_t)(row0 + wm * 64 + mt * 16 + crow + r) * ldc + cc] = acc[mt][nt][r];
            }
        }
}

// ---------------------------------------------------------------------------
// Depthwise causal conv (4 taps) + bias + SiLU + dt/dA precompute. (unchanged)
// ---------------------------------------------------------------------------
__global__ __launch_bounds__(320)
void conv_kernel(const float* __restrict__ zx,
                 const float* __restrict__ cw,
                 const float* __restrict__ cb,
                 const float* __restrict__ dtbias,
                 const float* __restrict__ alog,
                 float* __restrict__ xh,
                 float* __restrict__ Bb,
                 float* __restrict__ Cb,
                 float* __restrict__ dtb,
                 float* __restrict__ dAb)
{
    const int row = blockIdx.x;
    const int l   = row & (SEQ - 1);
    const int c4  = threadIdx.x * 4;

    float4 acc = *(const float4*)&cb[c4];
#pragma unroll
    for (int k = 0; k < DCONV; ++k) {
        const int lk = l - (DCONV - 1) + k;
        if (lk >= 0) {
            const float4 v = *(const float4*)&zx[(size_t)(row - (DCONV - 1) + k) * DINPROJ + DINNER + c4];
            const float4 w = *(const float4*)&cw[k * CONVDIM + c4];
            acc.x = fmaf(v.x, w.x, acc.x);
            acc.y = fmaf(v.y, w.y, acc.y);
            acc.z = fmaf(v.z, w.z, acc.z);
            acc.w = fmaf(v.w, w.w, acc.w);
        }
    }
    acc.x = silu_f(acc.x);
    acc.y = silu_f(acc.y);
    acc.z = silu_f(acc.z);
    acc.w = silu_f(acc.w);

    if (c4 < DINNER) {
        *(float4*)&xh[(size_t)row * DINNER + c4] = acc;
    } else if (c4 < DINNER + DSTATE) {
        *(float4*)&Bb[(size_t)row * DSTATE + (c4 - DINNER)] = acc;
    } else {
        *(float4*)&Cb[(size_t)row * DSTATE + (c4 - DINNER - DSTATE)] = acc;
    }

    if (threadIdx.x < NHEADS) {
        const int hh = threadIdx.x;
        const float raw = zx[(size_t)row * DINPROJ + (DINNER + CONVDIM) + hh] + dtbias[hh];
        const float dtv = (raw > 20.0f) ? raw : log1pf(expf(raw));
        const float a = expf(alog[hh]);
        dtb[row * NHEADS + hh] = dtv;
        dAb[row * NHEADS + hh] = expf(-a * dtv);
    }
}

// ---------------------------------------------------------------------------
// meta: per (b,h,chunk) wave: l[t] = inclusive cumsum(-a*dt); w; ptot.
// ---------------------------------------------------------------------------
__global__ __launch_bounds__(64)
void meta_kernel(const float* __restrict__ dtb,
                 const float* __restrict__ alog,
                 float* __restrict__ lB, float* __restrict__ wB,
                 float* __restrict__ ptot)
{
    const int bhc = blockIdx.x;
    const int chunk = bhc & 31;
    const int h = (bhc >> 5) & 15;
    const int b = bhc >> 9;
    const int t = threadIdx.x;
    const size_t row0 = (size_t)b * SEQ + (size_t)chunk * TSEG;

    const float a = __expf(alog[h]);
    const float dtv = dtb[(row0 + t) * NHEADS + h];
    float v = -a * dtv;
#pragma unroll
    for (int off = 1; off < 64; off <<= 1) {
        const float u = __shfl_up(v, off, 64);
        if (t >= off) v += u;
    }
    const float l63 = __shfl(v, 63, 64);
    lB[(size_t)bhc * 64 + t] = v;
    wB[(size_t)bhc * 64 + t] = __expf(l63 - v) * dtv;
    if (t == 0) ptot[bhc] = __expf(l63);
}

// ---------------------------------------------------------------------------
// cb: CB[t][s] = C_chunk @ B_chunk^T per (b,chunk). Swizzled (SWZ128).
// ---------------------------------------------------------------------------
__global__ __launch_bounds__(256)
void cb_kernel(const unsigned short* __restrict__ Ch,
               const unsigned short* __restrict__ Cl,
               const unsigned short* __restrict__ Bh_,
               const unsigned short* __restrict__ Bl_,
               float* __restrict__ CBo)
{
    __shared__ __align__(16) unsigned short Cs[2][64 * 128];
    __shared__ __align__(16) unsigned short Bs2[2][64 * 128];
    const int bc = blockIdx.x;
    const size_t base = (size_t)bc * 8192;
    const int tid = threadIdx.x;
#pragma unroll
    for (int i = 0; i < 4; ++i) {
        const int bi = tid + i * 256;           // 16B block 0..1023
        const int r = bi >> 4, c = (bi & 15) << 3;
        const int d = SWZ128(r, c);
        *(uint4*)&Cs[0][d]  = ((const uint4*)(Ch  + base))[bi];
        *(uint4*)&Cs[1][d]  = ((const uint4*)(Cl  + base))[bi];
        *(uint4*)&Bs2[0][d] = ((const uint4*)(Bh_ + base))[bi];
        *(uint4*)&Bs2[1][d] = ((const uint4*)(Bl_ + base))[bi];
    }
    __syncthreads();

    const int w = tid >> 6, lane = tid & 63;
    const int lr = lane & 15, lk = (lane >> 4) * 8;
    f32x4 acc[4];
#pragma unroll
    for (int i = 0; i < 4; ++i) acc[i] = (f32x4){0.f, 0.f, 0.f, 0.f};

#pragma unroll
    for (int kk = 0; kk < 4; ++kk) {
        const int k0 = kk * 32;
        const int ar = w * 16 + lr;
        const bf16x8 ah = *(const bf16x8*)&Cs[0][SWZ128(ar, k0 + lk)];
        const bf16x8 al = *(const bf16x8*)&Cs[1][SWZ128(ar, k0 + lk)];
#pragma unroll
        for (int st = 0; st < 4; ++st) {
            const int br = st * 16 + lr;
            const bf16x8 bh = *(const bf16x8*)&Bs2[0][SWZ128(br, k0 + lk)];
            const bf16x8 bl = *(const bf16x8*)&Bs2[1][SWZ128(br, k0 + lk)];
            acc[st] = __builtin_amdgcn_mfma_f32_16x16x32_bf16(ah, bh, acc[st], 0, 0, 0);
            acc[st] = __builtin_amdgcn_mfma_f32_16x16x32_bf16(ah, bl, acc[st], 0, 0, 0);
            acc[st] = __builtin_amdgcn_mfma_f32_16x16x32_bf16(al, bh, acc[st], 0, 0, 0);
        }
    }
    const int crow = (lane >> 4) * 4;
#pragma unroll
    for (int st = 0; st < 4; ++st)
#pragma unroll
        for (int r = 0; r < 4; ++r)
            CBo[(size_t)bc * 4096 + (size_t)(w * 16 + crow + r) * 64 + st * 16 + lr] = acc[st][r];
}

// ---------------------------------------------------------------------------
// state: S[n][p] = sum_t (B[t,n]*w[t]) * x[t,p] per (b,h,chunk). Swizzled.
// ---------------------------------------------------------------------------
__global__ __launch_bounds__(256)
void state_kernel(const unsigned short* __restrict__ BTh,
                  const unsigned short* __restrict__ BTl,
                  const float* __restrict__ xh,
                  const float* __restrict__ wB,
                  float* __restrict__ hloc)
{
    __shared__ __align__(16) unsigned short BTs[2][128 * 64];
    __shared__ float xsf[64 * 65];
    __shared__ __align__(16) unsigned short xwT[2][64 * 64];
    __shared__ float wsl[64];

    const int bhc = blockIdx.x;
    const int chunk = bhc & 31;
    const int h = (bhc >> 5) & 15;
    const int b = bhc >> 9;
    const int bc = b * 32 + chunk;
    const size_t row0 = (size_t)b * SEQ + (size_t)chunk * TSEG;
    const int tid = threadIdx.x;

    const size_t bbase = (size_t)bc * 8192;
#pragma unroll
    for (int i = 0; i < 4; ++i) {
        const int bi = tid + i * 256;           // 16B block 0..1023
        const int r = bi >> 3, c = (bi & 7) << 3;
        const int d = SWZ64(r, c);
        *(uint4*)&BTs[0][d] = ((const uint4*)(BTh + bbase))[bi];
        *(uint4*)&BTs[1][d] = ((const uint4*)(BTl + bbase))[bi];
    }
#pragma unroll
    for (int i = 0; i < 4; ++i) {
        const int l4 = tid + i * 256;           // 0..1023
        const int s = l4 >> 4, c4 = (l4 & 15) * 4;
        const float4 v = *(const float4*)&xh[(row0 + s) * DINNER + h * HEADDIM + c4];
        xsf[s * 65 + c4 + 0] = v.x;
        xsf[s * 65 + c4 + 1] = v.y;
        xsf[s * 65 + c4 + 2] = v.z;
        xsf[s * 65 + c4 + 3] = v.w;
    }
    if (tid < 64) wsl[tid] = wB[(size_t)bhc * 64 + tid];
    __syncthreads();

    {
        const int t = tid & 63;
        const int pb = (tid >> 6) * 16;
#pragma unroll
        for (int i = 0; i < 16; ++i) {
            const int p = pb + i;
            const float v = xsf[t * 65 + p] * wsl[t];
            const unsigned short hh = f2bfu(v);
            const int d = SWZ64(p, t);
            xwT[0][d] = hh;
            xwT[1][d] = f2bfu(v - bfu2f(hh));
        }
    }
    __syncthreads();

    const int w = tid >> 6, lane = tid & 63;
    const int lr = lane & 15, lk = (lane >> 4) * 8;
    f32x4 acc[2][4];
#pragma unroll
    for (int i = 0; i < 2; ++i)
#pragma unroll
        for (int j = 0; j < 4; ++j) acc[i][j] = (f32x4){0.f, 0.f, 0.f, 0.f};

#pragma unroll
    for (int kk = 0; kk < 2; ++kk) {
        const int k0 = kk * 32;
        bf16x8 ah[2], al[2];
#pragma unroll
        for (int nt = 0; nt < 2; ++nt) {
            const int n = w * 32 + nt * 16 + lr;
            ah[nt] = *(const bf16x8*)&BTs[0][SWZ64(n, k0 + lk)];
            al[nt] = *(const bf16x8*)&BTs[1][SWZ64(n, k0 + lk)];
        }
#pragma unroll
        for (int pt = 0; pt < 4; ++pt) {
            const int pr = pt * 16 + lr;
            const bf16x8 bh = *(const bf16x8*)&xwT[0][SWZ64(pr, k0 + lk)];
            const bf16x8 bl = *(const bf16x8*)&xwT[1][SWZ64(pr, k0 + lk)];
#pragma unroll
            for (int nt = 0; nt < 2; ++nt) {
                acc[nt][pt] = __builtin_amdgcn_mfma_f32_16x16x32_bf16(ah[nt], bh, acc[nt][pt], 0, 0, 0);
                acc[nt][pt] = __builtin_amdgcn_mfma_f32_16x16x32_bf16(ah[nt], bl, acc[nt][pt], 0, 0, 0);
                acc[nt][pt] = __builtin_amdgcn_mfma_f32_16x16x32_bf16(al[nt], bh, acc[nt][pt], 0, 0, 0);
            }
        }
    }

    const int crow = (lane >> 4) * 4;
#pragma unroll
    for (int nt = 0; nt < 2; ++nt)
#pragma unroll
        for (int pt = 0; pt < 4; ++pt)
#pragma unroll
            for (int r = 0; r < 4; ++r) {
                const int n = w * 32 + nt * 16 + crow + r;
                hloc[(size_t)bhc * 8192 + (size_t)n * 64 + pt * 16 + lr] = acc[nt][pt][r];
            }
}

// ---------------------------------------------------------------------------
// combine: sequential over 32 chunks (in-place: hloc becomes h0). (unchanged)
// ---------------------------------------------------------------------------
__global__ __launch_bounds__(256)
void combine_kernel(float* __restrict__ hloc,
                    const float* __restrict__ ptot)
{
    const int bid = blockIdx.x;
    const int bh = bid >> 3;
    const int chunk = bid & 7;
    const int e0 = chunk * 1024 + threadIdx.x * 4;

    float4 s = make_float4(0.f, 0.f, 0.f, 0.f);
    for (int k = 0; k < NSEG; ++k) {
        float* p = &hloc[((size_t)bh * NSEG + k) * (DSTATE * HEADDIM) + e0];
        const float4 v = *(const float4*)p;
        *(float4*)p = s;
        const float pt = ptot[bh * NSEG + k];
        s.x = fmaf(pt, s.x, v.x);
        s.y = fmaf(pt, s.y, v.y);
        s.z = fmaf(pt, s.z, v.z);
        s.w = fmaf(pt, s.w, v.w);
    }
}

// ---------------------------------------------------------------------------
// y: per (b,chunk,headgroup-of-4), 512 thr. Swizzled (SWZ128/SWZ64).
// ---------------------------------------------------------------------------
__global__ __launch_bounds__(512)
void y_kernel(const unsigned short* __restrict__ Ch,
              const unsigned short* __restrict__ Cl,
              const float* __restrict__ CBg,
              const float* __restrict__ lB,
              const float* __restrict__ dtb,
              const float* __restrict__ xh,
              const float* __restrict__ hloc,
              float* __restrict__ yb)
{
    __shared__ __align__(16) unsigned short CsA[2][64 * 128];  // C [t][n]
    __shared__ float scr[128 * 65];                            // padded scratch
    __shared__ __align__(16) unsigned short opB[2][64 * 128];  // phaseA h0T / phaseB xT
    __shared__ __align__(16) unsigned short Ms[2][64 * 64];    // M [t][s]
    __shared__ float ls4[256], dt4[256];

    const int gid = blockIdx.x;
    const int hg = gid & 3, bc = gid >> 2;
    const int chunk = bc & 31, b = bc >> 5;
    const size_t row0 = (size_t)b * SEQ + (size_t)chunk * TSEG;
    const int tid = threadIdx.x;

    const size_t cbase = (size_t)bc * 8192;
#pragma unroll
    for (int i = 0; i < 2; ++i) {
        const int bi = tid + i * 512;           // 16B block 0..1023
        const int r = bi >> 4, c = (bi & 15) << 3;
        const int d = SWZ128(r, c);
        *(uint4*)&CsA[0][d] = ((const uint4*)(Ch + cbase))[bi];
        *(uint4*)&CsA[1][d] = ((const uint4*)(Cl + cbase))[bi];
    }
    if (tid < 256) {
        const int e = tid >> 6, t = tid & 63;
        const int h = hg * 4 + e;
        const int bhc = (b * NHEADS + h) * NSEG + chunk;
        ls4[tid] = lB[(size_t)bhc * 64 + t];
        dt4[tid] = dtb[(row0 + t) * NHEADS + h];
    }
    __syncthreads();

    const int w = tid >> 6, lane = tid & 63;
    const int lr = lane & 15, lk = (lane >> 4) * 8;
    const int tt = w & 3, ph = w >> 2;
    const int crow = (lane >> 4) * 4;
    const float* CBc = CBg + (size_t)bc * 4096;

    for (int e = 0; e < 4; ++e) {
        const int h = hg * 4 + e;
        const int bhc = (b * NHEADS + h) * NSEG + chunk;
        const float* h0p = hloc + (size_t)bhc * 8192;

        // stage h0 (n-major [128][64]) into padded scr
#pragma unroll
        for (int i = 0; i < 4; ++i) {
            const int l4 = tid + i * 512;      // 0..2047
            const int n = l4 >> 4, c4 = (l4 & 15) * 4;
            const float4 v = *(const float4*)&h0p[(size_t)l4 * 4];
            scr[n * 65 + c4 + 0] = v.x;
            scr[n * 65 + c4 + 1] = v.y;
            scr[n * 65 + c4 + 2] = v.z;
            scr[n * 65 + c4 + 3] = v.w;
        }
        __syncthreads();

        // transpose-split h0 -> opB [p][n] (k=n contig), swizzled
        {
            const int n = tid & 127;
            const int pb = (tid >> 7) * 4;
#pragma unroll
            for (int i = 0; i < 16; ++i) {
                const int p = pb + (i & 3) + (i >> 2) * 16;
                const float v = scr[n * 65 + p];
                const unsigned short hh = f2bfu(v);
                const int d = SWZ128(p, n);
                opB[0][d] = hh;
                opB[1][d] = f2bfu(v - bfu2f(hh));
            }
        }
        __syncthreads();

        // MFMA phase A: acc = C @ h0  (K=128)
        f32x4 acc[2];
        acc[0] = (f32x4){0.f, 0.f, 0.f, 0.f};
        acc[1] = (f32x4){0.f, 0.f, 0.f, 0.f};
#pragma unroll
        for (int kk = 0; kk < 4; ++kk) {
            const int k0 = kk * 32;
            const int ar = tt * 16 + lr;
            const bf16x8 ah = *(const bf16x8*)&CsA[0][SWZ128(ar, k0 + lk)];
            const bf16x8 al = *(const bf16x8*)&CsA[1][SWZ128(ar, k0 + lk)];
#pragma unroll
            for (int pt = 0; pt < 2; ++pt) {
                const int pc = (ph * 2 + pt) * 16 + lr;
                const bf16x8 bh = *(const bf16x8*)&opB[0][SWZ128(pc, k0 + lk)];
                const bf16x8 bl = *(const bf16x8*)&opB[1][SWZ128(pc, k0 + lk)];
                acc[pt] = __builtin_amdgcn_mfma_f32_16x16x32_bf16(ah, bh, acc[pt], 0, 0, 0);
                acc[pt] = __builtin_amdgcn_mfma_f32_16x16x32_bf16(ah, bl, acc[pt], 0, 0, 0);
                acc[pt] = __builtin_amdgcn_mfma_f32_16x16x32_bf16(al, bh, acc[pt], 0, 0, 0);
            }
        }
        // row scale by exp(l[t])
        {
            float el[4];
#pragma unroll
            for (int r = 0; r < 4; ++r) el[r] = __expf(ls4[e * 64 + tt * 16 + crow + r]);
#pragma unroll
            for (int pt = 0; pt < 2; ++pt)
#pragma unroll
                for (int r = 0; r < 4; ++r) acc[pt][r] *= el[r];
        }

        // stage x [64s][64p] into scr  +  form M hi/lo (swizzled Ms)
#pragma unroll
        for (int i = 0; i < 2; ++i) {
            const int l4 = tid + i * 512;      // 0..1023
            const int s = l4 >> 4, c4 = (l4 & 15) * 4;
            const float4 v = *(const float4*)&xh[(row0 + s) * DINNER + h * HEADDIM + c4];
            scr[s * 65 + c4 + 0] = v.x;
            scr[s * 65 + c4 + 1] = v.y;
            scr[s * 65 + c4 + 2] = v.z;
            scr[s * 65 + c4 + 3] = v.w;
        }
#pragma unroll
        for (int i = 0; i < 8; ++i) {
            const int lin = tid * 8 + i;
            const int t = lin >> 6, s = lin & 63;
            float m = 0.0f;
            if (s <= t)
                m = CBc[t * 64 + s] * dt4[e * 64 + s] * __expf(ls4[e * 64 + t] - ls4[e * 64 + s]);
            const unsigned short mh = f2bfu(m);
            const int d = SWZ64(t, s);
            Ms[0][d] = mh;
            Ms[1][d] = f2bfu(m - bfu2f(mh));
        }
        __syncthreads();

        // transpose-split x -> opB [p][s] (64-col rows), swizzled
        {
            const int s = tid & 63;
            const int pb = (tid >> 6) * 8;
#pragma unroll
            for (int i = 0; i < 8; ++i) {
                const int p = pb + i;
                const float v = scr[s * 65 + p];
                const unsigned short hh = f2bfu(v);
                const int d = SWZ64(p, s);
                opB[0][d] = hh;
                opB[1][d] = f2bfu(v - bfu2f(hh));
            }
        }
        __syncthreads();

        // MFMA phase B: acc += M @ x  (K=64)
#pragma unroll
        for (int kk = 0; kk < 2; ++kk) {
            const int k0 = kk * 32;
            const int ar = tt * 16 + lr;
            const bf16x8 ah = *(const bf16x8*)&Ms[0][SWZ64(ar, k0 + lk)];
            const bf16x8 al = *(const bf16x8*)&Ms[1][SWZ64(ar, k0 + lk)];
#pragma unroll
            for (int pt = 0; pt < 2; ++pt) {
                const int pc = (ph * 2 + pt) * 16 + lr;
                const bf16x8 bh = *(const bf16x8*)&opB[0][SWZ64(pc, k0 + lk)];
                const bf16x8 bl = *(const bf16x8*)&opB[1][SWZ64(pc, k0 + lk)];
                acc[pt] = __builtin_amdgcn_mfma_f32_16x16x32_bf16(ah, bh, acc[pt], 0, 0, 0);
                acc[pt] = __builtin_amdgcn_mfma_f32_16x16x32_bf16(ah, bl, acc[pt], 0, 0, 0);
                acc[pt] = __builtin_amdgcn_mfma_f32_16x16x32_bf16(al, bh, acc[pt], 0, 0, 0);
            }
        }

        // write y
#pragma unroll
        for (int pt = 0; pt < 2; ++pt)
#pragma unroll
            for (int r = 0; r < 4; ++r)
                yb[(row0 + tt * 16 + crow + r) * DINNER + h * HEADDIM + (ph * 2 + pt) * 16 + lr] = acc[pt][r];
        __syncthreads();
    }
}

// ---------------------------------------------------------------------------
// Gate + D-skip + RMSNorm; writes ynorm as split-bf16 planes. (unchanged)
// ---------------------------------------------------------------------------
__global__ __launch_bounds__(256)
void gate_kernel(const float* __restrict__ yb,
                 const float* __restrict__ xh,
                 const float* __restrict__ dskip,
                 const float* __restrict__ zx,
                 const float* __restrict__ nw,
                 unsigned short* __restrict__ yh,
                 unsigned short* __restrict__ yl)
{
    const int row = blockIdx.x;
    const int c4 = threadIdx.x * 4;

    float4 y = *(const float4*)&yb[(size_t)row * DINNER + c4];
    const float4 xv = *(const float4*)&xh[(size_t)row * DINNER + c4];
    const float dsk = dskip[c4 >> 6];
    y.x = fmaf(dsk, xv.x, y.x);
    y.y = fmaf(dsk, xv.y, y.y);
    y.z = fmaf(dsk, xv.z, y.z);
    y.w = fmaf(dsk, xv.w, y.w);

    const float4 z = *(const float4*)&zx[(size_t)row * DINPROJ + c4];
    float4 g;
    g.x = y.x * silu_f(z.x);
    g.y = y.y * silu_f(z.y);
    g.z = y.z * silu_f(z.z);
    g.w = y.w * silu_f(z.w);

    float local = g.x * g.x + g.y * g.y + g.z * g.z + g.w * g.w;
#pragma unroll
    for (int m = 32; m >= 1; m >>= 1) local += __shfl_xor(local, m, 64);

    __shared__ float red[4];
    if ((threadIdx.x & 63) == 0) red[threadIdx.x >> 6] = local;
    __syncthreads();
    const float total = red[0] + red[1] + red[2] + red[3];
    const float scale = rsqrtf(total * (1.0f / (float)DINNER) + 1e-5f);

    const float4 w = *(const float4*)&nw[c4];
    float o[4];
    o[0] = g.x * scale * w.x;
    o[1] = g.y * scale * w.y;
    o[2] = g.z * scale * w.z;
    o[3] = g.w * scale * w.w;

    unsigned hv[4], lv[4];
#pragma unroll
    for (int j = 0; j < 4; ++j) {
        hv[j] = f2bfu(o[j]);
        lv[j] = f2bfu(o[j] - bfu2f((unsigned short)hv[j]));
    }
    const size_t oi = (size_t)row * DINNER + c4;
    *(uint2*)&yh[oi] = make_uint2(hv[0] | (hv[1] << 16), hv[2] | (hv[3] << 16));
    *(uint2*)&yl[oi] = make_uint2(lv[0] | (lv[1] << 16), lv[2] | (lv[3] << 16));
}

// ---------------------------------------------------------------------------
extern "C" void kernel_launch(void* const* d_in, const int* in_sizes, int n_in,
                              void* d_out, int out_size, void* d_ws, size_t ws_size,
                              hipStream_t stream)
{
    const float* x_in    = (const float*)d_in[0];
    const float* in_w    = (const float*)d_in[1];
    const float* conv_w  = (const float*)d_in[2];
    const float* conv_b  = (const float*)d_in[3];
    const float* dt_bias = (const float*)d_in[4];
    const float* A_log   = (const float*)d_in[5];
    const float* D_skip  = (const float*)d_in[6];
    const float* norm_w  = (const float*)d_in[7];
    const float* out_w   = (const float*)d_in[8];
    float* out = (float*)d_out;

    float* ws   = (float*)d_ws;
    float* zx   = ws;                               // 19,005,440 f
    float* xh   = zx   + (size_t)ROWS * DINPROJ;    //  8,388,608 f
    float* Bb   = xh   + (size_t)ROWS * DINNER;     //  1,048,576 f
    float* Cb   = Bb   + (size_t)ROWS * DSTATE;     //  1,048,576 f
    float* dtb  = Cb   + (size_t)ROWS * DSTATE;     //    131,072 f
    float* dAb  = dtb  + (size_t)ROWS * NHEADS;     //    131,072 f
    float* yb   = dAb  + (size_t)ROWS * NHEADS;     //  8,388,608 f
    float* UN   = yb   + (size_t)ROWS * DINNER;     // 16,777,216 f (union)
    float* BtF  = UN   + (size_t)16777216;          //  1,245,184 f
    float* WtF  = BtF  + (size_t)1245184;           //    524,288 f
    float* ptot = WtF  + (size_t)524288;            //      2,048 f
    float* lB   = ptot + (size_t)2048;              //    131,072 f
    float* wB   = lB   + (size_t)131072;            //    131,072 f
    float* BTf  = wB   + (size_t)131072;            //  1,048,576 f
    float* Bspf = BTf  + (size_t)1048576;           //  1,048,576 f
    float* Cspf = Bspf + (size_t)1048576;           //  1,048,576 f
    float* CBb  = Cspf + (size_t)1048576;           //    524,288 f
    // total 60,622,848 f = 242.5 MB

    unsigned short* Ah = (unsigned short*)UN;                 // [8192][512]
    unsigned short* Al = Ah + (size_t)ROWS * DMODEL;
    float*          hloc = UN;                                // 16.78M f
    unsigned short* yh = (unsigned short*)UN;                 // [8192][1024]
    unsigned short* yl = yh + (size_t)ROWS * DINNER;

    unsigned short* Bth = (unsigned short*)BtF;               // [2432][512]
    unsigned short* Btl = Bth + (size_t)NPAD_IN * DMODEL;
    unsigned short* Wth = (unsigned short*)WtF;               // [512][1024]
    unsigned short* Wtl = Wth + (size_t)DMODEL * DINNER;

    unsigned short* BTh = (unsigned short*)BTf;               // [128][128][64]
    unsigned short* BTl = BTh + (size_t)128 * 8192;
    unsigned short* Bsph = (unsigned short*)Bspf;             // [8192][128]
    unsigned short* Bspl = Bsph + (size_t)ROWS * DSTATE;
    unsigned short* Csph = (unsigned short*)Cspf;             // [8192][128]
    unsigned short* Cspl = Csph + (size_t)ROWS * DSTATE;

    for (int layer = 0; layer < 2; ++layer) {
        const float* xl = (layer == 0) ? x_in : out;

        split_a_kernel<<<(ROWS * DMODEL) / (256 * 8), 256, 0, stream>>>(xl, Ah, Al);

        tsplit_w_kernel<<<dim3(NPAD_IN / 32, DMODEL / 32), 256, 0, stream>>>(
            in_w + (size_t)layer * DMODEL * DINPROJ, DMODEL, DINPROJ, Bth, Btl);

        gemm_bf16s<<<dim3(NPAD_IN / 128, ROWS / 128), 256, 0, stream>>>(
            Ah, Al, Bth, Btl, zx, DINPROJ, DINPROJ, DMODEL);

        conv_kernel<<<ROWS, CONVDIM / 4, 0, stream>>>(
            zx,
            conv_w + (size_t)layer * DCONV * CONVDIM,
            conv_b + (size_t)layer * CONVDIM,
            dt_bias + (size_t)layer * NHEADS,
            A_log + (size_t)layer * NHEADS,
            xh, Bb, Cb, dtb, dAb);

        meta_kernel<<<BATCH * NHEADS * NSEG, 64, 0, stream>>>(
            dtb, A_log + (size_t)layer * NHEADS, lB, wB, ptot);

        split_a_kernel<<<(ROWS * DSTATE) / (256 * 8), 256, 0, stream>>>(Bb, Bsph, Bspl);
        split_a_kernel<<<(ROWS * DSTATE) / (256 * 8), 256, 0, stream>>>(Cb, Csph, Cspl);

        tsplit_chunk_kernel<<<dim3(128 / 32, 64 / 32, BATCH * NSEG), 256, 0, stream>>>(
            Bb, TSEG, DSTATE, DSTATE, (size_t)TSEG * DSTATE, BTh, BTl);

        cb_kernel<<<BATCH * NSEG, 256, 0, stream>>>(Csph, Cspl, Bsph, Bspl, CBb);

        state_kernel<<<BATCH * NHEADS * NSEG, 256, 0, stream>>>(
            BTh, BTl, xh, wB, hloc);

        combine_kernel<<<BATCH * NHEADS * 8, 256, 0, stream>>>(hloc, ptot);

        y_kernel<<<BATCH * NSEG * 4, 512, 0, stream>>>(
            Csph, Cspl, CBb, lB, dtb, xh, hloc, yb);

        gate_kernel<<<ROWS, 256, 0, stream>>>(
            yb, xh, D_skip + (size_t)layer * NHEADS,
            zx, norm_w + (size_t)layer * DINNER, yh, yl);

        tsplit_w_kernel<<<dim3(DMODEL / 32, DINNER / 32), 256, 0, stream>>>(
            out_w + (size_t)layer * DINNER * DMODEL, DINNER, DMODEL, Wth, Wtl);

        gemm_bf16s<<<dim3(DMODEL / 128, ROWS / 128), 256, 0, stream>>>(
            yh, yl, Wth, Wtl, out, DMODEL, DMODEL, DINNER);
    }
}

// Round 13
// 568.107 us; speedup vs baseline: 1.3962x; 1.0227x over previous
//
#include <hip/hip_runtime.h>
#include <hip/hip_bf16.h>
#include <cstddef>
#include <cstdint>

// Mamba2 (2 layers). GEMMs via split-bf16 MFMA; round-13: 2-pass (A*Bh =
// AhBh + AlBh) everywhere EXCEPT the dt column block (col0 >= 2304) which
// keeps the 3rd AhBl pass (dt feeds exp(-a*dt) -> precision critical).
// + XCD-aware block swizzle inside gemm (nwg % 8 == 0 for both shapes).
// Selective scan via CHUNKED SSD (chunk Q=64), all LDS tiles T2-swizzled.

#define BATCH 4
#define SEQ   2048
#define DMODEL 512
#define DINNER 1024
#define DSTATE 128
#define HEADDIM 64
#define NHEADS 16
#define DCONV 4
#define CONVDIM 1280
#define DINPROJ 2320
#define NPAD_IN 2432          // 19 * 128
#define ROWS (BATCH * SEQ)    // 8192
#define NSEG 32               // chunks per sequence
#define TSEG 64               // chunk length

// swizzled index into a [rows][32/64/128]-ushort LDS tile (16B-slot XOR)
#define SWZ32(r, c)  ((r) * 32  + (((((c) >> 3) ^ (((r) >> 1) & 3)) << 3) | ((c) & 7)))
#define SWZ64(r, c)  ((r) * 64  + (((((c) >> 3) ^ ((r) & 7)) << 3) | ((c) & 7)))
#define SWZ128(r, c) ((r) * 128 + (((((c) >> 3) ^ ((r) & 7)) << 3) | ((c) & 7)))

typedef __attribute__((ext_vector_type(8))) short bf16x8;
typedef __attribute__((ext_vector_type(4))) float f32x4;

__device__ __forceinline__ float silu_f(float x) {
    return x * (1.0f / (1.0f + __expf(-x)));
}
__device__ __forceinline__ unsigned short f2bfu(float f) {  // RNE fp32->bf16
    unsigned u = __float_as_uint(f);
    unsigned r = u + 0x7FFFu + ((u >> 16) & 1u);
    return (unsigned short)(r >> 16);
}
__device__ __forceinline__ float bfu2f(unsigned short h) {
    return __uint_as_float(((unsigned)h) << 16);
}

// ---------------------------------------------------------------------------
// Split fp32 flat array -> hi/lo bf16. 8 elems/thread.
// ---------------------------------------------------------------------------
__global__ __launch_bounds__(256)
void split_a_kernel(const float* __restrict__ A,
                    unsigned short* __restrict__ Ah,
                    unsigned short* __restrict__ Al)
{
    const size_t i = ((size_t)blockIdx.x * 256 + threadIdx.x) * 8;
    const float4 a = *(const float4*)&A[i];
    const float4 b = *(const float4*)&A[i + 4];
    float v[8] = {a.x, a.y, a.z, a.w, b.x, b.y, b.z, b.w};
    unsigned hv[8], lv[8];
#pragma unroll
    for (int j = 0; j < 8; ++j) {
        hv[j] = f2bfu(v[j]);
        lv[j] = f2bfu(v[j] - bfu2f((unsigned short)hv[j]));
    }
    uint4 ph = make_uint4(hv[0] | (hv[1] << 16), hv[2] | (hv[3] << 16),
                          hv[4] | (hv[5] << 16), hv[6] | (hv[7] << 16));
    uint4 pl = make_uint4(lv[0] | (lv[1] << 16), lv[2] | (lv[3] << 16),
                          lv[4] | (lv[5] << 16), lv[6] | (lv[7] << 16));
    *(uint4*)&Ah[i] = ph;
    *(uint4*)&Al[i] = pl;
}

// ---------------------------------------------------------------------------
// Transpose + split weight W[K][N] fp32 -> Oh/Ol[Npad][K] bf16 (n >= N -> 0).
// ---------------------------------------------------------------------------
__global__ __launch_bounds__(256)
void tsplit_w_kernel(const float* __restrict__ W, int K, int N,
                     unsigned short* __restrict__ Oh,
                     unsigned short* __restrict__ Ol)
{
    __shared__ float tile[32][33];
    const int n0 = blockIdx.x * 32, k0 = blockIdx.y * 32;
    const int c = threadIdx.x & 31, r8 = threadIdx.x >> 5;
    const int n = n0 + c;
#pragma unroll
    for (int i = 0; i < 4; ++i) {
        const int k = r8 + i * 8;
        float v = 0.0f;
        if (n < N) v = W[(size_t)(k0 + k) * N + n];
        tile[c][k] = v;
    }
    __syncthreads();
#pragma unroll
    for (int i = 0; i < 4; ++i) {
        const int nl = r8 + i * 8;
        const float v = tile[nl][c];
        const unsigned short h = f2bfu(v);
        const unsigned short l = f2bfu(v - bfu2f(h));
        const size_t o = (size_t)(n0 + nl) * K + k0 + c;
        Oh[o] = h;
        Ol[o] = l;
    }
}

// ---------------------------------------------------------------------------
// Chunked transpose+split: per z, fp32 [K][N] (rowstride rs) -> bf16 [N][K].
// ---------------------------------------------------------------------------
__global__ __launch_bounds__(256)
void tsplit_chunk_kernel(const float* __restrict__ src, int K, int N, int rs,
                         size_t chunkStride,
                         unsigned short* __restrict__ Oh,
                         unsigned short* __restrict__ Ol)
{
    __shared__ float tile[32][33];
    const int z = blockIdx.z;
    const float* W = src + (size_t)z * chunkStride;
    const int n0 = blockIdx.x * 32, k0 = blockIdx.y * 32;
    const int c = threadIdx.x & 31, r8 = threadIdx.x >> 5;
#pragma unroll
    for (int i = 0; i < 4; ++i) {
        const int k = r8 + i * 8;
        tile[c][k] = W[(size_t)(k0 + k) * rs + n0 + c];
    }
    __syncthreads();
#pragma unroll
    for (int i = 0; i < 4; ++i) {
        const int nl = r8 + i * 8;
        const float v = tile[nl][c];
        const unsigned short h = f2bfu(v);
        const unsigned short l = f2bfu(v - bfu2f(h));
        const size_t o = (size_t)z * N * K + (size_t)(n0 + nl) * K + k0 + c;
        Oh[o] = h;
        Ol[o] = l;
    }
}

// ---------------------------------------------------------------------------
// Split-bf16 MFMA GEMM. 2-pass C = (Ah+Al)*Bh; blocks with col0+128 >
// exactCol0 add the AhBl pass. XCD-chunked block swizzle (nwg % 8 == 0).
// ---------------------------------------------------------------------------
__global__ __launch_bounds__(256)
void gemm_bf16s(const unsigned short* __restrict__ Ah,
                const unsigned short* __restrict__ Al,
                const unsigned short* __restrict__ Bh,
                const unsigned short* __restrict__ Bl,
                float* __restrict__ C, int ldc, int N, int K,
                int exactCol0)
{
    __shared__ __align__(16) unsigned short As[2][128 * 32];
    __shared__ __align__(16) unsigned short Bs[2][128 * 32];

    const int tid = threadIdx.x;
    const int w = tid >> 6, lane = tid & 63;
    const int wm = w >> 1, wn = w & 1;

    // XCD-aware bijective remap (requires nwg % 8 == 0)
    const int nwg = gridDim.x * gridDim.y;
    int flat = blockIdx.y * gridDim.x + blockIdx.x;
    flat = (flat & 7) * (nwg >> 3) + (flat >> 3);
    const int bx = flat % gridDim.x, by = flat / gridDim.x;
    const int row0 = by * 128, col0 = bx * 128;
    const bool exact = (col0 + 128 > exactCol0);

    const int srow = tid >> 1;
    const int sk   = (tid & 1) * 16;

    const int lr = lane & 15;
    const int lk = (lane >> 4) * 8;

    f32x4 acc[4][4];
#pragma unroll
    for (int i = 0; i < 4; ++i)
#pragma unroll
        for (int j = 0; j < 4; ++j) acc[i][j] = (f32x4){0.f, 0.f, 0.f, 0.f};

    const int sw0 = SWZ32(srow, sk);
    const int sw1 = SWZ32(srow, sk + 8);

    for (int k0 = 0; k0 < K; k0 += 32) {
        const size_t ga = (size_t)(row0 + srow) * K + k0 + sk;
        const size_t gb = (size_t)(col0 + srow) * K + k0 + sk;
        const uint4 vah0 = *(const uint4*)&Ah[ga];
        const uint4 vah1 = *(const uint4*)&Ah[ga + 8];
        const uint4 val0 = *(const uint4*)&Al[ga];
        const uint4 val1 = *(const uint4*)&Al[ga + 8];
        const uint4 vbh0 = *(const uint4*)&Bh[gb];
        const uint4 vbh1 = *(const uint4*)&Bh[gb + 8];
        uint4 vbl0, vbl1;
        if (exact) {
            vbl0 = *(const uint4*)&Bl[gb];
            vbl1 = *(const uint4*)&Bl[gb + 8];
        }
        __syncthreads();
        *(uint4*)&As[0][sw0] = vah0;  *(uint4*)&As[0][sw1] = vah1;
        *(uint4*)&As[1][sw0] = val0;  *(uint4*)&As[1][sw1] = val1;
        *(uint4*)&Bs[0][sw0] = vbh0;  *(uint4*)&Bs[0][sw1] = vbh1;
        if (exact) {
            *(uint4*)&Bs[1][sw0] = vbl0;  *(uint4*)&Bs[1][sw1] = vbl1;
        }
        __syncthreads();

        bf16x8 a_h[4], a_l[4], b_h[4];
#pragma unroll
        for (int mt = 0; mt < 4; ++mt) {
            const int r = wm * 64 + mt * 16 + lr;
            a_h[mt] = *(const bf16x8*)&As[0][SWZ32(r, lk)];
            a_l[mt] = *(const bf16x8*)&As[1][SWZ32(r, lk)];
        }
#pragma unroll
        for (int nt = 0; nt < 4; ++nt) {
            const int c = wn * 64 + nt * 16 + lr;
            b_h[nt] = *(const bf16x8*)&Bs[0][SWZ32(c, lk)];
        }
#pragma unroll
        for (int mt = 0; mt < 4; ++mt)
#pragma unroll
            for (int nt = 0; nt < 4; ++nt) {
                acc[mt][nt] = __builtin_amdgcn_mfma_f32_16x16x32_bf16(a_h[mt], b_h[nt], acc[mt][nt], 0, 0, 0);
                acc[mt][nt] = __builtin_amdgcn_mfma_f32_16x16x32_bf16(a_l[mt], b_h[nt], acc[mt][nt], 0, 0, 0);
            }
        if (exact) {
            bf16x8 b_l[4];
#pragma unroll
            for (int nt = 0; nt < 4; ++nt) {
                const int c = wn * 64 + nt * 16 + lr;
                b_l[nt] = *(const bf16x8*)&Bs[1][SWZ32(c, lk)];
            }
#pragma unroll
            for (int mt = 0; mt < 4; ++mt)
#pragma unroll
                for (int nt = 0; nt < 4; ++nt)
                    acc[mt][nt] = __builtin_amdgcn_mfma_f32_16x16x32_bf16(a_h[mt], b_l[nt], acc[mt][nt], 0, 0, 0);
        }
    }

    const int crow = (lane >> 4) * 4;
#pragma unroll
    for (int mt = 0; mt < 4; ++mt)
#pragma unroll
        for (int nt = 0; nt < 4; ++nt) {
            const int cc = col0 + wn * 64 + nt * 16 + lr;
            if (cc < N) {
#pragma unroll
                for (int r = 0; r < 4; ++r)
                    C[(size_t)(row0 + wm * 64 + mt * 16 + crow + r) * ldc + cc] = acc[mt][nt][r];
            }
        }
}

// ---------------------------------------------------------------------------
// Depthwise causal conv (4 taps) + bias + SiLU + dt/dA precompute. (unchanged)
// ---------------------------------------------------------------------------
__global__ __launch_bounds__(320)
void conv_kernel(const float* __restrict__ zx,
                 const float* __restrict__ cw,
                 const float* __restrict__ cb,
                 const float* __restrict__ dtbias,
                 const float* __restrict__ alog,
                 float* __restrict__ xh,
                 float* __restrict__ Bb,
                 float* __restrict__ Cb,
                 float* __restrict__ dtb,
                 float* __restrict__ dAb)
{
    const int row = blockIdx.x;
    const int l   = row & (SEQ - 1);
    const int c4  = threadIdx.x * 4;

    float4 acc = *(const float4*)&cb[c4];
#pragma unroll
    for (int k = 0; k < DCONV; ++k) {
        const int lk = l - (DCONV - 1) + k;
        if (lk >= 0) {
            const float4 v = *(const float4*)&zx[(size_t)(row - (DCONV - 1) + k) * DINPROJ + DINNER + c4];
            const float4 w = *(const float4*)&cw[k * CONVDIM + c4];
            acc.x = fmaf(v.x, w.x, acc.x);
            acc.y = fmaf(v.y, w.y, acc.y);
            acc.z = fmaf(v.z, w.z, acc.z);
            acc.w = fmaf(v.w, w.w, acc.w);
        }
    }
    acc.x = silu_f(acc.x);
    acc.y = silu_f(acc.y);
    acc.z = silu_f(acc.z);
    acc.w = silu_f(acc.w);

    if (c4 < DINNER) {
        *(float4*)&xh[(size_t)row * DINNER + c4] = acc;
    } else if (c4 < DINNER + DSTATE) {
        *(float4*)&Bb[(size_t)row * DSTATE + (c4 - DINNER)] = acc;
    } else {
        *(float4*)&Cb[(size_t)row * DSTATE + (c4 - DINNER - DSTATE)] = acc;
    }

    if (threadIdx.x < NHEADS) {
        const int hh = threadIdx.x;
        const float raw = zx[(size_t)row * DINPROJ + (DINNER + CONVDIM) + hh] + dtbias[hh];
        const float dtv = (raw > 20.0f) ? raw : log1pf(expf(raw));
        const float a = expf(alog[hh]);
        dtb[row * NHEADS + hh] = dtv;
        dAb[row * NHEADS + hh] = expf(-a * dtv);
    }
}

// ---------------------------------------------------------------------------
// meta: per (b,h,chunk) wave: l[t] = inclusive cumsum(-a*dt); w; ptot.
// ---------------------------------------------------------------------------
__global__ __launch_bounds__(64)
void meta_kernel(const float* __restrict__ dtb,
                 const float* __restrict__ alog,
                 float* __restrict__ lB, float* __restrict__ wB,
                 float* __restrict__ ptot)
{
    const int bhc = blockIdx.x;
    const int chunk = bhc & 31;
    const int h = (bhc >> 5) & 15;
    const int b = bhc >> 9;
    const int t = threadIdx.x;
    const size_t row0 = (size_t)b * SEQ + (size_t)chunk * TSEG;

    const float a = __expf(alog[h]);
    const float dtv = dtb[(row0 + t) * NHEADS + h];
    float v = -a * dtv;
#pragma unroll
    for (int off = 1; off < 64; off <<= 1) {
        const float u = __shfl_up(v, off, 64);
        if (t >= off) v += u;
    }
    const float l63 = __shfl(v, 63, 64);
    lB[(size_t)bhc * 64 + t] = v;
    wB[(size_t)bhc * 64 + t] = __expf(l63 - v) * dtv;
    if (t == 0) ptot[bhc] = __expf(l63);
}

// ---------------------------------------------------------------------------
// cb: CB[t][s] = C_chunk @ B_chunk^T per (b,chunk). Swizzled (SWZ128).
// ---------------------------------------------------------------------------
__global__ __launch_bounds__(256)
void cb_kernel(const unsigned short* __restrict__ Ch,
               const unsigned short* __restrict__ Cl,
               const unsigned short* __restrict__ Bh_,
               const unsigned short* __restrict__ Bl_,
               float* __restrict__ CBo)
{
    __shared__ __align__(16) unsigned short Cs[2][64 * 128];
    __shared__ __align__(16) unsigned short Bs2[2][64 * 128];
    const int bc = blockIdx.x;
    const size_t base = (size_t)bc * 8192;
    const int tid = threadIdx.x;
#pragma unroll
    for (int i = 0; i < 4; ++i) {
        const int bi = tid + i * 256;           // 16B block 0..1023
        const int r = bi >> 4, c = (bi & 15) << 3;
        const int d = SWZ128(r, c);
        *(uint4*)&Cs[0][d]  = ((const uint4*)(Ch  + base))[bi];
        *(uint4*)&Cs[1][d]  = ((const uint4*)(Cl  + base))[bi];
        *(uint4*)&Bs2[0][d] = ((const uint4*)(Bh_ + base))[bi];
        *(uint4*)&Bs2[1][d] = ((const uint4*)(Bl_ + base))[bi];
    }
    __syncthreads();

    const int w = tid >> 6, lane = tid & 63;
    const int lr = lane & 15, lk = (lane >> 4) * 8;
    f32x4 acc[4];
#pragma unroll
    for (int i = 0; i < 4; ++i) acc[i] = (f32x4){0.f, 0.f, 0.f, 0.f};

#pragma unroll
    for (int kk = 0; kk < 4; ++kk) {
        const int k0 = kk * 32;
        const int ar = w * 16 + lr;
        const bf16x8 ah = *(const bf16x8*)&Cs[0][SWZ128(ar, k0 + lk)];
        const bf16x8 al = *(const bf16x8*)&Cs[1][SWZ128(ar, k0 + lk)];
#pragma unroll
        for (int st = 0; st < 4; ++st) {
            const int br = st * 16 + lr;
            const bf16x8 bh = *(const bf16x8*)&Bs2[0][SWZ128(br, k0 + lk)];
            const bf16x8 bl = *(const bf16x8*)&Bs2[1][SWZ128(br, k0 + lk)];
            acc[st] = __builtin_amdgcn_mfma_f32_16x16x32_bf16(ah, bh, acc[st], 0, 0, 0);
            acc[st] = __builtin_amdgcn_mfma_f32_16x16x32_bf16(ah, bl, acc[st], 0, 0, 0);
            acc[st] = __builtin_amdgcn_mfma_f32_16x16x32_bf16(al, bh, acc[st], 0, 0, 0);
        }
    }
    const int crow = (lane >> 4) * 4;
#pragma unroll
    for (int st = 0; st < 4; ++st)
#pragma unroll
        for (int r = 0; r < 4; ++r)
            CBo[(size_t)bc * 4096 + (size_t)(w * 16 + crow + r) * 64 + st * 16 + lr] = acc[st][r];
}

// ---------------------------------------------------------------------------
// state: S[n][p] = sum_t (B[t,n]*w[t]) * x[t,p] per (b,h,chunk). Swizzled.
// ---------------------------------------------------------------------------
__global__ __launch_bounds__(256)
void state_kernel(const unsigned short* __restrict__ BTh,
                  const unsigned short* __restrict__ BTl,
                  const float* __restrict__ xh,
                  const float* __restrict__ wB,
                  float* __restrict__ hloc)
{
    __shared__ __align__(16) unsigned short BTs[2][128 * 64];
    __shared__ float xsf[64 * 65];
    __shared__ __align__(16) unsigned short xwT[2][64 * 64];
    __shared__ float wsl[64];

    const int bhc = blockIdx.x;
    const int chunk = bhc & 31;
    const int h = (bhc >> 5) & 15;
    const int b = bhc >> 9;
    const int bc = b * 32 + chunk;
    const size_t row0 = (size_t)b * SEQ + (size_t)chunk * TSEG;
    const int tid = threadIdx.x;

    const size_t bbase = (size_t)bc * 8192;
#pragma unroll
    for (int i = 0; i < 4; ++i) {
        const int bi = tid + i * 256;           // 16B block 0..1023
        const int r = bi >> 3, c = (bi & 7) << 3;
        const int d = SWZ64(r, c);
        *(uint4*)&BTs[0][d] = ((const uint4*)(BTh + bbase))[bi];
        *(uint4*)&BTs[1][d] = ((const uint4*)(BTl + bbase))[bi];
    }
#pragma unroll
    for (int i = 0; i < 4; ++i) {
        const int l4 = tid + i * 256;           // 0..1023
        const int s = l4 >> 4, c4 = (l4 & 15) * 4;
        const float4 v = *(const float4*)&xh[(row0 + s) * DINNER + h * HEADDIM + c4];
        xsf[s * 65 + c4 + 0] = v.x;
        xsf[s * 65 + c4 + 1] = v.y;
        xsf[s * 65 + c4 + 2] = v.z;
        xsf[s * 65 + c4 + 3] = v.w;
    }
    if (tid < 64) wsl[tid] = wB[(size_t)bhc * 64 + tid];
    __syncthreads();

    {
        const int t = tid & 63;
        const int pb = (tid >> 6) * 16;
#pragma unroll
        for (int i = 0; i < 16; ++i) {
            const int p = pb + i;
            const float v = xsf[t * 65 + p] * wsl[t];
            const unsigned short hh = f2bfu(v);
            const int d = SWZ64(p, t);
            xwT[0][d] = hh;
            xwT[1][d] = f2bfu(v - bfu2f(hh));
        }
    }
    __syncthreads();

    const int w = tid >> 6, lane = tid & 63;
    const int lr = lane & 15, lk = (lane >> 4) * 8;
    f32x4 acc[2][4];
#pragma unroll
    for (int i = 0; i < 2; ++i)
#pragma unroll
        for (int j = 0; j < 4; ++j) acc[i][j] = (f32x4){0.f, 0.f, 0.f, 0.f};

#pragma unroll
    for (int kk = 0; kk < 2; ++kk) {
        const int k0 = kk * 32;
        bf16x8 ah[2], al[2];
#pragma unroll
        for (int nt = 0; nt < 2; ++nt) {
            const int n = w * 32 + nt * 16 + lr;
            ah[nt] = *(const bf16x8*)&BTs[0][SWZ64(n, k0 + lk)];
            al[nt] = *(const bf16x8*)&BTs[1][SWZ64(n, k0 + lk)];
        }
#pragma unroll
        for (int pt = 0; pt < 4; ++pt) {
            const int pr = pt * 16 + lr;
            const bf16x8 bh = *(const bf16x8*)&xwT[0][SWZ64(pr, k0 + lk)];
            const bf16x8 bl = *(const bf16x8*)&xwT[1][SWZ64(pr, k0 + lk)];
#pragma unroll
            for (int nt = 0; nt < 2; ++nt) {
                acc[nt][pt] = __builtin_amdgcn_mfma_f32_16x16x32_bf16(ah[nt], bh, acc[nt][pt], 0, 0, 0);
                acc[nt][pt] = __builtin_amdgcn_mfma_f32_16x16x32_bf16(ah[nt], bl, acc[nt][pt], 0, 0, 0);
                acc[nt][pt] = __builtin_amdgcn_mfma_f32_16x16x32_bf16(al[nt], bh, acc[nt][pt], 0, 0, 0);
            }
        }
    }

    const int crow = (lane >> 4) * 4;
#pragma unroll
    for (int nt = 0; nt < 2; ++nt)
#pragma unroll
        for (int pt = 0; pt < 4; ++pt)
#pragma unroll
            for (int r = 0; r < 4; ++r) {
                const int n = w * 32 + nt * 16 + crow + r;
                hloc[(size_t)bhc * 8192 + (size_t)n * 64 + pt * 16 + lr] = acc[nt][pt][r];
            }
}

// ---------------------------------------------------------------------------
// combine: sequential over 32 chunks (in-place: hloc becomes h0). (unchanged)
// ---------------------------------------------------------------------------
__global__ __launch_bounds__(256)
void combine_kernel(float* __restrict__ hloc,
                    const float* __restrict__ ptot)
{
    const int bid = blockIdx.x;
    const int bh = bid >> 3;
    const int chunk = bid & 7;
    const int e0 = chunk * 1024 + threadIdx.x * 4;

    float4 s = make_float4(0.f, 0.f, 0.f, 0.f);
    for (int k = 0; k < NSEG; ++k) {
        float* p = &hloc[((size_t)bh * NSEG + k) * (DSTATE * HEADDIM) + e0];
        const float4 v = *(const float4*)p;
        *(float4*)p = s;
        const float pt = ptot[bh * NSEG + k];
        s.x = fmaf(pt, s.x, v.x);
        s.y = fmaf(pt, s.y, v.y);
        s.z = fmaf(pt, s.z, v.z);
        s.w = fmaf(pt, s.w, v.w);
    }
}

// ---------------------------------------------------------------------------
// y: per (b,chunk,headgroup-of-4), 512 thr. Swizzled (SWZ128/SWZ64).
// ---------------------------------------------------------------------------
__global__ __launch_bounds__(512)
void y_kernel(const unsigned short* __restrict__ Ch,
              const unsigned short* __restrict__ Cl,
              const float* __restrict__ CBg,
              const float* __restrict__ lB,
              const float* __restrict__ dtb,
              const float* __restrict__ xh,
              const float* __restrict__ hloc,
              float* __restrict__ yb)
{
    __shared__ __align__(16) unsigned short CsA[2][64 * 128];  // C [t][n]
    __shared__ float scr[128 * 65];                            // padded scratch
    __shared__ __align__(16) unsigned short opB[2][64 * 128];  // phaseA h0T / phaseB xT
    __shared__ __align__(16) unsigned short Ms[2][64 * 64];    // M [t][s]
    __shared__ float ls4[256], dt4[256];

    const int gid = blockIdx.x;
    const int hg = gid & 3, bc = gid >> 2;
    const int chunk = bc & 31, b = bc >> 5;
    const size_t row0 = (size_t)b * SEQ + (size_t)chunk * TSEG;
    const int tid = threadIdx.x;

    const size_t cbase = (size_t)bc * 8192;
#pragma unroll
    for (int i = 0; i < 2; ++i) {
        const int bi = tid + i * 512;           // 16B block 0..1023
        const int r = bi >> 4, c = (bi & 15) << 3;
        const int d = SWZ128(r, c);
        *(uint4*)&CsA[0][d] = ((const uint4*)(Ch + cbase))[bi];
        *(uint4*)&CsA[1][d] = ((const uint4*)(Cl + cbase))[bi];
    }
    if (tid < 256) {
        const int e = tid >> 6, t = tid & 63;
        const int h = hg * 4 + e;
        const int bhc = (b * NHEADS + h) * NSEG + chunk;
        ls4[tid] = lB[(size_t)bhc * 64 + t];
        dt4[tid] = dtb[(row0 + t) * NHEADS + h];
    }
    __syncthreads();

    const int w = tid >> 6, lane = tid & 63;
    const int lr = lane & 15, lk = (lane >> 4) * 8;
    const int tt = w & 3, ph = w >> 2;
    const int crow = (lane >> 4) * 4;
    const float* CBc = CBg + (size_t)bc * 4096;

    for (int e = 0; e < 4; ++e) {
        const int h = hg * 4 + e;
        const int bhc = (b * NHEADS + h) * NSEG + chunk;
        const float* h0p = hloc + (size_t)bhc * 8192;

        // stage h0 (n-major [128][64]) into padded scr
#pragma unroll
        for (int i = 0; i < 4; ++i) {
            const int l4 = tid + i * 512;      // 0..2047
            const int n = l4 >> 4, c4 = (l4 & 15) * 4;
            const float4 v = *(const float4*)&h0p[(size_t)l4 * 4];
            scr[n * 65 + c4 + 0] = v.x;
            scr[n * 65 + c4 + 1] = v.y;
            scr[n * 65 + c4 + 2] = v.z;
            scr[n * 65 + c4 + 3] = v.w;
        }
        __syncthreads();

        // transpose-split h0 -> opB [p][n] (k=n contig), swizzled
        {
            const int n = tid & 127;
            const int pb = (tid >> 7) * 4;
#pragma unroll
            for (int i = 0; i < 16; ++i) {
                const int p = pb + (i & 3) + (i >> 2) * 16;
                const float v = scr[n * 65 + p];
                const unsigned short hh = f2bfu(v);
                const int d = SWZ128(p, n);
                opB[0][d] = hh;
                opB[1][d] = f2bfu(v - bfu2f(hh));
            }
        }
        __syncthreads();

        // MFMA phase A: acc = C @ h0  (K=128)
        f32x4 acc[2];
        acc[0] = (f32x4){0.f, 0.f, 0.f, 0.f};
        acc[1] = (f32x4){0.f, 0.f, 0.f, 0.f};
#pragma unroll
        for (int kk = 0; kk < 4; ++kk) {
            const int k0 = kk * 32;
            const int ar = tt * 16 + lr;
            const bf16x8 ah = *(const bf16x8*)&CsA[0][SWZ128(ar, k0 + lk)];
            const bf16x8 al = *(const bf16x8*)&CsA[1][SWZ128(ar, k0 + lk)];
#pragma unroll
            for (int pt = 0; pt < 2; ++pt) {
                const int pc = (ph * 2 + pt) * 16 + lr;
                const bf16x8 bh = *(const bf16x8*)&opB[0][SWZ128(pc, k0 + lk)];
                const bf16x8 bl = *(const bf16x8*)&opB[1][SWZ128(pc, k0 + lk)];
                acc[pt] = __builtin_amdgcn_mfma_f32_16x16x32_bf16(ah, bh, acc[pt], 0, 0, 0);
                acc[pt] = __builtin_amdgcn_mfma_f32_16x16x32_bf16(ah, bl, acc[pt], 0, 0, 0);
                acc[pt] = __builtin_amdgcn_mfma_f32_16x16x32_bf16(al, bh, acc[pt], 0, 0, 0);
            }
        }
        // row scale by exp(l[t])
        {
            float el[4];
#pragma unroll
            for (int r = 0; r < 4; ++r) el[r] = __expf(ls4[e * 64 + tt * 16 + crow + r]);
#pragma unroll
            for (int pt = 0; pt < 2; ++pt)
#pragma unroll
                for (int r = 0; r < 4; ++r) acc[pt][r] *= el[r];
        }

        // stage x [64s][64p] into scr  +  form M hi/lo (swizzled Ms)
#pragma unroll
        for (int i = 0; i < 2; ++i) {
            const int l4 = tid + i * 512;      // 0..1023
            const int s = l4 >> 4, c4 = (l4 & 15) * 4;
            const float4 v = *(const float4*)&xh[(row0 + s) * DINNER + h * HEADDIM + c4];
            scr[s * 65 + c4 + 0] = v.x;
            scr[s * 65 + c4 + 1] = v.y;
            scr[s * 65 + c4 + 2] = v.z;
            scr[s * 65 + c4 + 3] = v.w;
        }
#pragma unroll
        for (int i = 0; i < 8; ++i) {
            const int lin = tid * 8 + i;
            const int t = lin >> 6, s = lin & 63;
            float m = 0.0f;
            if (s <= t)
                m = CBc[t * 64 + s] * dt4[e * 64 + s] * __expf(ls4[e * 64 + t] - ls4[e * 64 + s]);
            const unsigned short mh = f2bfu(m);
            const int d = SWZ64(t, s);
            Ms[0][d] = mh;
            Ms[1][d] = f2bfu(m - bfu2f(mh));
        }
        __syncthreads();

        // transpose-split x -> opB [p][s] (64-col rows), swizzled
        {
            const int s = tid & 63;
            const int pb = (tid >> 6) * 8;
#pragma unroll
            for (int i = 0; i < 8; ++i) {
                const int p = pb + i;
                const float v = scr[s * 65 + p];
                const unsigned short hh = f2bfu(v);
                const int d = SWZ64(p, s);
                opB[0][d] = hh;
                opB[1][d] = f2bfu(v - bfu2f(hh));
            }
        }
        __syncthreads();

        // MFMA phase B: acc += M @ x  (K=64)
#pragma unroll
        for (int kk = 0; kk < 2; ++kk) {
            const int k0 = kk * 32;
            const int ar = tt * 16 + lr;
            const bf16x8 ah = *(const bf16x8*)&Ms[0][SWZ64(ar, k0 + lk)];
            const bf16x8 al = *(const bf16x8*)&Ms[1][SWZ64(ar, k0 + lk)];
#pragma unroll
            for (int pt = 0; pt < 2; ++pt) {
                const int pc = (ph * 2 + pt) * 16 + lr;
                const bf16x8 bh = *(const bf16x8*)&opB[0][SWZ64(pc, k0 + lk)];
                const bf16x8 bl = *(const bf16x8*)&opB[1][SWZ64(pc, k0 + lk)];
                acc[pt] = __builtin_amdgcn_mfma_f32_16x16x32_bf16(ah, bh, acc[pt], 0, 0, 0);
                acc[pt] = __builtin_amdgcn_mfma_f32_16x16x32_bf16(ah, bl, acc[pt], 0, 0, 0);
                acc[pt] = __builtin_amdgcn_mfma_f32_16x16x32_bf16(al, bh, acc[pt], 0, 0, 0);
            }
        }

        // write y
#pragma unroll
        for (int pt = 0; pt < 2; ++pt)
#pragma unroll
            for (int r = 0; r < 4; ++r)
                yb[(row0 + tt * 16 + crow + r) * DINNER + h * HEADDIM + (ph * 2 + pt) * 16 + lr] = acc[pt][r];
        __syncthreads();
    }
}

// ---------------------------------------------------------------------------
// Gate + D-skip + RMSNorm; writes ynorm as split-bf16 planes. (unchanged)
// ---------------------------------------------------------------------------
__global__ __launch_bounds__(256)
void gate_kernel(const float* __restrict__ yb,
                 const float* __restrict__ xh,
                 const float* __restrict__ dskip,
                 const float* __restrict__ zx,
                 const float* __restrict__ nw,
                 unsigned short* __restrict__ yh,
                 unsigned short* __restrict__ yl)
{
    const int row = blockIdx.x;
    const int c4 = threadIdx.x * 4;

    float4 y = *(const float4*)&yb[(size_t)row * DINNER + c4];
    const float4 xv = *(const float4*)&xh[(size_t)row * DINNER + c4];
    const float dsk = dskip[c4 >> 6];
    y.x = fmaf(dsk, xv.x, y.x);
    y.y = fmaf(dsk, xv.y, y.y);
    y.z = fmaf(dsk, xv.z, y.z);
    y.w = fmaf(dsk, xv.w, y.w);

    const float4 z = *(const float4*)&zx[(size_t)row * DINPROJ + c4];
    float4 g;
    g.x = y.x * silu_f(z.x);
    g.y = y.y * silu_f(z.y);
    g.z = y.z * silu_f(z.z);
    g.w = y.w * silu_f(z.w);

    float local = g.x * g.x + g.y * g.y + g.z * g.z + g.w * g.w;
#pragma unroll
    for (int m = 32; m >= 1; m >>= 1) local += __shfl_xor(local, m, 64);

    __shared__ float red[4];
    if ((threadIdx.x & 63) == 0) red[threadIdx.x >> 6] = local;
    __syncthreads();
    const float total = red[0] + red[1] + red[2] + red[3];
    const float scale = rsqrtf(total * (1.0f / (float)DINNER) + 1e-5f);

    const float4 w = *(const float4*)&nw[c4];
    float o[4];
    o[0] = g.x * scale * w.x;
    o[1] = g.y * scale * w.y;
    o[2] = g.z * scale * w.z;
    o[3] = g.w * scale * w.w;

    unsigned hv[4], lv[4];
#pragma unroll
    for (int j = 0; j < 4; ++j) {
        hv[j] = f2bfu(o[j]);
        lv[j] = f2bfu(o[j] - bfu2f((unsigned short)hv[j]));
    }
    const size_t oi = (size_t)row * DINNER + c4;
    *(uint2*)&yh[oi] = make_uint2(hv[0] | (hv[1] << 16), hv[2] | (hv[3] << 16));
    *(uint2*)&yl[oi] = make_uint2(lv[0] | (lv[1] << 16), lv[2] | (lv[3] << 16));
}

// ---------------------------------------------------------------------------
extern "C" void kernel_launch(void* const* d_in, const int* in_sizes, int n_in,
                              void* d_out, int out_size, void* d_ws, size_t ws_size,
                              hipStream_t stream)
{
    const float* x_in    = (const float*)d_in[0];
    const float* in_w    = (const float*)d_in[1];
    const float* conv_w  = (const float*)d_in[2];
    const float* conv_b  = (const float*)d_in[3];
    const float* dt_bias = (const float*)d_in[4];
    const float* A_log   = (const float*)d_in[5];
    const float* D_skip  = (const float*)d_in[6];
    const float* norm_w  = (const float*)d_in[7];
    const float* out_w   = (const float*)d_in[8];
    float* out = (float*)d_out;

    float* ws   = (float*)d_ws;
    float* zx   = ws;                               // 19,005,440 f
    float* xh   = zx   + (size_t)ROWS * DINPROJ;    //  8,388,608 f
    float* Bb   = xh   + (size_t)ROWS * DINNER;     //  1,048,576 f
    float* Cb   = Bb   + (size_t)ROWS * DSTATE;     //  1,048,576 f
    float* dtb  = Cb   + (size_t)ROWS * DSTATE;     //    131,072 f
    float* dAb  = dtb  + (size_t)ROWS * NHEADS;     //    131,072 f
    float* yb   = dAb  + (size_t)ROWS * NHEADS;     //  8,388,608 f
    float* UN   = yb   + (size_t)ROWS * DINNER;     // 16,777,216 f (union)
    float* BtF  = UN   + (size_t)16777216;          //  1,245,184 f
    float* WtF  = BtF  + (size_t)1245184;           //    524,288 f
    float* ptot = WtF  + (size_t)524288;            //      2,048 f
    float* lB   = ptot + (size_t)2048;              //    131,072 f
    float* wB   = lB   + (size_t)131072;            //    131,072 f
    float* BTf  = wB   + (size_t)131072;            //  1,048,576 f
    float* Bspf = BTf  + (size_t)1048576;           //  1,048,576 f
    float* Cspf = Bspf + (size_t)1048576;           //  1,048,576 f
    float* CBb  = Cspf + (size_t)1048576;           //    524,288 f
    // total 60,622,848 f = 242.5 MB

    unsigned short* Ah = (unsigned short*)UN;                 // [8192][512]
    unsigned short* Al = Ah + (size_t)ROWS * DMODEL;
    float*          hloc = UN;                                // 16.78M f
    unsigned short* yh = (unsigned short*)UN;                 // [8192][1024]
    unsigned short* yl = yh + (size_t)ROWS * DINNER;

    unsigned short* Bth = (unsigned short*)BtF;               // [2432][512]
    unsigned short* Btl = Bth + (size_t)NPAD_IN * DMODEL;
    unsigned short* Wth = (unsigned short*)WtF;               // [512][1024]
    unsigned short* Wtl = Wth + (size_t)DMODEL * DINNER;

    unsigned short* BTh = (unsigned short*)BTf;               // [128][128][64]
    unsigned short* BTl = BTh + (size_t)128 * 8192;
    unsigned short* Bsph = (unsigned short*)Bspf;             // [8192][128]
    unsigned short* Bspl = Bsph + (size_t)ROWS * DSTATE;
    unsigned short* Csph = (unsigned short*)Cspf;             // [8192][128]
    unsigned short* Cspl = Csph + (size_t)ROWS * DSTATE;

    for (int layer = 0; layer < 2; ++layer) {
        const float* xl = (layer == 0) ? x_in : out;

        split_a_kernel<<<(ROWS * DMODEL) / (256 * 8), 256, 0, stream>>>(xl, Ah, Al);

        tsplit_w_kernel<<<dim3(NPAD_IN / 32, DMODEL / 32), 256, 0, stream>>>(
            in_w + (size_t)layer * DMODEL * DINPROJ, DMODEL, DINPROJ, Bth, Btl);

        // 2-pass everywhere except the dt block (cols >= 2304 get 3rd pass)
        gemm_bf16s<<<dim3(NPAD_IN / 128, ROWS / 128), 256, 0, stream>>>(
            Ah, Al, Bth, Btl, zx, DINPROJ, DINPROJ, DMODEL,
            DINNER + CONVDIM);

        conv_kernel<<<ROWS, CONVDIM / 4, 0, stream>>>(
            zx,
            conv_w + (size_t)layer * DCONV * CONVDIM,
            conv_b + (size_t)layer * CONVDIM,
            dt_bias + (size_t)layer * NHEADS,
            A_log + (size_t)layer * NHEADS,
            xh, Bb, Cb, dtb, dAb);

        meta_kernel<<<BATCH * NHEADS * NSEG, 64, 0, stream>>>(
            dtb, A_log + (size_t)layer * NHEADS, lB, wB, ptot);

        split_a_kernel<<<(ROWS * DSTATE) / (256 * 8), 256, 0, stream>>>(Bb, Bsph, Bspl);
        split_a_kernel<<<(ROWS * DSTATE) / (256 * 8), 256, 0, stream>>>(Cb, Csph, Cspl);

        tsplit_chunk_kernel<<<dim3(128 / 32, 64 / 32, BATCH * NSEG), 256, 0, stream>>>(
            Bb, TSEG, DSTATE, DSTATE, (size_t)TSEG * DSTATE, BTh, BTl);

        cb_kernel<<<BATCH * NSEG, 256, 0, stream>>>(Csph, Cspl, Bsph, Bspl, CBb);

        state_kernel<<<BATCH * NHEADS * NSEG, 256, 0, stream>>>(
            BTh, BTl, xh, wB, hloc);

        combine_kernel<<<BATCH * NHEADS * 8, 256, 0, stream>>>(hloc, ptot);

        y_kernel<<<BATCH * NSEG * 4, 512, 0, stream>>>(
            Csph, Cspl, CBb, lB, dtb, xh, hloc, yb);

        gate_kernel<<<ROWS, 256, 0, stream>>>(
            yb, xh, D_skip + (size_t)layer * NHEADS,
            zx, norm_w + (size_t)layer * DINNER, yh, yl);

        tsplit_w_kernel<<<dim3(DMODEL / 32, DINNER / 32), 256, 0, stream>>>(
            out_w + (size_t)layer * DINNER * DMODEL, DINNER, DMODEL, Wth, Wtl);

        // out-proj fully 2-pass (errors enter output linearly, ~0.4% rel)
        gemm_bf16s<<<dim3(DMODEL / 128, ROWS / 128), 256, 0, stream>>>(
            yh, yl, Wth, Wtl, out, DMODEL, DMODEL, DINNER,
            1 << 30);
    }
}

// Round 14
// 541.456 us; speedup vs baseline: 1.4649x; 1.0492x over previous
//
#include <hip/hip_runtime.h>
#include <hip/hip_bf16.h>
#include <cstddef>
#include <cstdint>

// Mamba2 (2 layers). GEMMs via split-bf16 MFMA; 2-pass (A*Bh) everywhere
// except the dt column block (3rd AhBl pass). XCD-chunked block swizzle.
// Round-14: K-loop software rotation — global loads for iter k+1 are issued
// AFTER the second barrier and BEFORE the MFMA of iter k, so HBM latency
// hides under compute (previously every K-step serialized a full vmcnt(0)
// drain of just-issued loads). Scan via chunked SSD, LDS tiles T2-swizzled.

#define BATCH 4
#define SEQ   2048
#define DMODEL 512
#define DINNER 1024
#define DSTATE 128
#define HEADDIM 64
#define NHEADS 16
#define DCONV 4
#define CONVDIM 1280
#define DINPROJ 2320
#define NPAD_IN 2432          // 19 * 128
#define ROWS (BATCH * SEQ)    // 8192
#define NSEG 32               // chunks per sequence
#define TSEG 64               // chunk length

// swizzled index into a [rows][32/64/128]-ushort LDS tile (16B-slot XOR)
#define SWZ32(r, c)  ((r) * 32  + (((((c) >> 3) ^ (((r) >> 1) & 3)) << 3) | ((c) & 7)))
#define SWZ64(r, c)  ((r) * 64  + (((((c) >> 3) ^ ((r) & 7)) << 3) | ((c) & 7)))
#define SWZ128(r, c) ((r) * 128 + (((((c) >> 3) ^ ((r) & 7)) << 3) | ((c) & 7)))

typedef __attribute__((ext_vector_type(8))) short bf16x8;
typedef __attribute__((ext_vector_type(4))) float f32x4;

__device__ __forceinline__ float silu_f(float x) {
    return x * (1.0f / (1.0f + __expf(-x)));
}
__device__ __forceinline__ unsigned short f2bfu(float f) {  // RNE fp32->bf16
    unsigned u = __float_as_uint(f);
    unsigned r = u + 0x7FFFu + ((u >> 16) & 1u);
    return (unsigned short)(r >> 16);
}
__device__ __forceinline__ float bfu2f(unsigned short h) {
    return __uint_as_float(((unsigned)h) << 16);
}

// ---------------------------------------------------------------------------
// Split fp32 flat array -> hi/lo bf16. 8 elems/thread.
// ---------------------------------------------------------------------------
__global__ __launch_bounds__(256)
void split_a_kernel(const float* __restrict__ A,
                    unsigned short* __restrict__ Ah,
                    unsigned short* __restrict__ Al)
{
    const size_t i = ((size_t)blockIdx.x * 256 + threadIdx.x) * 8;
    const float4 a = *(const float4*)&A[i];
    const float4 b = *(const float4*)&A[i + 4];
    float v[8] = {a.x, a.y, a.z, a.w, b.x, b.y, b.z, b.w};
    unsigned hv[8], lv[8];
#pragma unroll
    for (int j = 0; j < 8; ++j) {
        hv[j] = f2bfu(v[j]);
        lv[j] = f2bfu(v[j] - bfu2f((unsigned short)hv[j]));
    }
    uint4 ph = make_uint4(hv[0] | (hv[1] << 16), hv[2] | (hv[3] << 16),
                          hv[4] | (hv[5] << 16), hv[6] | (hv[7] << 16));
    uint4 pl = make_uint4(lv[0] | (lv[1] << 16), lv[2] | (lv[3] << 16),
                          lv[4] | (lv[5] << 16), lv[6] | (lv[7] << 16));
    *(uint4*)&Ah[i] = ph;
    *(uint4*)&Al[i] = pl;
}

// ---------------------------------------------------------------------------
// Transpose + split weight W[K][N] fp32 -> Oh/Ol[Npad][K] bf16 (n >= N -> 0).
// ---------------------------------------------------------------------------
__global__ __launch_bounds__(256)
void tsplit_w_kernel(const float* __restrict__ W, int K, int N,
                     unsigned short* __restrict__ Oh,
                     unsigned short* __restrict__ Ol)
{
    __shared__ float tile[32][33];
    const int n0 = blockIdx.x * 32, k0 = blockIdx.y * 32;
    const int c = threadIdx.x & 31, r8 = threadIdx.x >> 5;
    const int n = n0 + c;
#pragma unroll
    for (int i = 0; i < 4; ++i) {
        const int k = r8 + i * 8;
        float v = 0.0f;
        if (n < N) v = W[(size_t)(k0 + k) * N + n];
        tile[c][k] = v;
    }
    __syncthreads();
#pragma unroll
    for (int i = 0; i < 4; ++i) {
        const int nl = r8 + i * 8;
        const float v = tile[nl][c];
        const unsigned short h = f2bfu(v);
        const unsigned short l = f2bfu(v - bfu2f(h));
        const size_t o = (size_t)(n0 + nl) * K + k0 + c;
        Oh[o] = h;
        Ol[o] = l;
    }
}

// ---------------------------------------------------------------------------
// Chunked transpose+split: per z, fp32 [K][N] (rowstride rs) -> bf16 [N][K].
// ---------------------------------------------------------------------------
__global__ __launch_bounds__(256)
void tsplit_chunk_kernel(const float* __restrict__ src, int K, int N, int rs,
                         size_t chunkStride,
                         unsigned short* __restrict__ Oh,
                         unsigned short* __restrict__ Ol)
{
    __shared__ float tile[32][33];
    const int z = blockIdx.z;
    const float* W = src + (size_t)z * chunkStride;
    const int n0 = blockIdx.x * 32, k0 = blockIdx.y * 32;
    const int c = threadIdx.x & 31, r8 = threadIdx.x >> 5;
#pragma unroll
    for (int i = 0; i < 4; ++i) {
        const int k = r8 + i * 8;
        tile[c][k] = W[(size_t)(k0 + k) * rs + n0 + c];
    }
    __syncthreads();
#pragma unroll
    for (int i = 0; i < 4; ++i) {
        const int nl = r8 + i * 8;
        const float v = tile[nl][c];
        const unsigned short h = f2bfu(v);
        const unsigned short l = f2bfu(v - bfu2f(h));
        const size_t o = (size_t)z * N * K + (size_t)(n0 + nl) * K + k0 + c;
        Oh[o] = h;
        Ol[o] = l;
    }
}

// ---------------------------------------------------------------------------
// Split-bf16 MFMA GEMM. 2-pass C = (Ah+Al)*Bh; blocks with col0+128 >
// exactCol0 add the AhBl pass. XCD-chunked swizzle. Rotated K-loop:
// next-iter loads issued before MFMA so latency hides under compute.
// ---------------------------------------------------------------------------
__global__ __launch_bounds__(256)
void gemm_bf16s(const unsigned short* __restrict__ Ah,
                const unsigned short* __restrict__ Al,
                const unsigned short* __restrict__ Bh,
                const unsigned short* __restrict__ Bl,
                float* __restrict__ C, int ldc, int N, int K,
                int exactCol0)
{
    __shared__ __align__(16) unsigned short As[2][128 * 32];
    __shared__ __align__(16) unsigned short Bs[2][128 * 32];

    const int tid = threadIdx.x;
    const int w = tid >> 6, lane = tid & 63;
    const int wm = w >> 1, wn = w & 1;

    // XCD-aware bijective remap (requires nwg % 8 == 0)
    const int nwg = gridDim.x * gridDim.y;
    int flat = blockIdx.y * gridDim.x + blockIdx.x;
    flat = (flat & 7) * (nwg >> 3) + (flat >> 3);
    const int bx = flat % gridDim.x, by = flat / gridDim.x;
    const int row0 = by * 128, col0 = bx * 128;
    const bool exact = (col0 + 128 > exactCol0);

    const int srow = tid >> 1;
    const int sk   = (tid & 1) * 16;

    const int lr = lane & 15;
    const int lk = (lane >> 4) * 8;

    f32x4 acc[4][4];
#pragma unroll
    for (int i = 0; i < 4; ++i)
#pragma unroll
        for (int j = 0; j < 4; ++j) acc[i][j] = (f32x4){0.f, 0.f, 0.f, 0.f};

    const int sw0 = SWZ32(srow, sk);
    const int sw1 = SWZ32(srow, sk + 8);
    const size_t gabase = (size_t)(row0 + srow) * K + sk;
    const size_t gbbase = (size_t)(col0 + srow) * K + sk;

    // preload iter 0
    uint4 vah0 = *(const uint4*)&Ah[gabase];
    uint4 vah1 = *(const uint4*)&Ah[gabase + 8];
    uint4 val0 = *(const uint4*)&Al[gabase];
    uint4 val1 = *(const uint4*)&Al[gabase + 8];
    uint4 vbh0 = *(const uint4*)&Bh[gbbase];
    uint4 vbh1 = *(const uint4*)&Bh[gbbase + 8];

    for (int k0 = 0; k0 < K; k0 += 32) {
        __syncthreads();                      // previous iter's LDS readers done
        *(uint4*)&As[0][sw0] = vah0;  *(uint4*)&As[0][sw1] = vah1;
        *(uint4*)&As[1][sw0] = val0;  *(uint4*)&As[1][sw1] = val1;
        *(uint4*)&Bs[0][sw0] = vbh0;  *(uint4*)&Bs[0][sw1] = vbh1;
        if (exact) {
            const size_t gb = gbbase + k0;
            *(uint4*)&Bs[1][sw0] = *(const uint4*)&Bl[gb];
            *(uint4*)&Bs[1][sw1] = *(const uint4*)&Bl[gb + 8];
        }
        __syncthreads();                      // staging visible

        // issue next-iter loads NOW; they stay in flight across the MFMAs
        if (k0 + 32 < K) {
            const size_t ga = gabase + k0 + 32;
            const size_t gb = gbbase + k0 + 32;
            vah0 = *(const uint4*)&Ah[ga];
            vah1 = *(const uint4*)&Ah[ga + 8];
            val0 = *(const uint4*)&Al[ga];
            val1 = *(const uint4*)&Al[ga + 8];
            vbh0 = *(const uint4*)&Bh[gb];
            vbh1 = *(const uint4*)&Bh[gb + 8];
        }

        bf16x8 a_h[4], a_l[4], b_h[4];
#pragma unroll
        for (int mt = 0; mt < 4; ++mt) {
            const int r = wm * 64 + mt * 16 + lr;
            a_h[mt] = *(const bf16x8*)&As[0][SWZ32(r, lk)];
            a_l[mt] = *(const bf16x8*)&As[1][SWZ32(r, lk)];
        }
#pragma unroll
        for (int nt = 0; nt < 4; ++nt) {
            const int c = wn * 64 + nt * 16 + lr;
            b_h[nt] = *(const bf16x8*)&Bs[0][SWZ32(c, lk)];
        }
#pragma unroll
        for (int mt = 0; mt < 4; ++mt)
#pragma unroll
            for (int nt = 0; nt < 4; ++nt) {
                acc[mt][nt] = __builtin_amdgcn_mfma_f32_16x16x32_bf16(a_h[mt], b_h[nt], acc[mt][nt], 0, 0, 0);
                acc[mt][nt] = __builtin_amdgcn_mfma_f32_16x16x32_bf16(a_l[mt], b_h[nt], acc[mt][nt], 0, 0, 0);
            }
        if (exact) {
            bf16x8 b_l[4];
#pragma unroll
            for (int nt = 0; nt < 4; ++nt) {
                const int c = wn * 64 + nt * 16 + lr;
                b_l[nt] = *(const bf16x8*)&Bs[1][SWZ32(c, lk)];
            }
#pragma unroll
            for (int mt = 0; mt < 4; ++mt)
#pragma unroll
                for (int nt = 0; nt < 4; ++nt)
                    acc[mt][nt] = __builtin_amdgcn_mfma_f32_16x16x32_bf16(a_h[mt], b_l[nt], acc[mt][nt], 0, 0, 0);
        }
    }

    const int crow = (lane >> 4) * 4;
#pragma unroll
    for (int mt = 0; mt < 4; ++mt)
#pragma unroll
        for (int nt = 0; nt < 4; ++nt) {
            const int cc = col0 + wn * 64 + nt * 16 + lr;
            if (cc < N) {
#pragma unroll
                for (int r = 0; r < 4; ++r)
                    C[(size_t)(row0 + wm * 64 + mt * 16 + crow + r) * ldc + cc] = acc[mt][nt][r];
            }
        }
}

// ---------------------------------------------------------------------------
// Depthwise causal conv (4 taps) + bias + SiLU + dt/dA precompute. (unchanged)
// ---------------------------------------------------------------------------
__global__ __launch_bounds__(320)
void conv_kernel(const float* __restrict__ zx,
                 const float* __restrict__ cw,
                 const float* __restrict__ cb,
                 const float* __restrict__ dtbias,
                 const float* __restrict__ alog,
                 float* __restrict__ xh,
                 float* __restrict__ Bb,
                 float* __restrict__ Cb,
                 float* __restrict__ dtb,
                 float* __restrict__ dAb)
{
    const int row = blockIdx.x;
    const int l   = row & (SEQ - 1);
    const int c4  = threadIdx.x * 4;

    float4 acc = *(const float4*)&cb[c4];
#pragma unroll
    for (int k = 0; k < DCONV; ++k) {
        const int lk = l - (DCONV - 1) + k;
        if (lk >= 0) {
            const float4 v = *(const float4*)&zx[(size_t)(row - (DCONV - 1) + k) * DINPROJ + DINNER + c4];
            const float4 w = *(const float4*)&cw[k * CONVDIM + c4];
            acc.x = fmaf(v.x, w.x, acc.x);
            acc.y = fmaf(v.y, w.y, acc.y);
            acc.z = fmaf(v.z, w.z, acc.z);
            acc.w = fmaf(v.w, w.w, acc.w);
        }
    }
    acc.x = silu_f(acc.x);
    acc.y = silu_f(acc.y);
    acc.z = silu_f(acc.z);
    acc.w = silu_f(acc.w);

    if (c4 < DINNER) {
        *(float4*)&xh[(size_t)row * DINNER + c4] = acc;
    } else if (c4 < DINNER + DSTATE) {
        *(float4*)&Bb[(size_t)row * DSTATE + (c4 - DINNER)] = acc;
    } else {
        *(float4*)&Cb[(size_t)row * DSTATE + (c4 - DINNER - DSTATE)] = acc;
    }

    if (threadIdx.x < NHEADS) {
        const int hh = threadIdx.x;
        const float raw = zx[(size_t)row * DINPROJ + (DINNER + CONVDIM) + hh] + dtbias[hh];
        const float dtv = (raw > 20.0f) ? raw : log1pf(expf(raw));
        const float a = expf(alog[hh]);
        dtb[row * NHEADS + hh] = dtv;
        dAb[row * NHEADS + hh] = expf(-a * dtv);
    }
}

// ---------------------------------------------------------------------------
// meta: per (b,h,chunk) wave: l[t] = inclusive cumsum(-a*dt); w; ptot.
// ---------------------------------------------------------------------------
__global__ __launch_bounds__(64)
void meta_kernel(const float* __restrict__ dtb,
                 const float* __restrict__ alog,
                 float* __restrict__ lB, float* __restrict__ wB,
                 float* __restrict__ ptot)
{
    const int bhc = blockIdx.x;
    const int chunk = bhc & 31;
    const int h = (bhc >> 5) & 15;
    const int b = bhc >> 9;
    const int t = threadIdx.x;
    const size_t row0 = (size_t)b * SEQ + (size_t)chunk * TSEG;

    const float a = __expf(alog[h]);
    const float dtv = dtb[(row0 + t) * NHEADS + h];
    float v = -a * dtv;
#pragma unroll
    for (int off = 1; off < 64; off <<= 1) {
        const float u = __shfl_up(v, off, 64);
        if (t >= off) v += u;
    }
    const float l63 = __shfl(v, 63, 64);
    lB[(size_t)bhc * 64 + t] = v;
    wB[(size_t)bhc * 64 + t] = __expf(l63 - v) * dtv;
    if (t == 0) ptot[bhc] = __expf(l63);
}

// ---------------------------------------------------------------------------
// cb: CB[t][s] = C_chunk @ B_chunk^T per (b,chunk). Swizzled (SWZ128).
// ---------------------------------------------------------------------------
__global__ __launch_bounds__(256)
void cb_kernel(const unsigned short* __restrict__ Ch,
               const unsigned short* __restrict__ Cl,
               const unsigned short* __restrict__ Bh_,
               const unsigned short* __restrict__ Bl_,
               float* __restrict__ CBo)
{
    __shared__ __align__(16) unsigned short Cs[2][64 * 128];
    __shared__ __align__(16) unsigned short Bs2[2][64 * 128];
    const int bc = blockIdx.x;
    const size_t base = (size_t)bc * 8192;
    const int tid = threadIdx.x;
#pragma unroll
    for (int i = 0; i < 4; ++i) {
        const int bi = tid + i * 256;           // 16B block 0..1023
        const int r = bi >> 4, c = (bi & 15) << 3;
        const int d = SWZ128(r, c);
        *(uint4*)&Cs[0][d]  = ((const uint4*)(Ch  + base))[bi];
        *(uint4*)&Cs[1][d]  = ((const uint4*)(Cl  + base))[bi];
        *(uint4*)&Bs2[0][d] = ((const uint4*)(Bh_ + base))[bi];
        *(uint4*)&Bs2[1][d] = ((const uint4*)(Bl_ + base))[bi];
    }
    __syncthreads();

    const int w = tid >> 6, lane = tid & 63;
    const int lr = lane & 15, lk = (lane >> 4) * 8;
    f32x4 acc[4];
#pragma unroll
    for (int i = 0; i < 4; ++i) acc[i] = (f32x4){0.f, 0.f, 0.f, 0.f};

#pragma unroll
    for (int kk = 0; kk < 4; ++kk) {
        const int k0 = kk * 32;
        const int ar = w * 16 + lr;
        const bf16x8 ah = *(const bf16x8*)&Cs[0][SWZ128(ar, k0 + lk)];
        const bf16x8 al = *(const bf16x8*)&Cs[1][SWZ128(ar, k0 + lk)];
#pragma unroll
        for (int st = 0; st < 4; ++st) {
            const int br = st * 16 + lr;
            const bf16x8 bh = *(const bf16x8*)&Bs2[0][SWZ128(br, k0 + lk)];
            const bf16x8 bl = *(const bf16x8*)&Bs2[1][SWZ128(br, k0 + lk)];
            acc[st] = __builtin_amdgcn_mfma_f32_16x16x32_bf16(ah, bh, acc[st], 0, 0, 0);
            acc[st] = __builtin_amdgcn_mfma_f32_16x16x32_bf16(ah, bl, acc[st], 0, 0, 0);
            acc[st] = __builtin_amdgcn_mfma_f32_16x16x32_bf16(al, bh, acc[st], 0, 0, 0);
        }
    }
    const int crow = (lane >> 4) * 4;
#pragma unroll
    for (int st = 0; st < 4; ++st)
#pragma unroll
        for (int r = 0; r < 4; ++r)
            CBo[(size_t)bc * 4096 + (size_t)(w * 16 + crow + r) * 64 + st * 16 + lr] = acc[st][r];
}

// ---------------------------------------------------------------------------
// state: S[n][p] = sum_t (B[t,n]*w[t]) * x[t,p] per (b,h,chunk). Swizzled.
// ---------------------------------------------------------------------------
__global__ __launch_bounds__(256)
void state_kernel(const unsigned short* __restrict__ BTh,
                  const unsigned short* __restrict__ BTl,
                  const float* __restrict__ xh,
                  const float* __restrict__ wB,
                  float* __restrict__ hloc)
{
    __shared__ __align__(16) unsigned short BTs[2][128 * 64];
    __shared__ float xsf[64 * 65];
    __shared__ __align__(16) unsigned short xwT[2][64 * 64];
    __shared__ float wsl[64];

    const int bhc = blockIdx.x;
    const int chunk = bhc & 31;
    const int h = (bhc >> 5) & 15;
    const int b = bhc >> 9;
    const int bc = b * 32 + chunk;
    const size_t row0 = (size_t)b * SEQ + (size_t)chunk * TSEG;
    const int tid = threadIdx.x;

    const size_t bbase = (size_t)bc * 8192;
#pragma unroll
    for (int i = 0; i < 4; ++i) {
        const int bi = tid + i * 256;           // 16B block 0..1023
        const int r = bi >> 3, c = (bi & 7) << 3;
        const int d = SWZ64(r, c);
        *(uint4*)&BTs[0][d] = ((const uint4*)(BTh + bbase))[bi];
        *(uint4*)&BTs[1][d] = ((const uint4*)(BTl + bbase))[bi];
    }
#pragma unroll
    for (int i = 0; i < 4; ++i) {
        const int l4 = tid + i * 256;           // 0..1023
        const int s = l4 >> 4, c4 = (l4 & 15) * 4;
        const float4 v = *(const float4*)&xh[(row0 + s) * DINNER + h * HEADDIM + c4];
        xsf[s * 65 + c4 + 0] = v.x;
        xsf[s * 65 + c4 + 1] = v.y;
        xsf[s * 65 + c4 + 2] = v.z;
        xsf[s * 65 + c4 + 3] = v.w;
    }
    if (tid < 64) wsl[tid] = wB[(size_t)bhc * 64 + tid];
    __syncthreads();

    {
        const int t = tid & 63;
        const int pb = (tid >> 6) * 16;
#pragma unroll
        for (int i = 0; i < 16; ++i) {
            const int p = pb + i;
            const float v = xsf[t * 65 + p] * wsl[t];
            const unsigned short hh = f2bfu(v);
            const int d = SWZ64(p, t);
            xwT[0][d] = hh;
            xwT[1][d] = f2bfu(v - bfu2f(hh));
        }
    }
    __syncthreads();

    const int w = tid >> 6, lane = tid & 63;
    const int lr = lane & 15, lk = (lane >> 4) * 8;
    f32x4 acc[2][4];
#pragma unroll
    for (int i = 0; i < 2; ++i)
#pragma unroll
        for (int j = 0; j < 4; ++j) acc[i][j] = (f32x4){0.f, 0.f, 0.f, 0.f};

#pragma unroll
    for (int kk = 0; kk < 2; ++kk) {
        const int k0 = kk * 32;
        bf16x8 ah[2], al[2];
#pragma unroll
        for (int nt = 0; nt < 2; ++nt) {
            const int n = w * 32 + nt * 16 + lr;
            ah[nt] = *(const bf16x8*)&BTs[0][SWZ64(n, k0 + lk)];
            al[nt] = *(const bf16x8*)&BTs[1][SWZ64(n, k0 + lk)];
        }
#pragma unroll
        for (int pt = 0; pt < 4; ++pt) {
            const int pr = pt * 16 + lr;
            const bf16x8 bh = *(const bf16x8*)&xwT[0][SWZ64(pr, k0 + lk)];
            const bf16x8 bl = *(const bf16x8*)&xwT[1][SWZ64(pr, k0 + lk)];
#pragma unroll
            for (int nt = 0; nt < 2; ++nt) {
                acc[nt][pt] = __builtin_amdgcn_mfma_f32_16x16x32_bf16(ah[nt], bh, acc[nt][pt], 0, 0, 0);
                acc[nt][pt] = __builtin_amdgcn_mfma_f32_16x16x32_bf16(ah[nt], bl, acc[nt][pt], 0, 0, 0);
                acc[nt][pt] = __builtin_amdgcn_mfma_f32_16x16x32_bf16(al[nt], bh, acc[nt][pt], 0, 0, 0);
            }
        }
    }

    const int crow = (lane >> 4) * 4;
#pragma unroll
    for (int nt = 0; nt < 2; ++nt)
#pragma unroll
        for (int pt = 0; pt < 4; ++pt)
#pragma unroll
            for (int r = 0; r < 4; ++r) {
                const int n = w * 32 + nt * 16 + crow + r;
                hloc[(size_t)bhc * 8192 + (size_t)n * 64 + pt * 16 + lr] = acc[nt][pt][r];
            }
}

// ---------------------------------------------------------------------------
// combine: sequential over 32 chunks (in-place: hloc becomes h0). (unchanged)
// ---------------------------------------------------------------------------
__global__ __launch_bounds__(256)
void combine_kernel(float* __restrict__ hloc,
                    const float* __restrict__ ptot)
{
    const int bid = blockIdx.x;
    const int bh = bid >> 3;
    const int chunk = bid & 7;
    const int e0 = chunk * 1024 + threadIdx.x * 4;

    float4 s = make_float4(0.f, 0.f, 0.f, 0.f);
    for (int k = 0; k < NSEG; ++k) {
        float* p = &hloc[((size_t)bh * NSEG + k) * (DSTATE * HEADDIM) + e0];
        const float4 v = *(const float4*)p;
        *(float4*)p = s;
        const float pt = ptot[bh * NSEG + k];
        s.x = fmaf(pt, s.x, v.x);
        s.y = fmaf(pt, s.y, v.y);
        s.z = fmaf(pt, s.z, v.z);
        s.w = fmaf(pt, s.w, v.w);
    }
}

// ---------------------------------------------------------------------------
// y: per (b,chunk,headgroup-of-4), 512 thr. Swizzled (SWZ128/SWZ64).
// ---------------------------------------------------------------------------
__global__ __launch_bounds__(512)
void y_kernel(const unsigned short* __restrict__ Ch,
              const unsigned short* __restrict__ Cl,
              const float* __restrict__ CBg,
              const float* __restrict__ lB,
              const float* __restrict__ dtb,
              const float* __restrict__ xh,
              const float* __restrict__ hloc,
              float* __restrict__ yb)
{
    __shared__ __align__(16) unsigned short CsA[2][64 * 128];  // C [t][n]
    __shared__ float scr[128 * 65];                            // padded scratch
    __shared__ __align__(16) unsigned short opB[2][64 * 128];  // phaseA h0T / phaseB xT
    __shared__ __align__(16) unsigned short Ms[2][64 * 64];    // M [t][s]
    __shared__ float ls4[256], dt4[256];

    const int gid = blockIdx.x;
    const int hg = gid & 3, bc = gid >> 2;
    const int chunk = bc & 31, b = bc >> 5;
    const size_t row0 = (size_t)b * SEQ + (size_t)chunk * TSEG;
    const int tid = threadIdx.x;

    const size_t cbase = (size_t)bc * 8192;
#pragma unroll
    for (int i = 0; i < 2; ++i) {
        const int bi = tid + i * 512;           // 16B block 0..1023
        const int r = bi >> 4, c = (bi & 15) << 3;
        const int d = SWZ128(r, c);
        *(uint4*)&CsA[0][d] = ((const uint4*)(Ch + cbase))[bi];
        *(uint4*)&CsA[1][d] = ((const uint4*)(Cl + cbase))[bi];
    }
    if (tid < 256) {
        const int e = tid >> 6, t = tid & 63;
        const int h = hg * 4 + e;
        const int bhc = (b * NHEADS + h) * NSEG + chunk;
        ls4[tid] = lB[(size_t)bhc * 64 + t];
        dt4[tid] = dtb[(row0 + t) * NHEADS + h];
    }
    __syncthreads();

    const int w = tid >> 6, lane = tid & 63;
    const int lr = lane & 15, lk = (lane >> 4) * 8;
    const int tt = w & 3, ph = w >> 2;
    const int crow = (lane >> 4) * 4;
    const float* CBc = CBg + (size_t)bc * 4096;

    for (int e = 0; e < 4; ++e) {
        const int h = hg * 4 + e;
        const int bhc = (b * NHEADS + h) * NSEG + chunk;
        const float* h0p = hloc + (size_t)bhc * 8192;

        // stage h0 (n-major [128][64]) into padded scr
#pragma unroll
        for (int i = 0; i < 4; ++i) {
            const int l4 = tid + i * 512;      // 0..2047
            const int n = l4 >> 4, c4 = (l4 & 15) * 4;
            const float4 v = *(const float4*)&h0p[(size_t)l4 * 4];
            scr[n * 65 + c4 + 0] = v.x;
            scr[n * 65 + c4 + 1] = v.y;
            scr[n * 65 + c4 + 2] = v.z;
            scr[n * 65 + c4 + 3] = v.w;
        }
        __syncthreads();

        // transpose-split h0 -> opB [p][n] (k=n contig), swizzled
        {
            const int n = tid & 127;
            const int pb = (tid >> 7) * 4;
#pragma unroll
            for (int i = 0; i < 16; ++i) {
                const int p = pb + (i & 3) + (i >> 2) * 16;
                const float v = scr[n * 65 + p];
                const unsigned short hh = f2bfu(v);
                const int d = SWZ128(p, n);
                opB[0][d] = hh;
                opB[1][d] = f2bfu(v - bfu2f(hh));
            }
        }
        __syncthreads();

        // MFMA phase A: acc = C @ h0  (K=128)
        f32x4 acc[2];
        acc[0] = (f32x4){0.f, 0.f, 0.f, 0.f};
        acc[1] = (f32x4){0.f, 0.f, 0.f, 0.f};
#pragma unroll
        for (int kk = 0; kk < 4; ++kk) {
            const int k0 = kk * 32;
            const int ar = tt * 16 + lr;
            const bf16x8 ah = *(const bf16x8*)&CsA[0][SWZ128(ar, k0 + lk)];
            const bf16x8 al = *(const bf16x8*)&CsA[1][SWZ128(ar, k0 + lk)];
#pragma unroll
            for (int pt = 0; pt < 2; ++pt) {
                const int pc = (ph * 2 + pt) * 16 + lr;
                const bf16x8 bh = *(const bf16x8*)&opB[0][SWZ128(pc, k0 + lk)];
                const bf16x8 bl = *(const bf16x8*)&opB[1][SWZ128(pc, k0 + lk)];
                acc[pt] = __builtin_amdgcn_mfma_f32_16x16x32_bf16(ah, bh, acc[pt], 0, 0, 0);
                acc[pt] = __builtin_amdgcn_mfma_f32_16x16x32_bf16(ah, bl, acc[pt], 0, 0, 0);
                acc[pt] = __builtin_amdgcn_mfma_f32_16x16x32_bf16(al, bh, acc[pt], 0, 0, 0);
            }
        }
        // row scale by exp(l[t])
        {
            float el[4];
#pragma unroll
            for (int r = 0; r < 4; ++r) el[r] = __expf(ls4[e * 64 + tt * 16 + crow + r]);
#pragma unroll
            for (int pt = 0; pt < 2; ++pt)
#pragma unroll
                for (int r = 0; r < 4; ++r) acc[pt][r] *= el[r];
        }

        // stage x [64s][64p] into scr  +  form M hi/lo (swizzled Ms)
#pragma unroll
        for (int i = 0; i < 2; ++i) {
            const int l4 = tid + i * 512;      // 0..1023
            const int s = l4 >> 4, c4 = (l4 & 15) * 4;
            const float4 v = *(const float4*)&xh[(row0 + s) * DINNER + h * HEADDIM + c4];
            scr[s * 65 + c4 + 0] = v.x;
            scr[s * 65 + c4 + 1] = v.y;
            scr[s * 65 + c4 + 2] = v.z;
            scr[s * 65 + c4 + 3] = v.w;
        }
#pragma unroll
        for (int i = 0; i < 8; ++i) {
            const int lin = tid * 8 + i;
            const int t = lin >> 6, s = lin & 63;
            float m = 0.0f;
            if (s <= t)
                m = CBc[t * 64 + s] * dt4[e * 64 + s] * __expf(ls4[e * 64 + t] - ls4[e * 64 + s]);
            const unsigned short mh = f2bfu(m);
            const int d = SWZ64(t, s);
            Ms[0][d] = mh;
            Ms[1][d] = f2bfu(m - bfu2f(mh));
        }
        __syncthreads();

        // transpose-split x -> opB [p][s] (64-col rows), swizzled
        {
            const int s = tid & 63;
            const int pb = (tid >> 6) * 8;
#pragma unroll
            for (int i = 0; i < 8; ++i) {
                const int p = pb + i;
                const float v = scr[s * 65 + p];
                const unsigned short hh = f2bfu(v);
                const int d = SWZ64(p, s);
                opB[0][d] = hh;
                opB[1][d] = f2bfu(v - bfu2f(hh));
            }
        }
        __syncthreads();

        // MFMA phase B: acc += M @ x  (K=64)
#pragma unroll
        for (int kk = 0; kk < 2; ++kk) {
            const int k0 = kk * 32;
            const int ar = tt * 16 + lr;
            const bf16x8 ah = *(const bf16x8*)&Ms[0][SWZ64(ar, k0 + lk)];
            const bf16x8 al = *(const bf16x8*)&Ms[1][SWZ64(ar, k0 + lk)];
#pragma unroll
            for (int pt = 0; pt < 2; ++pt) {
                const int pc = (ph * 2 + pt) * 16 + lr;
                const bf16x8 bh = *(const bf16x8*)&opB[0][SWZ64(pc, k0 + lk)];
                const bf16x8 bl = *(const bf16x8*)&opB[1][SWZ64(pc, k0 + lk)];
                acc[pt] = __builtin_amdgcn_mfma_f32_16x16x32_bf16(ah, bh, acc[pt], 0, 0, 0);
                acc[pt] = __builtin_amdgcn_mfma_f32_16x16x32_bf16(ah, bl, acc[pt], 0, 0, 0);
                acc[pt] = __builtin_amdgcn_mfma_f32_16x16x32_bf16(al, bh, acc[pt], 0, 0, 0);
            }
        }

        // write y
#pragma unroll
        for (int pt = 0; pt < 2; ++pt)
#pragma unroll
            for (int r = 0; r < 4; ++r)
                yb[(row0 + tt * 16 + crow + r) * DINNER + h * HEADDIM + (ph * 2 + pt) * 16 + lr] = acc[pt][r];
        __syncthreads();
    }
}

// ---------------------------------------------------------------------------
// Gate + D-skip + RMSNorm; writes ynorm as split-bf16 planes. (unchanged)
// ---------------------------------------------------------------------------
__global__ __launch_bounds__(256)
void gate_kernel(const float* __restrict__ yb,
                 const float* __restrict__ xh,
                 const float* __restrict__ dskip,
                 const float* __restrict__ zx,
                 const float* __restrict__ nw,
                 unsigned short* __restrict__ yh,
                 unsigned short* __restrict__ yl)
{
    const int row = blockIdx.x;
    const int c4 = threadIdx.x * 4;

    float4 y = *(const float4*)&yb[(size_t)row * DINNER + c4];
    const float4 xv = *(const float4*)&xh[(size_t)row * DINNER + c4];
    const float dsk = dskip[c4 >> 6];
    y.x = fmaf(dsk, xv.x, y.x);
    y.y = fmaf(dsk, xv.y, y.y);
    y.z = fmaf(dsk, xv.z, y.z);
    y.w = fmaf(dsk, xv.w, y.w);

    const float4 z = *(const float4*)&zx[(size_t)row * DINPROJ + c4];
    float4 g;
    g.x = y.x * silu_f(z.x);
    g.y = y.y * silu_f(z.y);
    g.z = y.z * silu_f(z.z);
    g.w = y.w * silu_f(z.w);

    float local = g.x * g.x + g.y * g.y + g.z * g.z + g.w * g.w;
#pragma unroll
    for (int m = 32; m >= 1; m >>= 1) local += __shfl_xor(local, m, 64);

    __shared__ float red[4];
    if ((threadIdx.x & 63) == 0) red[threadIdx.x >> 6] = local;
    __syncthreads();
    const float total = red[0] + red[1] + red[2] + red[3];
    const float scale = rsqrtf(total * (1.0f / (float)DINNER) + 1e-5f);

    const float4 w = *(const float4*)&nw[c4];
    float o[4];
    o[0] = g.x * scale * w.x;
    o[1] = g.y * scale * w.y;
    o[2] = g.z * scale * w.z;
    o[3] = g.w * scale * w.w;

    unsigned hv[4], lv[4];
#pragma unroll
    for (int j = 0; j < 4; ++j) {
        hv[j] = f2bfu(o[j]);
        lv[j] = f2bfu(o[j] - bfu2f((unsigned short)hv[j]));
    }
    const size_t oi = (size_t)row * DINNER + c4;
    *(uint2*)&yh[oi] = make_uint2(hv[0] | (hv[1] << 16), hv[2] | (hv[3] << 16));
    *(uint2*)&yl[oi] = make_uint2(lv[0] | (lv[1] << 16), lv[2] | (lv[3] << 16));
}

// ---------------------------------------------------------------------------
extern "C" void kernel_launch(void* const* d_in, const int* in_sizes, int n_in,
                              void* d_out, int out_size, void* d_ws, size_t ws_size,
                              hipStream_t stream)
{
    const float* x_in    = (const float*)d_in[0];
    const float* in_w    = (const float*)d_in[1];
    const float* conv_w  = (const float*)d_in[2];
    const float* conv_b  = (const float*)d_in[3];
    const float* dt_bias = (const float*)d_in[4];
    const float* A_log   = (const float*)d_in[5];
    const float* D_skip  = (const float*)d_in[6];
    const float* norm_w  = (const float*)d_in[7];
    const float* out_w   = (const float*)d_in[8];
    float* out = (float*)d_out;

    float* ws   = (float*)d_ws;
    float* zx   = ws;                               // 19,005,440 f
    float* xh   = zx   + (size_t)ROWS * DINPROJ;    //  8,388,608 f
    float* Bb   = xh   + (size_t)ROWS * DINNER;     //  1,048,576 f
    float* Cb   = Bb   + (size_t)ROWS * DSTATE;     //  1,048,576 f
    float* dtb  = Cb   + (size_t)ROWS * DSTATE;     //    131,072 f
    float* dAb  = dtb  + (size_t)ROWS * NHEADS;     //    131,072 f
    float* yb   = dAb  + (size_t)ROWS * NHEADS;     //  8,388,608 f
    float* UN   = yb   + (size_t)ROWS * DINNER;     // 16,777,216 f (union)
    float* BtF  = UN   + (size_t)16777216;          //  1,245,184 f
    float* WtF  = BtF  + (size_t)1245184;           //    524,288 f
    float* ptot = WtF  + (size_t)524288;            //      2,048 f
    float* lB   = ptot + (size_t)2048;              //    131,072 f
    float* wB   = lB   + (size_t)131072;            //    131,072 f
    float* BTf  = wB   + (size_t)131072;            //  1,048,576 f
    float* Bspf = BTf  + (size_t)1048576;           //  1,048,576 f
    float* Cspf = Bspf + (size_t)1048576;           //  1,048,576 f
    float* CBb  = Cspf + (size_t)1048576;           //    524,288 f
    // total 60,622,848 f = 242.5 MB

    unsigned short* Ah = (unsigned short*)UN;                 // [8192][512]
    unsigned short* Al = Ah + (size_t)ROWS * DMODEL;
    float*          hloc = UN;                                // 16.78M f
    unsigned short* yh = (unsigned short*)UN;                 // [8192][1024]
    unsigned short* yl = yh + (size_t)ROWS * DINNER;

    unsigned short* Bth = (unsigned short*)BtF;               // [2432][512]
    unsigned short* Btl = Bth + (size_t)NPAD_IN * DMODEL;
    unsigned short* Wth = (unsigned short*)WtF;               // [512][1024]
    unsigned short* Wtl = Wth + (size_t)DMODEL * DINNER;

    unsigned short* BTh = (unsigned short*)BTf;               // [128][128][64]
    unsigned short* BTl = BTh + (size_t)128 * 8192;
    unsigned short* Bsph = (unsigned short*)Bspf;             // [8192][128]
    unsigned short* Bspl = Bsph + (size_t)ROWS * DSTATE;
    unsigned short* Csph = (unsigned short*)Cspf;             // [8192][128]
    unsigned short* Cspl = Csph + (size_t)ROWS * DSTATE;

    for (int layer = 0; layer < 2; ++layer) {
        const float* xl = (layer == 0) ? x_in : out;

        split_a_kernel<<<(ROWS * DMODEL) / (256 * 8), 256, 0, stream>>>(xl, Ah, Al);

        tsplit_w_kernel<<<dim3(NPAD_IN / 32, DMODEL / 32), 256, 0, stream>>>(
            in_w + (size_t)layer * DMODEL * DINPROJ, DMODEL, DINPROJ, Bth, Btl);

        // 2-pass everywhere except the dt block (cols >= 2304 get 3rd pass)
        gemm_bf16s<<<dim3(NPAD_IN / 128, ROWS / 128), 256, 0, stream>>>(
            Ah, Al, Bth, Btl, zx, DINPROJ, DINPROJ, DMODEL,
            DINNER + CONVDIM);

        conv_kernel<<<ROWS, CONVDIM / 4, 0, stream>>>(
            zx,
            conv_w + (size_t)layer * DCONV * CONVDIM,
            conv_b + (size_t)layer * CONVDIM,
            dt_bias + (size_t)layer * NHEADS,
            A_log + (size_t)layer * NHEADS,
            xh, Bb, Cb, dtb, dAb);

        meta_kernel<<<BATCH * NHEADS * NSEG, 64, 0, stream>>>(
            dtb, A_log + (size_t)layer * NHEADS, lB, wB, ptot);

        split_a_kernel<<<(ROWS * DSTATE) / (256 * 8), 256, 0, stream>>>(Bb, Bsph, Bspl);
        split_a_kernel<<<(ROWS * DSTATE) / (256 * 8), 256, 0, stream>>>(Cb, Csph, Cspl);

        tsplit_chunk_kernel<<<dim3(128 / 32, 64 / 32, BATCH * NSEG), 256, 0, stream>>>(
            Bb, TSEG, DSTATE, DSTATE, (size_t)TSEG * DSTATE, BTh, BTl);

        cb_kernel<<<BATCH * NSEG, 256, 0, stream>>>(Csph, Cspl, Bsph, Bspl, CBb);

        state_kernel<<<BATCH * NHEADS * NSEG, 256, 0, stream>>>(
            BTh, BTl, xh, wB, hloc);

        combine_kernel<<<BATCH * NHEADS * 8, 256, 0, stream>>>(hloc, ptot);

        y_kernel<<<BATCH * NSEG * 4, 512, 0, stream>>>(
            Csph, Cspl, CBb, lB, dtb, xh, hloc, yb);

        gate_kernel<<<ROWS, 256, 0, stream>>>(
            yb, xh, D_skip + (size_t)layer * NHEADS,
            zx, norm_w + (size_t)layer * DINNER, yh, yl);

        tsplit_w_kernel<<<dim3(DMODEL / 32, DINNER / 32), 256, 0, stream>>>(
            out_w + (size_t)layer * DINNER * DMODEL, DINNER, DMODEL, Wth, Wtl);

        // out-proj fully 2-pass (errors enter output linearly, ~0.4% rel)
        gemm_bf16s<<<dim3(DMODEL / 128, ROWS / 128), 256, 0, stream>>>(
            yh, yl, Wth, Wtl, out, DMODEL, DMODEL, DINNER,
            1 << 30);
    }
}